// Round 1
// baseline (766.357 us; speedup 1.0000x reference)
//
#include <hip/hip_runtime.h>
#include <math.h>

#define INC 128
#define HID 64
#define OUTC 40

// ---------------- CSR build ----------------

__global__ void k_deg(const int* __restrict__ ei, int E, int M, int* __restrict__ deg) {
    for (int e = blockIdx.x * blockDim.x + threadIdx.x; e < M; e += gridDim.x * blockDim.x) {
        int dst = (e < E) ? ei[E + e] : (e - E);
        atomicAdd(&deg[dst], 1);
    }
}

__global__ void k_scan1(const int* __restrict__ deg, int* __restrict__ incl,
                        int* __restrict__ bsums, int n) {
    __shared__ int tmp[256];
    int tid = threadIdx.x;
    int i = blockIdx.x * 256 + tid;
    int v = (i < n) ? deg[i] : 0;
    tmp[tid] = v;
    __syncthreads();
    for (int off = 1; off < 256; off <<= 1) {
        int t = (tid >= off) ? tmp[tid - off] : 0;
        __syncthreads();
        tmp[tid] += t;
        __syncthreads();
    }
    if (i < n) incl[i] = tmp[tid];
    if (tid == 255) bsums[blockIdx.x] = tmp[255];
}

__global__ void k_scan2(int* __restrict__ bsums, int nb) {
    __shared__ int tmp[512];
    int tid = threadIdx.x;
    int v = (tid < nb) ? bsums[tid] : 0;
    tmp[tid] = v;
    __syncthreads();
    for (int off = 1; off < 512; off <<= 1) {
        int t = (tid >= off) ? tmp[tid - off] : 0;
        __syncthreads();
        tmp[tid] += t;
        __syncthreads();
    }
    if (tid < nb) bsums[tid] = tmp[tid];
}

__global__ void k_scan3(const int* __restrict__ deg, const int* __restrict__ incl,
                        const int* __restrict__ bsums, int* __restrict__ row_ptr,
                        int* __restrict__ fill, int n) {
    int tid = threadIdx.x;
    int i = blockIdx.x * 256 + tid;
    if (i < n) {
        int off = blockIdx.x ? bsums[blockIdx.x - 1] : 0;
        int excl = incl[i] - deg[i] + off;
        row_ptr[i] = excl;
        fill[i] = excl;
        if (i == n - 1) row_ptr[n] = incl[i] + off;
    }
}

__global__ void k_scatter(const int* __restrict__ ei, int E, int M,
                          int* __restrict__ fill, int* __restrict__ csr_src) {
    for (int e = blockIdx.x * blockDim.x + threadIdx.x; e < M; e += gridDim.x * blockDim.x) {
        int src, dst;
        if (e < E) { src = ei[e]; dst = ei[E + e]; }
        else       { src = dst = e - E; }
        int slot = atomicAdd(&fill[dst], 1);
        csr_src[slot] = src;
    }
}

// ---------------- Linear1 + ReLU + fused row-norm ----------------

__global__ __launch_bounds__(256) void k_linear1(const float* __restrict__ x,
                                                 const float* __restrict__ W1,
                                                 const float* __restrict__ b1,
                                                 float* __restrict__ h1,
                                                 float* __restrict__ rn1, int n) {
    __shared__ float W1s[INC * HID];   // 32 KB
    __shared__ float xs[4][INC];       // 2 KB
    __shared__ float b1s[HID];
    int tid = threadIdx.x;
    for (int i = tid; i < INC * HID; i += 256) W1s[i] = W1[i];
    if (tid < HID) b1s[tid] = b1[tid];
    __syncthreads();

    int nl = tid >> 6;        // node within group of 4
    int c  = tid & 63;        // channel = lane
    for (int base = blockIdx.x * 4; base < n; base += gridDim.x * 4) {
        for (int i = tid; i < 4 * INC; i += 256) {
            int g = base + (i >> 7);
            xs[i >> 7][i & 127] = (g < n) ? x[(size_t)g * INC + (i & 127)] : 0.0f;
        }
        __syncthreads();
        int node = base + nl;
        if (node < n) {
            float s = b1s[c];
            #pragma unroll
            for (int k = 0; k < INC; ++k) s += xs[nl][k] * W1s[k * HID + c];
            float r = fmaxf(s, 0.0f);
            h1[(size_t)node * HID + c] = r;
            float q = r * r;
            #pragma unroll
            for (int off = 32; off >= 1; off >>= 1) q += __shfl_xor(q, off, 64);
            if (c == 0) rn1[node] = rsqrtf(fmaxf(q, 1e-24f));
        }
        __syncthreads();
    }
}

// ---------------- AGNN propagation (one wave per dst node) ----------------

__global__ __launch_bounds__(256) void k_prop(const float* __restrict__ h,
                                              const float* __restrict__ rn,
                                              const int* __restrict__ row_ptr,
                                              const int* __restrict__ csr_src,
                                              const float* __restrict__ beta_ptr,
                                              float* __restrict__ out,
                                              float* __restrict__ rn_out, int n) {
    int node = blockIdx.x * 4 + (threadIdx.x >> 6);
    if (node >= n) return;
    int lane = threadIdx.x & 63;
    float beta = beta_ptr ? beta_ptr[0] : 1.0f;

    float hd  = h[(size_t)node * HID + lane];
    float rnd = rn[node];
    int s0 = row_ptr[node], s1 = row_ptr[node + 1];
    float acc = 0.0f, denom = 0.0f;
    for (int j = s0; j < s1; ++j) {
        int s = csr_src[j];
        float hs = h[(size_t)s * HID + lane];
        float d = hs * hd;
        #pragma unroll
        for (int off = 32; off >= 1; off >>= 1) d += __shfl_xor(d, off, 64);
        float e = __expf(beta * rn[s] * rnd * d);
        denom += e;
        acc += e * hs;
    }
    float o = acc / denom;
    out[(size_t)node * HID + lane] = o;
    float q = o * o;
    #pragma unroll
    for (int off = 32; off >= 1; off >>= 1) q += __shfl_xor(q, off, 64);
    if (lane == 0) rn_out[node] = rsqrtf(fmaxf(q, 1e-24f));
}

// ---------------- Linear2 + log_softmax ----------------

__global__ __launch_bounds__(256) void k_out(const float* __restrict__ h,
                                             const float* __restrict__ W2,
                                             const float* __restrict__ b2,
                                             float* __restrict__ out, int n) {
    __shared__ float W2s[HID * OUTC];  // 10 KB
    __shared__ float b2s[OUTC];
    int tid = threadIdx.x;
    for (int i = tid; i < HID * OUTC; i += 256) W2s[i] = W2[i];
    if (tid < OUTC) b2s[tid] = b2[tid];
    __syncthreads();

    int node = blockIdx.x * 4 + (tid >> 6);
    if (node >= n) return;
    int lane = tid & 63;

    float logit = -INFINITY;
    if (lane < OUTC) {
        float s = b2s[lane];
        #pragma unroll
        for (int k = 0; k < HID; ++k) s += h[(size_t)node * HID + k] * W2s[k * OUTC + lane];
        logit = s;
    }
    float m = logit;
    #pragma unroll
    for (int off = 32; off >= 1; off >>= 1) m = fmaxf(m, __shfl_xor(m, off, 64));
    float z = (lane < OUTC) ? __expf(logit - m) : 0.0f;
    #pragma unroll
    for (int off = 32; off >= 1; off >>= 1) z += __shfl_xor(z, off, 64);
    if (lane < OUTC) out[(size_t)node * OUTC + lane] = logit - m - __logf(z);
}

// ---------------- launch ----------------

extern "C" void kernel_launch(void* const* d_in, const int* in_sizes, int n_in,
                              void* d_out, int out_size, void* d_ws, size_t ws_size,
                              hipStream_t stream) {
    const float* x   = (const float*)d_in[0];
    const int*   ei  = (const int*)d_in[1];
    const float* W1  = (const float*)d_in[2];
    const float* b1  = (const float*)d_in[3];
    const float* W2  = (const float*)d_in[4];
    const float* b2  = (const float*)d_in[5];
    const float* beta2 = (const float*)d_in[6];
    float* out = (float*)d_out;

    const int n = in_sizes[0] / INC;       // 100000
    const int E = in_sizes[1] / 2;         // 1600000
    const int M = E + n;                   // with self loops
    const int nb = (n + 255) / 256;        // scan blocks (391)

    // workspace layout
    char* p = (char*)d_ws;
    float* h1  = (float*)p;            p += (size_t)n * HID * 4;
    float* h2  = (float*)p;            p += (size_t)n * HID * 4;
    float* rn1 = (float*)p;            p += (size_t)n * 4;
    float* rn2 = (float*)p;            p += (size_t)n * 4;
    int* deg     = (int*)p;            p += (size_t)n * 4;
    int* incl    = (int*)p;            p += (size_t)n * 4;
    int* bsums   = (int*)p;            p += 512 * 4;
    int* row_ptr = (int*)p;            p += (size_t)(n + 1) * 4;
    int* fill    = (int*)p;            p += (size_t)n * 4;
    int* csr_src = (int*)p;            p += (size_t)M * 4;
    float* h3 = h1;                    // reuse

    // CSR build
    hipMemsetAsync(deg, 0, (size_t)n * 4, stream);
    k_deg<<<2048, 256, 0, stream>>>(ei, E, M, deg);
    k_scan1<<<nb, 256, 0, stream>>>(deg, incl, bsums, n);
    k_scan2<<<1, 512, 0, stream>>>(bsums, nb);
    k_scan3<<<nb, 256, 0, stream>>>(deg, incl, bsums, row_ptr, fill, n);
    k_scatter<<<2048, 256, 0, stream>>>(ei, E, M, fill, csr_src);

    // MLP front + props + head
    k_linear1<<<1024, 256, 0, stream>>>(x, W1, b1, h1, rn1, n);
    int pgrid = (n + 3) / 4;
    k_prop<<<pgrid, 256, 0, stream>>>(h1, rn1, row_ptr, csr_src, nullptr, h2, rn2, n);
    k_prop<<<pgrid, 256, 0, stream>>>(h2, rn2, row_ptr, csr_src, beta2, h3, rn1, n);
    k_out<<<pgrid, 256, 0, stream>>>(h3, W2, b2, out, n);
}

// Round 2
// 601.429 us; speedup vs baseline: 1.2742x; 1.2742x over previous
//
#include <hip/hip_runtime.h>
#include <math.h>

#define INC 128
#define HID 64
#define OUTC 40

// ---------------- CSR build ----------------

__global__ void k_deg(const int* __restrict__ ei, int E, int M, int* __restrict__ deg) {
    for (int e = blockIdx.x * blockDim.x + threadIdx.x; e < M; e += gridDim.x * blockDim.x) {
        int dst = (e < E) ? ei[E + e] : (e - E);
        atomicAdd(&deg[dst], 1);
    }
}

__global__ void k_scan1(const int* __restrict__ deg, int* __restrict__ incl,
                        int* __restrict__ bsums, int n) {
    __shared__ int tmp[256];
    int tid = threadIdx.x;
    int i = blockIdx.x * 256 + tid;
    int v = (i < n) ? deg[i] : 0;
    tmp[tid] = v;
    __syncthreads();
    for (int off = 1; off < 256; off <<= 1) {
        int t = (tid >= off) ? tmp[tid - off] : 0;
        __syncthreads();
        tmp[tid] += t;
        __syncthreads();
    }
    if (i < n) incl[i] = tmp[tid];
    if (tid == 255) bsums[blockIdx.x] = tmp[255];
}

__global__ void k_scan2(int* __restrict__ bsums, int nb) {
    __shared__ int tmp[512];
    int tid = threadIdx.x;
    int v = (tid < nb) ? bsums[tid] : 0;
    tmp[tid] = v;
    __syncthreads();
    for (int off = 1; off < 512; off <<= 1) {
        int t = (tid >= off) ? tmp[tid - off] : 0;
        __syncthreads();
        tmp[tid] += t;
        __syncthreads();
    }
    if (tid < nb) bsums[tid] = tmp[tid];
}

__global__ void k_scan3(const int* __restrict__ deg, const int* __restrict__ incl,
                        const int* __restrict__ bsums, int* __restrict__ row_ptr,
                        int* __restrict__ fill, int n) {
    int tid = threadIdx.x;
    int i = blockIdx.x * 256 + tid;
    if (i < n) {
        int off = blockIdx.x ? bsums[blockIdx.x - 1] : 0;
        int excl = incl[i] - deg[i] + off;
        row_ptr[i] = excl;
        fill[i] = excl;
        if (i == n - 1) row_ptr[n] = incl[i] + off;
    }
}

__global__ void k_scatter(const int* __restrict__ ei, int E, int M,
                          int* __restrict__ fill, int* __restrict__ csr_src) {
    for (int e = blockIdx.x * blockDim.x + threadIdx.x; e < M; e += gridDim.x * blockDim.x) {
        int src, dst;
        if (e < E) { src = ei[e]; dst = ei[E + e]; }
        else       { src = dst = e - E; }
        int slot = atomicAdd(&fill[dst], 1);
        csr_src[slot] = src;
    }
}

// ---------------- Linear1 + ReLU + fused row-norm ----------------

__global__ __launch_bounds__(256) void k_linear1(const float* __restrict__ x,
                                                 const float* __restrict__ W1,
                                                 const float* __restrict__ b1,
                                                 float* __restrict__ h1,
                                                 float* __restrict__ rn1, int n) {
    __shared__ float W1s[INC * HID];   // 32 KB
    __shared__ float xs[4][INC];       // 2 KB
    __shared__ float b1s[HID];
    int tid = threadIdx.x;
    for (int i = tid; i < INC * HID; i += 256) W1s[i] = W1[i];
    if (tid < HID) b1s[tid] = b1[tid];
    __syncthreads();

    int nl = tid >> 6;        // node within group of 4
    int c  = tid & 63;        // channel = lane
    for (int base = blockIdx.x * 4; base < n; base += gridDim.x * 4) {
        for (int i = tid; i < 4 * INC; i += 256) {
            int g = base + (i >> 7);
            xs[i >> 7][i & 127] = (g < n) ? x[(size_t)g * INC + (i & 127)] : 0.0f;
        }
        __syncthreads();
        int node = base + nl;
        if (node < n) {
            float s = b1s[c];
            #pragma unroll
            for (int k = 0; k < INC; ++k) s += xs[nl][k] * W1s[k * HID + c];
            float r = fmaxf(s, 0.0f);
            h1[(size_t)node * HID + c] = r;
            float q = r * r;
            #pragma unroll
            for (int off = 32; off >= 1; off >>= 1) q += __shfl_xor(q, off, 64);
            if (c == 0) rn1[node] = rsqrtf(fmaxf(q, 1e-24f));
        }
        __syncthreads();
    }
}

// ---------------- AGNN propagation (one wave per dst node, 4-deep ILP) ----------------

__global__ __launch_bounds__(256) void k_prop(const float* __restrict__ h,
                                              const float* __restrict__ rn,
                                              const int* __restrict__ row_ptr,
                                              const int* __restrict__ csr_src,
                                              const float* __restrict__ beta_ptr,
                                              float* __restrict__ out,
                                              float* __restrict__ rn_out, int n) {
    int node = blockIdx.x * 4 + (threadIdx.x >> 6);
    if (node >= n) return;
    int lane = threadIdx.x & 63;
    float beta = beta_ptr ? beta_ptr[0] : 1.0f;

    float hd  = h[(size_t)node * HID + lane];
    float rnd = rn[node];
    float brnd = beta * rnd;
    int s0 = row_ptr[node], s1 = row_ptr[node + 1];

    float acc0 = 0.0f, acc1 = 0.0f, acc2 = 0.0f, acc3 = 0.0f;
    float den0 = 0.0f, den1 = 0.0f, den2 = 0.0f, den3 = 0.0f;

    int j = s0;
    for (; j + 3 < s1; j += 4) {
        int i0 = csr_src[j];
        int i1 = csr_src[j + 1];
        int i2 = csr_src[j + 2];
        int i3 = csr_src[j + 3];
        float a0 = h[(size_t)i0 * HID + lane];
        float a1 = h[(size_t)i1 * HID + lane];
        float a2 = h[(size_t)i2 * HID + lane];
        float a3 = h[(size_t)i3 * HID + lane];
        float r0 = rn[i0], r1 = rn[i1], r2 = rn[i2], r3 = rn[i3];
        float d0 = a0 * hd, d1 = a1 * hd, d2 = a2 * hd, d3 = a3 * hd;
        #pragma unroll
        for (int off = 32; off >= 1; off >>= 1) {
            d0 += __shfl_xor(d0, off, 64);
            d1 += __shfl_xor(d1, off, 64);
            d2 += __shfl_xor(d2, off, 64);
            d3 += __shfl_xor(d3, off, 64);
        }
        float e0 = __expf(brnd * r0 * d0);
        float e1 = __expf(brnd * r1 * d1);
        float e2 = __expf(brnd * r2 * d2);
        float e3 = __expf(brnd * r3 * d3);
        den0 += e0; acc0 += e0 * a0;
        den1 += e1; acc1 += e1 * a1;
        den2 += e2; acc2 += e2 * a2;
        den3 += e3; acc3 += e3 * a3;
    }
    for (; j < s1; ++j) {
        int s = csr_src[j];
        float hs = h[(size_t)s * HID + lane];
        float d = hs * hd;
        #pragma unroll
        for (int off = 32; off >= 1; off >>= 1) d += __shfl_xor(d, off, 64);
        float e = __expf(brnd * rn[s] * d);
        den0 += e;
        acc0 += e * hs;
    }
    float acc = (acc0 + acc1) + (acc2 + acc3);
    float den = (den0 + den1) + (den2 + den3);
    float o = acc / den;
    out[(size_t)node * HID + lane] = o;
    float q = o * o;
    #pragma unroll
    for (int off = 32; off >= 1; off >>= 1) q += __shfl_xor(q, off, 64);
    if (lane == 0) rn_out[node] = rsqrtf(fmaxf(q, 1e-24f));
}

// ---------------- Linear2 + log_softmax ----------------

__global__ __launch_bounds__(256) void k_out(const float* __restrict__ h,
                                             const float* __restrict__ W2,
                                             const float* __restrict__ b2,
                                             float* __restrict__ out, int n) {
    __shared__ float W2s[HID * OUTC];  // 10 KB
    __shared__ float b2s[OUTC];
    int tid = threadIdx.x;
    for (int i = tid; i < HID * OUTC; i += 256) W2s[i] = W2[i];
    if (tid < OUTC) b2s[tid] = b2[tid];
    __syncthreads();

    int node = blockIdx.x * 4 + (tid >> 6);
    if (node >= n) return;
    int lane = tid & 63;

    float logit = -INFINITY;
    if (lane < OUTC) {
        float s = b2s[lane];
        #pragma unroll
        for (int k = 0; k < HID; ++k) s += h[(size_t)node * HID + k] * W2s[k * OUTC + lane];
        logit = s;
    }
    float m = logit;
    #pragma unroll
    for (int off = 32; off >= 1; off >>= 1) m = fmaxf(m, __shfl_xor(m, off, 64));
    float z = (lane < OUTC) ? __expf(logit - m) : 0.0f;
    #pragma unroll
    for (int off = 32; off >= 1; off >>= 1) z += __shfl_xor(z, off, 64);
    if (lane < OUTC) out[(size_t)node * OUTC + lane] = logit - m - __logf(z);
}

// ---------------- launch ----------------

extern "C" void kernel_launch(void* const* d_in, const int* in_sizes, int n_in,
                              void* d_out, int out_size, void* d_ws, size_t ws_size,
                              hipStream_t stream) {
    const float* x   = (const float*)d_in[0];
    const int*   ei  = (const int*)d_in[1];
    const float* W1  = (const float*)d_in[2];
    const float* b1  = (const float*)d_in[3];
    const float* W2  = (const float*)d_in[4];
    const float* b2  = (const float*)d_in[5];
    const float* beta2 = (const float*)d_in[6];
    float* out = (float*)d_out;

    const int n = in_sizes[0] / INC;       // 100000
    const int E = in_sizes[1] / 2;         // 1600000
    const int M = E + n;                   // with self loops
    const int nb = (n + 255) / 256;        // scan blocks (391)

    // workspace layout
    char* p = (char*)d_ws;
    float* h1  = (float*)p;            p += (size_t)n * HID * 4;
    float* h2  = (float*)p;            p += (size_t)n * HID * 4;
    float* rn1 = (float*)p;            p += (size_t)n * 4;
    float* rn2 = (float*)p;            p += (size_t)n * 4;
    int* deg     = (int*)p;            p += (size_t)n * 4;
    int* incl    = (int*)p;            p += (size_t)n * 4;
    int* bsums   = (int*)p;            p += 512 * 4;
    int* row_ptr = (int*)p;            p += (size_t)(n + 1) * 4;
    int* fill    = (int*)p;            p += (size_t)n * 4;
    int* csr_src = (int*)p;            p += (size_t)M * 4;
    float* h3 = h1;                    // reuse

    // CSR build
    hipMemsetAsync(deg, 0, (size_t)n * 4, stream);
    k_deg<<<2048, 256, 0, stream>>>(ei, E, M, deg);
    k_scan1<<<nb, 256, 0, stream>>>(deg, incl, bsums, n);
    k_scan2<<<1, 512, 0, stream>>>(bsums, nb);
    k_scan3<<<nb, 256, 0, stream>>>(deg, incl, bsums, row_ptr, fill, n);
    k_scatter<<<2048, 256, 0, stream>>>(ei, E, M, fill, csr_src);

    // MLP front + props + head
    k_linear1<<<1024, 256, 0, stream>>>(x, W1, b1, h1, rn1, n);
    int pgrid = (n + 3) / 4;
    k_prop<<<pgrid, 256, 0, stream>>>(h1, rn1, row_ptr, csr_src, nullptr, h2, rn2, n);
    k_prop<<<pgrid, 256, 0, stream>>>(h2, rn2, row_ptr, csr_src, beta2, h3, rn1, n);
    k_out<<<pgrid, 256, 0, stream>>>(h3, W2, b2, out, n);
}

// Round 3
// 528.872 us; speedup vs baseline: 1.4490x; 1.1372x over previous
//
#include <hip/hip_runtime.h>
#include <math.h>

#define INC 128
#define HID 64
#define OUTC 40

// ---------------- CSR build ----------------

__global__ void k_init(int* __restrict__ deg, int n) {
    int i = blockIdx.x * 256 + threadIdx.x;
    if (i < n) deg[i] = 1;          // self-loop pre-counted
}

__global__ void k_deg(const int* __restrict__ ei, int E, int* __restrict__ deg) {
    int t = blockIdx.x * blockDim.x + threadIdx.x;
    int base = t * 8;
    if (base >= E) return;
    if (base + 8 <= E) {
        const int4* d4 = (const int4*)(ei + E);
        int4 a = d4[t * 2], b = d4[t * 2 + 1];
        atomicAdd(&deg[a.x], 1); atomicAdd(&deg[a.y], 1);
        atomicAdd(&deg[a.z], 1); atomicAdd(&deg[a.w], 1);
        atomicAdd(&deg[b.x], 1); atomicAdd(&deg[b.y], 1);
        atomicAdd(&deg[b.z], 1); atomicAdd(&deg[b.w], 1);
    } else {
        for (int e = base; e < E; ++e) atomicAdd(&deg[ei[E + e]], 1);
    }
}

__global__ void k_scan1(const int* __restrict__ deg, int* __restrict__ incl,
                        int* __restrict__ bsums, int n) {
    __shared__ int tmp[256];
    int tid = threadIdx.x;
    int i = blockIdx.x * 256 + tid;
    int v = (i < n) ? deg[i] : 0;
    tmp[tid] = v;
    __syncthreads();
    for (int off = 1; off < 256; off <<= 1) {
        int t = (tid >= off) ? tmp[tid - off] : 0;
        __syncthreads();
        tmp[tid] += t;
        __syncthreads();
    }
    if (i < n) incl[i] = tmp[tid];
    if (tid == 255) bsums[blockIdx.x] = tmp[255];
}

__global__ void k_scan2(int* __restrict__ bsums, int nb) {
    __shared__ int tmp[512];
    int tid = threadIdx.x;
    int v = (tid < nb) ? bsums[tid] : 0;
    tmp[tid] = v;
    __syncthreads();
    for (int off = 1; off < 512; off <<= 1) {
        int t = (tid >= off) ? tmp[tid - off] : 0;
        __syncthreads();
        tmp[tid] += t;
        __syncthreads();
    }
    if (tid < nb) bsums[tid] = tmp[tid];
}

__global__ void k_scan3(const int* __restrict__ deg, const int* __restrict__ incl,
                        const int* __restrict__ bsums, int* __restrict__ row_ptr,
                        int* __restrict__ fill, int* __restrict__ csr_src, int n) {
    int tid = threadIdx.x;
    int i = blockIdx.x * 256 + tid;
    if (i < n) {
        int off = blockIdx.x ? bsums[blockIdx.x - 1] : 0;
        int excl = incl[i] - deg[i] + off;
        row_ptr[i] = excl;
        fill[i] = excl + 1;      // slot 0 of each bucket = self-loop
        csr_src[excl] = i;
        if (i == n - 1) row_ptr[n] = incl[i] + off;
    }
}

__global__ void k_scatter(const int* __restrict__ ei, int E,
                          int* __restrict__ fill, int* __restrict__ csr_src) {
    int t = blockIdx.x * blockDim.x + threadIdx.x;
    int base = t * 8;
    if (base >= E) return;
    if (base + 8 <= E) {
        const int4* s4 = (const int4*)ei;
        const int4* d4 = (const int4*)(ei + E);
        int4 sa = s4[t * 2], sb = s4[t * 2 + 1];
        int4 da = d4[t * 2], db = d4[t * 2 + 1];
        int p0 = atomicAdd(&fill[da.x], 1);
        int p1 = atomicAdd(&fill[da.y], 1);
        int p2 = atomicAdd(&fill[da.z], 1);
        int p3 = atomicAdd(&fill[da.w], 1);
        int p4 = atomicAdd(&fill[db.x], 1);
        int p5 = atomicAdd(&fill[db.y], 1);
        int p6 = atomicAdd(&fill[db.z], 1);
        int p7 = atomicAdd(&fill[db.w], 1);
        csr_src[p0] = sa.x; csr_src[p1] = sa.y;
        csr_src[p2] = sa.z; csr_src[p3] = sa.w;
        csr_src[p4] = sb.x; csr_src[p5] = sb.y;
        csr_src[p6] = sb.z; csr_src[p7] = sb.w;
    } else {
        for (int e = base; e < E; ++e) {
            int slot = atomicAdd(&fill[ei[E + e]], 1);
            csr_src[slot] = ei[e];
        }
    }
}

// ---------------- Linear1 + ReLU + fused row-norm ----------------

__global__ __launch_bounds__(256) void k_linear1(const float* __restrict__ x,
                                                 const float* __restrict__ W1,
                                                 const float* __restrict__ b1,
                                                 float* __restrict__ h1,
                                                 float* __restrict__ rn1, int n) {
    __shared__ float W1s[INC * HID];   // 32 KB
    __shared__ float xs[4][INC];       // 2 KB
    __shared__ float b1s[HID];
    int tid = threadIdx.x;
    for (int i = tid; i < INC * HID; i += 256) W1s[i] = W1[i];
    if (tid < HID) b1s[tid] = b1[tid];
    __syncthreads();

    int nl = tid >> 6;        // node within group of 4
    int c  = tid & 63;        // channel = lane
    for (int base = blockIdx.x * 4; base < n; base += gridDim.x * 4) {
        for (int i = tid; i < 4 * INC; i += 256) {
            int g = base + (i >> 7);
            xs[i >> 7][i & 127] = (g < n) ? x[(size_t)g * INC + (i & 127)] : 0.0f;
        }
        __syncthreads();
        int node = base + nl;
        if (node < n) {
            float s = b1s[c];
            #pragma unroll
            for (int k = 0; k < INC; ++k) s += xs[nl][k] * W1s[k * HID + c];
            float r = fmaxf(s, 0.0f);
            h1[(size_t)node * HID + c] = r;
            float q = r * r;
            #pragma unroll
            for (int off = 32; off >= 1; off >>= 1) q += __shfl_xor(q, off, 64);
            if (c == 0) rn1[node] = rsqrtf(fmaxf(q, 1e-24f));
        }
        __syncthreads();
    }
}

// ---------------- AGNN propagation ----------------
// one wave per dst node; half-wave (32 lanes x float2) per edge; 4 chains => 8 edges in flight

__global__ __launch_bounds__(256) void k_prop(const float* __restrict__ h,
                                              const float* __restrict__ rn,
                                              const int* __restrict__ row_ptr,
                                              const int* __restrict__ csr_src,
                                              const float* __restrict__ beta_ptr,
                                              float* __restrict__ out,
                                              float* __restrict__ rn_out, int n) {
    int node = blockIdx.x * 4 + (threadIdx.x >> 6);
    if (node >= n) return;
    int lane = threadIdx.x & 63;
    int half = lane >> 5;
    int hl   = lane & 31;
    float beta = beta_ptr ? beta_ptr[0] : 1.0f;

    const float2* h2 = (const float2*)h;
    float2 hd = h2[(size_t)node * 32 + hl];
    float brnd = beta * rn[node];
    int s0 = row_ptr[node], s1 = row_ptr[node + 1];

    float2 acc0 = {0.f, 0.f}, acc1 = {0.f, 0.f}, acc2 = {0.f, 0.f}, acc3 = {0.f, 0.f};
    float den0 = 0.f, den1 = 0.f, den2 = 0.f, den3 = 0.f;

    int j = s0;
    for (; j + 7 < s1; j += 8) {
        int i0 = csr_src[j +     half];
        int i1 = csr_src[j + 2 + half];
        int i2 = csr_src[j + 4 + half];
        int i3 = csr_src[j + 6 + half];
        float2 a0 = h2[(size_t)i0 * 32 + hl];
        float2 a1 = h2[(size_t)i1 * 32 + hl];
        float2 a2 = h2[(size_t)i2 * 32 + hl];
        float2 a3 = h2[(size_t)i3 * 32 + hl];
        float r0 = rn[i0], r1 = rn[i1], r2 = rn[i2], r3 = rn[i3];
        float d0 = a0.x * hd.x + a0.y * hd.y;
        float d1 = a1.x * hd.x + a1.y * hd.y;
        float d2 = a2.x * hd.x + a2.y * hd.y;
        float d3 = a3.x * hd.x + a3.y * hd.y;
        #pragma unroll
        for (int off = 16; off >= 1; off >>= 1) {
            d0 += __shfl_xor(d0, off, 64);
            d1 += __shfl_xor(d1, off, 64);
            d2 += __shfl_xor(d2, off, 64);
            d3 += __shfl_xor(d3, off, 64);
        }
        float e0 = __expf(brnd * r0 * d0);
        float e1 = __expf(brnd * r1 * d1);
        float e2 = __expf(brnd * r2 * d2);
        float e3 = __expf(brnd * r3 * d3);
        den0 += e0; acc0.x += e0 * a0.x; acc0.y += e0 * a0.y;
        den1 += e1; acc1.x += e1 * a1.x; acc1.y += e1 * a1.y;
        den2 += e2; acc2.x += e2 * a2.x; acc2.y += e2 * a2.y;
        den3 += e3; acc3.x += e3 * a3.x; acc3.y += e3 * a3.y;
    }
    for (; j < s1; j += 2) {
        int idx = j + half;
        bool act = idx < s1;
        int is = act ? csr_src[idx] : csr_src[s0];
        float2 a = h2[(size_t)is * 32 + hl];
        float rs = rn[is];
        float d = a.x * hd.x + a.y * hd.y;
        #pragma unroll
        for (int off = 16; off >= 1; off >>= 1) d += __shfl_xor(d, off, 64);
        float e = act ? __expf(brnd * rs * d) : 0.0f;
        den0 += e; acc0.x += e * a.x; acc0.y += e * a.y;
    }
    float ax = (acc0.x + acc1.x) + (acc2.x + acc3.x);
    float ay = (acc0.y + acc1.y) + (acc2.y + acc3.y);
    float dn = (den0 + den1) + (den2 + den3);
    ax += __shfl_xor(ax, 32, 64);
    ay += __shfl_xor(ay, 32, 64);
    dn += __shfl_xor(dn, 32, 64);
    float ox = ax / dn, oy = ay / dn;
    if (half == 0) ((float2*)out)[(size_t)node * 32 + hl] = make_float2(ox, oy);
    float q = ox * ox + oy * oy;
    #pragma unroll
    for (int off = 16; off >= 1; off >>= 1) q += __shfl_xor(q, off, 64);
    if (lane == 0) rn_out[node] = rsqrtf(fmaxf(q, 1e-24f));
}

// ---------------- Linear2 + log_softmax ----------------

__global__ __launch_bounds__(256) void k_out(const float* __restrict__ h,
                                             const float* __restrict__ W2,
                                             const float* __restrict__ b2,
                                             float* __restrict__ out, int n) {
    __shared__ float W2s[HID * OUTC];  // 10 KB
    __shared__ float b2s[OUTC];
    int tid = threadIdx.x;
    for (int i = tid; i < HID * OUTC; i += 256) W2s[i] = W2[i];
    if (tid < OUTC) b2s[tid] = b2[tid];
    __syncthreads();

    int node = blockIdx.x * 4 + (tid >> 6);
    if (node >= n) return;
    int lane = tid & 63;

    float logit = -INFINITY;
    if (lane < OUTC) {
        float s = b2s[lane];
        #pragma unroll
        for (int k = 0; k < HID; ++k) s += h[(size_t)node * HID + k] * W2s[k * OUTC + lane];
        logit = s;
    }
    float m = logit;
    #pragma unroll
    for (int off = 32; off >= 1; off >>= 1) m = fmaxf(m, __shfl_xor(m, off, 64));
    float z = (lane < OUTC) ? __expf(logit - m) : 0.0f;
    #pragma unroll
    for (int off = 32; off >= 1; off >>= 1) z += __shfl_xor(z, off, 64);
    if (lane < OUTC) out[(size_t)node * OUTC + lane] = logit - m - __logf(z);
}

// ---------------- launch ----------------

extern "C" void kernel_launch(void* const* d_in, const int* in_sizes, int n_in,
                              void* d_out, int out_size, void* d_ws, size_t ws_size,
                              hipStream_t stream) {
    const float* x   = (const float*)d_in[0];
    const int*   ei  = (const int*)d_in[1];
    const float* W1  = (const float*)d_in[2];
    const float* b1  = (const float*)d_in[3];
    const float* W2  = (const float*)d_in[4];
    const float* b2  = (const float*)d_in[5];
    const float* beta2 = (const float*)d_in[6];
    float* out = (float*)d_out;

    const int n = in_sizes[0] / INC;       // 100000
    const int E = in_sizes[1] / 2;         // 1600000
    const int M = E + n;                   // with self loops
    const int nb = (n + 255) / 256;        // scan blocks (391)

    // workspace layout
    char* p = (char*)d_ws;
    float* h1  = (float*)p;            p += (size_t)n * HID * 4;
    float* h2  = (float*)p;            p += (size_t)n * HID * 4;
    float* rn1 = (float*)p;            p += (size_t)n * 4;
    float* rn2 = (float*)p;            p += (size_t)n * 4;
    int* deg     = (int*)p;            p += (size_t)n * 4;
    int* incl    = (int*)p;            p += (size_t)n * 4;
    int* bsums   = (int*)p;            p += 512 * 4;
    int* row_ptr = (int*)p;            p += (size_t)(n + 1) * 4;
    int* fill    = (int*)p;            p += (size_t)n * 4;
    int* csr_src = (int*)p;            p += (size_t)M * 4;
    float* h3 = h1;                    // reuse

    // CSR build
    int egrid = (E / 8 + 255) / 256 + 1;
    k_init<<<nb, 256, 0, stream>>>(deg, n);
    k_deg<<<egrid, 256, 0, stream>>>(ei, E, deg);
    k_scan1<<<nb, 256, 0, stream>>>(deg, incl, bsums, n);
    k_scan2<<<1, 512, 0, stream>>>(bsums, nb);
    k_scan3<<<nb, 256, 0, stream>>>(deg, incl, bsums, row_ptr, fill, csr_src, n);
    k_scatter<<<egrid, 256, 0, stream>>>(ei, E, fill, csr_src);

    // MLP front + props + head
    k_linear1<<<1024, 256, 0, stream>>>(x, W1, b1, h1, rn1, n);
    int pgrid = (n + 3) / 4;
    k_prop<<<pgrid, 256, 0, stream>>>(h1, rn1, row_ptr, csr_src, nullptr, h2, rn2, n);
    k_prop<<<pgrid, 256, 0, stream>>>(h2, rn2, row_ptr, csr_src, beta2, h3, rn1, n);
    k_out<<<pgrid, 256, 0, stream>>>(h3, W2, b2, out, n);
}

// Round 4
// 382.946 us; speedup vs baseline: 2.0012x; 1.3811x over previous
//
#include <hip/hip_runtime.h>
#include <math.h>

#define INC 128
#define HID 64
#define OUTC 40
#define SHIFT 9
#define MAXB 256

// ---------------- CSR build: bucketed counting sort ----------------

// Pass 0: histogram of dst buckets
__global__ __launch_bounds__(256) void k_hist(const int* __restrict__ ei, int E,
                                              int* __restrict__ bucket_cnt, int nbuck) {
    __shared__ int lh[MAXB];
    int tid = threadIdx.x;
    for (int i = tid; i < nbuck; i += 256) lh[i] = 0;
    __syncthreads();
    int base = blockIdx.x * 4096;
    int end = min(base + 4096, E);
    for (int e = base + tid; e < end; e += 256)
        atomicAdd(&lh[ei[E + e] >> SHIFT], 1);
    __syncthreads();
    for (int i = tid; i < nbuck; i += 256)
        if (lh[i]) atomicAdd(&bucket_cnt[i], lh[i]);
}

// Scan bucket counts -> pair bases (edges only) and csr bases (edges + self loops)
__global__ __launch_bounds__(256) void k_bscan(const int* __restrict__ bucket_cnt,
                                               int* __restrict__ pair_base,
                                               int* __restrict__ pair_fill,
                                               int* __restrict__ bucket_base,
                                               int* __restrict__ row_ptr,
                                               int n, int E, int nbuck) {
    __shared__ int tmp[MAXB];
    int tid = threadIdx.x;
    int cnt = (tid < nbuck) ? bucket_cnt[tid] : 0;
    int nb0 = tid << SHIFT;
    int nodes = (tid < nbuck) ? (min(n, nb0 + (1 << SHIFT)) - nb0) : 0;

    tmp[tid] = cnt;
    __syncthreads();
    for (int off = 1; off < 256; off <<= 1) {
        int t = (tid >= off) ? tmp[tid - off] : 0;
        __syncthreads();
        tmp[tid] += t;
        __syncthreads();
    }
    if (tid < nbuck) { int pb = tmp[tid] - cnt; pair_base[tid] = pb; pair_fill[tid] = pb; }
    __syncthreads();

    tmp[tid] = cnt + nodes;
    __syncthreads();
    for (int off = 1; off < 256; off <<= 1) {
        int t = (tid >= off) ? tmp[tid - off] : 0;
        __syncthreads();
        tmp[tid] += t;
        __syncthreads();
    }
    if (tid < nbuck) bucket_base[tid] = tmp[tid] - (cnt + nodes);
    if (tid == 0) row_ptr[n] = E + n;
}

// Pass 1: bin (src,dst) pairs into bucket regions with coalesced run writes
__global__ __launch_bounds__(256) void k_bin(const int* __restrict__ ei, int E,
                                             int* __restrict__ pair_fill,
                                             int2* __restrict__ pairs, int nbuck) {
    __shared__ int lh[MAXB];
    __shared__ int lbase[MAXB];
    int tid = threadIdx.x;
    for (int i = tid; i < nbuck; i += 256) lh[i] = 0;
    __syncthreads();
    int base = blockIdx.x * 4096;
    int end = min(base + 4096, E);
    for (int e = base + tid; e < end; e += 256)
        atomicAdd(&lh[ei[E + e] >> SHIFT], 1);
    __syncthreads();
    for (int i = tid; i < nbuck; i += 256)
        lbase[i] = lh[i] ? atomicAdd(&pair_fill[i], lh[i]) : 0;
    __syncthreads();
    for (int e = base + tid; e < end; e += 256) {
        int s = ei[e], d = ei[E + e];
        int pos = atomicAdd(&lbase[d >> SHIFT], 1);
        pairs[pos] = make_int2(s, d);
    }
}

// Pass 2: per-bucket exact CSR build (L1/L2-resident scatter)
__global__ __launch_bounds__(256) void k_build(const int2* __restrict__ pairs,
                                               const int* __restrict__ pair_base,
                                               const int* __restrict__ bucket_cnt,
                                               const int* __restrict__ bucket_base,
                                               int* __restrict__ row_ptr,
                                               int* __restrict__ csr_src, int n) {
    __shared__ int cnt[1 << SHIFT];
    __shared__ int offs[1 << SHIFT];
    __shared__ int stmp[256];
    int b = blockIdx.x;
    int tid = threadIdx.x;
    int nb0 = b << SHIFT;
    int W = min(n - nb0, 1 << SHIFT);
    int p0 = pair_base[b], pc = bucket_cnt[b];
    int cb = bucket_base[b];

    cnt[tid] = 0; cnt[tid + 256] = 0;
    __syncthreads();
    for (int i = tid; i < pc; i += 256)
        atomicAdd(&cnt[pairs[p0 + i].y - nb0], 1);
    __syncthreads();

    // block scan of sizes (cnt+1 per live node), 2 elements per thread
    int i0 = 2 * tid, i1 = 2 * tid + 1;
    int s0 = (i0 < W) ? cnt[i0] + 1 : 0;
    int s1 = (i1 < W) ? cnt[i1] + 1 : 0;
    int ps = s0 + s1;
    stmp[tid] = ps;
    __syncthreads();
    for (int off = 1; off < 256; off <<= 1) {
        int t = (tid >= off) ? stmp[tid - off] : 0;
        __syncthreads();
        stmp[tid] += t;
        __syncthreads();
    }
    int excl = stmp[tid] - ps;
    int e0 = excl, e1 = excl + s0;
    if (i0 < W) { row_ptr[nb0 + i0] = cb + e0; offs[i0] = e0 + 1; csr_src[cb + e0] = nb0 + i0; }
    if (i1 < W) { row_ptr[nb0 + i1] = cb + e1; offs[i1] = e1 + 1; csr_src[cb + e1] = nb0 + i1; }
    __syncthreads();
    for (int i = tid; i < pc; i += 256) {
        int2 pr = pairs[p0 + i];
        int pos = atomicAdd(&offs[pr.y - nb0], 1);
        csr_src[cb + pos] = pr.x;
    }
}

// ---------------- Linear1 + ReLU + fused row-norm ----------------

__global__ __launch_bounds__(256) void k_linear1(const float* __restrict__ x,
                                                 const float* __restrict__ W1,
                                                 const float* __restrict__ b1,
                                                 float* __restrict__ h1,
                                                 float* __restrict__ rn1, int n) {
    __shared__ float W1s[INC * HID];   // 32 KB
    __shared__ float xs[4][INC];       // 2 KB
    __shared__ float b1s[HID];
    int tid = threadIdx.x;
    for (int i = tid; i < INC * HID; i += 256) W1s[i] = W1[i];
    if (tid < HID) b1s[tid] = b1[tid];
    __syncthreads();

    int nl = tid >> 6;
    int c  = tid & 63;
    for (int base = blockIdx.x * 4; base < n; base += gridDim.x * 4) {
        for (int i = tid; i < 4 * INC; i += 256) {
            int g = base + (i >> 7);
            xs[i >> 7][i & 127] = (g < n) ? x[(size_t)g * INC + (i & 127)] : 0.0f;
        }
        __syncthreads();
        int node = base + nl;
        if (node < n) {
            float s = b1s[c];
            #pragma unroll
            for (int k = 0; k < INC; ++k) s += xs[nl][k] * W1s[k * HID + c];
            float r = fmaxf(s, 0.0f);
            h1[(size_t)node * HID + c] = r;
            float q = r * r;
            #pragma unroll
            for (int off = 32; off >= 1; off >>= 1) q += __shfl_xor(q, off, 64);
            if (c == 0) rn1[node] = rsqrtf(fmaxf(q, 1e-24f));
        }
        __syncthreads();
    }
}

// ---------------- AGNN propagation ----------------
// one wave per dst node; half-wave (32 lanes x float2) per edge; 4 chains => 8 edges in flight

__global__ __launch_bounds__(256) void k_prop(const float* __restrict__ h,
                                              const float* __restrict__ rn,
                                              const int* __restrict__ row_ptr,
                                              const int* __restrict__ csr_src,
                                              const float* __restrict__ beta_ptr,
                                              float* __restrict__ out,
                                              float* __restrict__ rn_out, int n) {
    int node = blockIdx.x * 4 + (threadIdx.x >> 6);
    if (node >= n) return;
    int lane = threadIdx.x & 63;
    int half = lane >> 5;
    int hl   = lane & 31;
    float beta = beta_ptr ? beta_ptr[0] : 1.0f;

    const float2* h2 = (const float2*)h;
    float2 hd = h2[(size_t)node * 32 + hl];
    float brnd = beta * rn[node];
    int s0 = row_ptr[node], s1 = row_ptr[node + 1];

    float2 acc0 = {0.f, 0.f}, acc1 = {0.f, 0.f}, acc2 = {0.f, 0.f}, acc3 = {0.f, 0.f};
    float den0 = 0.f, den1 = 0.f, den2 = 0.f, den3 = 0.f;

    int j = s0;
    for (; j + 7 < s1; j += 8) {
        int i0 = csr_src[j +     half];
        int i1 = csr_src[j + 2 + half];
        int i2 = csr_src[j + 4 + half];
        int i3 = csr_src[j + 6 + half];
        float2 a0 = h2[(size_t)i0 * 32 + hl];
        float2 a1 = h2[(size_t)i1 * 32 + hl];
        float2 a2 = h2[(size_t)i2 * 32 + hl];
        float2 a3 = h2[(size_t)i3 * 32 + hl];
        float r0 = rn[i0], r1 = rn[i1], r2 = rn[i2], r3 = rn[i3];
        float d0 = a0.x * hd.x + a0.y * hd.y;
        float d1 = a1.x * hd.x + a1.y * hd.y;
        float d2 = a2.x * hd.x + a2.y * hd.y;
        float d3 = a3.x * hd.x + a3.y * hd.y;
        #pragma unroll
        for (int off = 16; off >= 1; off >>= 1) {
            d0 += __shfl_xor(d0, off, 64);
            d1 += __shfl_xor(d1, off, 64);
            d2 += __shfl_xor(d2, off, 64);
            d3 += __shfl_xor(d3, off, 64);
        }
        float e0 = __expf(brnd * r0 * d0);
        float e1 = __expf(brnd * r1 * d1);
        float e2 = __expf(brnd * r2 * d2);
        float e3 = __expf(brnd * r3 * d3);
        den0 += e0; acc0.x += e0 * a0.x; acc0.y += e0 * a0.y;
        den1 += e1; acc1.x += e1 * a1.x; acc1.y += e1 * a1.y;
        den2 += e2; acc2.x += e2 * a2.x; acc2.y += e2 * a2.y;
        den3 += e3; acc3.x += e3 * a3.x; acc3.y += e3 * a3.y;
    }
    for (; j < s1; j += 2) {
        int idx = j + half;
        bool act = idx < s1;
        int is = act ? csr_src[idx] : csr_src[s0];
        float2 a = h2[(size_t)is * 32 + hl];
        float rs = rn[is];
        float d = a.x * hd.x + a.y * hd.y;
        #pragma unroll
        for (int off = 16; off >= 1; off >>= 1) d += __shfl_xor(d, off, 64);
        float e = act ? __expf(brnd * rs * d) : 0.0f;
        den0 += e; acc0.x += e * a.x; acc0.y += e * a.y;
    }
    float ax = (acc0.x + acc1.x) + (acc2.x + acc3.x);
    float ay = (acc0.y + acc1.y) + (acc2.y + acc3.y);
    float dn = (den0 + den1) + (den2 + den3);
    ax += __shfl_xor(ax, 32, 64);
    ay += __shfl_xor(ay, 32, 64);
    dn += __shfl_xor(dn, 32, 64);
    float ox = ax / dn, oy = ay / dn;
    if (half == 0) ((float2*)out)[(size_t)node * 32 + hl] = make_float2(ox, oy);
    float q = ox * ox + oy * oy;
    #pragma unroll
    for (int off = 16; off >= 1; off >>= 1) q += __shfl_xor(q, off, 64);
    if (lane == 0) rn_out[node] = rsqrtf(fmaxf(q, 1e-24f));
}

// ---------------- Linear2 + log_softmax ----------------

__global__ __launch_bounds__(256) void k_out(const float* __restrict__ h,
                                             const float* __restrict__ W2,
                                             const float* __restrict__ b2,
                                             float* __restrict__ out, int n) {
    __shared__ float W2s[HID * OUTC];  // 10 KB
    __shared__ float b2s[OUTC];
    int tid = threadIdx.x;
    for (int i = tid; i < HID * OUTC; i += 256) W2s[i] = W2[i];
    if (tid < OUTC) b2s[tid] = b2[tid];
    __syncthreads();

    int node = blockIdx.x * 4 + (tid >> 6);
    if (node >= n) return;
    int lane = tid & 63;

    float logit = -INFINITY;
    if (lane < OUTC) {
        float s = b2s[lane];
        #pragma unroll
        for (int k = 0; k < HID; ++k) s += h[(size_t)node * HID + k] * W2s[k * OUTC + lane];
        logit = s;
    }
    float m = logit;
    #pragma unroll
    for (int off = 32; off >= 1; off >>= 1) m = fmaxf(m, __shfl_xor(m, off, 64));
    float z = (lane < OUTC) ? __expf(logit - m) : 0.0f;
    #pragma unroll
    for (int off = 32; off >= 1; off >>= 1) z += __shfl_xor(z, off, 64);
    if (lane < OUTC) out[(size_t)node * OUTC + lane] = logit - m - __logf(z);
}

// ---------------- launch ----------------

extern "C" void kernel_launch(void* const* d_in, const int* in_sizes, int n_in,
                              void* d_out, int out_size, void* d_ws, size_t ws_size,
                              hipStream_t stream) {
    const float* x   = (const float*)d_in[0];
    const int*   ei  = (const int*)d_in[1];
    const float* W1  = (const float*)d_in[2];
    const float* b1  = (const float*)d_in[3];
    const float* W2  = (const float*)d_in[4];
    const float* b2  = (const float*)d_in[5];
    const float* beta2 = (const float*)d_in[6];
    float* out = (float*)d_out;

    const int n = in_sizes[0] / INC;       // 100000
    const int E = in_sizes[1] / 2;         // 1600000
    const int M = E + n;
    const int nbuck = (n + (1 << SHIFT) - 1) >> SHIFT;   // 196

    // workspace layout
    char* p = (char*)d_ws;
    float* h1  = (float*)p;            p += (size_t)n * HID * 4;
    float* h2  = (float*)p;            p += (size_t)n * HID * 4;
    float* rn1 = (float*)p;            p += (size_t)n * 4;
    float* rn2 = (float*)p;            p += (size_t)n * 4;
    int* bucket_cnt  = (int*)p;        p += MAXB * 4;
    int* pair_base   = (int*)p;        p += MAXB * 4;
    int* pair_fill   = (int*)p;        p += MAXB * 4;
    int* bucket_base = (int*)p;        p += MAXB * 4;
    int* row_ptr = (int*)p;            p += (size_t)(n + 1) * 4;
    int* csr_src = (int*)p;            p += (size_t)M * 4;
    int2* pairs = (int2*)h2;           // alias: dead before prop1 writes h2
    float* h3 = h1;                    // reuse

    // CSR build (bucketed counting sort)
    int cgrid = (E + 4095) / 4096;     // 391
    hipMemsetAsync(bucket_cnt, 0, MAXB * 4, stream);
    k_hist<<<cgrid, 256, 0, stream>>>(ei, E, bucket_cnt, nbuck);
    k_bscan<<<1, 256, 0, stream>>>(bucket_cnt, pair_base, pair_fill, bucket_base,
                                   row_ptr, n, E, nbuck);
    k_bin<<<cgrid, 256, 0, stream>>>(ei, E, pair_fill, pairs, nbuck);
    k_build<<<nbuck, 256, 0, stream>>>(pairs, pair_base, bucket_cnt, bucket_base,
                                       row_ptr, csr_src, n);

    // MLP front + props + head
    k_linear1<<<1024, 256, 0, stream>>>(x, W1, b1, h1, rn1, n);
    int pgrid = (n + 3) / 4;
    k_prop<<<pgrid, 256, 0, stream>>>(h1, rn1, row_ptr, csr_src, nullptr, h2, rn2, n);
    k_prop<<<pgrid, 256, 0, stream>>>(h2, rn2, row_ptr, csr_src, beta2, h3, rn1, n);
    k_out<<<pgrid, 256, 0, stream>>>(h3, W2, b2, out, n);
}

// Round 6
// 354.360 us; speedup vs baseline: 2.1627x; 1.0807x over previous
//
#include <hip/hip_runtime.h>
#include <math.h>

#define INC 128
#define HID 64
#define OUTC 40
#define SHIFT 9
#define MAXB 256
#define NPB 64

// ---------------- CSR build: bucketed counting sort ----------------

__global__ __launch_bounds__(256) void k_hist(const int* __restrict__ ei, int E,
                                              int* __restrict__ bucket_cnt, int nbuck) {
    __shared__ int lh[MAXB];
    int tid = threadIdx.x;
    for (int i = tid; i < nbuck; i += 256) lh[i] = 0;
    __syncthreads();
    int base = blockIdx.x * 4096;
    int end = min(base + 4096, E);
    for (int e = base + tid; e < end; e += 256)
        atomicAdd(&lh[ei[E + e] >> SHIFT], 1);
    __syncthreads();
    for (int i = tid; i < nbuck; i += 256)
        if (lh[i]) atomicAdd(&bucket_cnt[i], lh[i]);
}

__global__ __launch_bounds__(256) void k_bscan(const int* __restrict__ bucket_cnt,
                                               int* __restrict__ pair_base,
                                               int* __restrict__ pair_fill,
                                               int* __restrict__ bucket_base,
                                               int* __restrict__ row_ptr,
                                               int n, int E, int nbuck) {
    __shared__ int tmp[MAXB];
    int tid = threadIdx.x;
    int cnt = (tid < nbuck) ? bucket_cnt[tid] : 0;
    int nb0 = tid << SHIFT;
    int nodes = (tid < nbuck) ? (min(n, nb0 + (1 << SHIFT)) - nb0) : 0;

    tmp[tid] = cnt;
    __syncthreads();
    for (int off = 1; off < 256; off <<= 1) {
        int t = (tid >= off) ? tmp[tid - off] : 0;
        __syncthreads();
        tmp[tid] += t;
        __syncthreads();
    }
    if (tid < nbuck) { int pb = tmp[tid] - cnt; pair_base[tid] = pb; pair_fill[tid] = pb; }
    __syncthreads();

    tmp[tid] = cnt + nodes;
    __syncthreads();
    for (int off = 1; off < 256; off <<= 1) {
        int t = (tid >= off) ? tmp[tid - off] : 0;
        __syncthreads();
        tmp[tid] += t;
        __syncthreads();
    }
    if (tid < nbuck) bucket_base[tid] = tmp[tid] - (cnt + nodes);
    if (tid == 0) row_ptr[n] = E + n;
}

__global__ __launch_bounds__(256) void k_bin(const int* __restrict__ ei, int E,
                                             int* __restrict__ pair_fill,
                                             int2* __restrict__ pairs, int nbuck) {
    __shared__ int lh[MAXB];
    __shared__ int lbase[MAXB];
    int tid = threadIdx.x;
    for (int i = tid; i < nbuck; i += 256) lh[i] = 0;
    __syncthreads();
    int base = blockIdx.x * 4096;
    int end = min(base + 4096, E);
    for (int e = base + tid; e < end; e += 256)
        atomicAdd(&lh[ei[E + e] >> SHIFT], 1);
    __syncthreads();
    for (int i = tid; i < nbuck; i += 256)
        lbase[i] = lh[i] ? atomicAdd(&pair_fill[i], lh[i]) : 0;
    __syncthreads();
    for (int e = base + tid; e < end; e += 256) {
        int s = ei[e], d = ei[E + e];
        int pos = atomicAdd(&lbase[d >> SHIFT], 1);
        pairs[pos] = make_int2(s, d);
    }
}

__global__ __launch_bounds__(256) void k_build(const int2* __restrict__ pairs,
                                               const int* __restrict__ pair_base,
                                               const int* __restrict__ bucket_cnt,
                                               const int* __restrict__ bucket_base,
                                               int* __restrict__ row_ptr,
                                               int* __restrict__ csr_src, int n) {
    __shared__ int cnt[1 << SHIFT];
    __shared__ int offs[1 << SHIFT];
    __shared__ int stmp[256];
    int b = blockIdx.x;
    int tid = threadIdx.x;
    int nb0 = b << SHIFT;
    int W = min(n - nb0, 1 << SHIFT);
    int p0 = pair_base[b], pc = bucket_cnt[b];
    int cb = bucket_base[b];

    cnt[tid] = 0; cnt[tid + 256] = 0;
    __syncthreads();
    for (int i = tid; i < pc; i += 256)
        atomicAdd(&cnt[pairs[p0 + i].y - nb0], 1);
    __syncthreads();

    int i0 = 2 * tid, i1 = 2 * tid + 1;
    int s0 = (i0 < W) ? cnt[i0] + 1 : 0;
    int s1 = (i1 < W) ? cnt[i1] + 1 : 0;
    int ps = s0 + s1;
    stmp[tid] = ps;
    __syncthreads();
    for (int off = 1; off < 256; off <<= 1) {
        int t = (tid >= off) ? stmp[tid - off] : 0;
        __syncthreads();
        stmp[tid] += t;
        __syncthreads();
    }
    int excl = stmp[tid] - ps;
    int e0 = excl, e1 = excl + s0;
    if (i0 < W) { row_ptr[nb0 + i0] = cb + e0; offs[i0] = e0 + 1; csr_src[cb + e0] = nb0 + i0; }
    if (i1 < W) { row_ptr[nb0 + i1] = cb + e1; offs[i1] = e1 + 1; csr_src[cb + e1] = nb0 + i1; }
    __syncthreads();
    for (int i = tid; i < pc; i += 256) {
        int2 pr = pairs[p0 + i];
        int pos = atomicAdd(&offs[pr.y - nb0], 1);
        csr_src[cb + pos] = pr.x;
    }
}

// ---------------- Linear1: register-tiled 64x64 GEMM + ReLU + row-norm ----------------

__device__ inline void fma4(float4& a, float s, const float4& w) {
    a.x += s * w.x; a.y += s * w.y; a.z += s * w.z; a.w += s * w.w;
}

__global__ __launch_bounds__(256) void k_linear1(const float* __restrict__ x,
                                                 const float* __restrict__ W1,
                                                 const float* __restrict__ b1,
                                                 float* __restrict__ h1,
                                                 float* __restrict__ rn1, int n) {
    __shared__ float W1s[INC * HID];   // 32 KB  [k][c]
    __shared__ float xs[NPB * INC];    // 32 KB  [node][k] with XOR swizzle
    int tid = threadIdx.x;
    int base = blockIdx.x * NPB;

    for (int i = tid; i < INC * HID / 4; i += 256)
        ((float4*)W1s)[i] = ((const float4*)W1)[i];
    for (int i = tid; i < NPB * INC / 4; i += 256) {
        int nl = i >> 5;                 // 32 float4 per node
        int k4 = i & 31;
        int gn = base + nl;
        float4 v = (gn < n) ? ((const float4*)x)[(size_t)gn * 32 + k4]
                            : make_float4(0.f, 0.f, 0.f, 0.f);
        int swk = (k4 * 4) ^ ((nl & 7) << 2);
        *(float4*)&xs[nl * INC + swk] = v;
    }
    __syncthreads();

    int cg = tid & 15;                   // col group: cols cg*4..+3
    int ng = tid >> 4;                   // node group: nodes ng*4..+3
    int n0 = ng * 4;
    float4 acc0 = {0,0,0,0}, acc1 = {0,0,0,0}, acc2 = {0,0,0,0}, acc3 = {0,0,0,0};
    const int sw0 = ((n0 + 0) & 7) << 2;
    const int sw1 = ((n0 + 1) & 7) << 2;
    const int sw2 = ((n0 + 2) & 7) << 2;
    const int sw3 = ((n0 + 3) & 7) << 2;

    #pragma unroll 8
    for (int k = 0; k < INC; k += 4) {
        float4 w0 = *(float4*)&W1s[(k + 0) * HID + cg * 4];
        float4 w1 = *(float4*)&W1s[(k + 1) * HID + cg * 4];
        float4 w2 = *(float4*)&W1s[(k + 2) * HID + cg * 4];
        float4 w3 = *(float4*)&W1s[(k + 3) * HID + cg * 4];
        float4 x0 = *(float4*)&xs[(n0 + 0) * INC + (k ^ sw0)];
        float4 x1 = *(float4*)&xs[(n0 + 1) * INC + (k ^ sw1)];
        float4 x2 = *(float4*)&xs[(n0 + 2) * INC + (k ^ sw2)];
        float4 x3 = *(float4*)&xs[(n0 + 3) * INC + (k ^ sw3)];
        fma4(acc0, x0.x, w0); fma4(acc0, x0.y, w1); fma4(acc0, x0.z, w2); fma4(acc0, x0.w, w3);
        fma4(acc1, x1.x, w0); fma4(acc1, x1.y, w1); fma4(acc1, x1.z, w2); fma4(acc1, x1.w, w3);
        fma4(acc2, x2.x, w0); fma4(acc2, x2.y, w1); fma4(acc2, x2.z, w2); fma4(acc2, x2.w, w3);
        fma4(acc3, x3.x, w0); fma4(acc3, x3.y, w1); fma4(acc3, x3.z, w2); fma4(acc3, x3.w, w3);
    }

    float4 bb = ((const float4*)b1)[cg];
    float4 r[4] = {acc0, acc1, acc2, acc3};
    #pragma unroll
    for (int nl = 0; nl < 4; ++nl) {
        int node = base + n0 + nl;
        float4 v = r[nl];
        v.x = fmaxf(v.x + bb.x, 0.f); v.y = fmaxf(v.y + bb.y, 0.f);
        v.z = fmaxf(v.z + bb.z, 0.f); v.w = fmaxf(v.w + bb.w, 0.f);
        float q = v.x * v.x + v.y * v.y + v.z * v.z + v.w * v.w;
        #pragma unroll
        for (int off = 8; off >= 1; off >>= 1) q += __shfl_xor(q, off, 64);
        if (node < n) {
            ((float4*)h1)[(size_t)node * 16 + cg] = v;
            if (cg == 0) rn1[node] = rsqrtf(fmaxf(q, 1e-24f));
        }
    }
}

// ---------------- AGNN propagation ----------------
// one wave per dst node; half-wave (32 lanes x float2) per edge; 4 chains => 8 edges in flight

__global__ __launch_bounds__(256) void k_prop(const float* __restrict__ h,
                                              const float* __restrict__ rn,
                                              const int* __restrict__ row_ptr,
                                              const int* __restrict__ csr_src,
                                              const float* __restrict__ beta_ptr,
                                              float* __restrict__ out,
                                              float* __restrict__ rn_out, int n) {
    int node = blockIdx.x * 4 + (threadIdx.x >> 6);
    if (node >= n) return;
    int lane = threadIdx.x & 63;
    int half = lane >> 5;
    int hl   = lane & 31;
    float beta = beta_ptr ? beta_ptr[0] : 1.0f;

    const float2* h2 = (const float2*)h;
    float2 hd = h2[(size_t)node * 32 + hl];
    float brnd = beta * rn[node];
    int s0 = row_ptr[node], s1 = row_ptr[node + 1];

    float2 acc0 = {0.f, 0.f}, acc1 = {0.f, 0.f}, acc2 = {0.f, 0.f}, acc3 = {0.f, 0.f};
    float den0 = 0.f, den1 = 0.f, den2 = 0.f, den3 = 0.f;

    int j = s0;
    for (; j + 7 < s1; j += 8) {
        int i0 = csr_src[j +     half];
        int i1 = csr_src[j + 2 + half];
        int i2 = csr_src[j + 4 + half];
        int i3 = csr_src[j + 6 + half];
        float2 a0 = h2[(size_t)i0 * 32 + hl];
        float2 a1 = h2[(size_t)i1 * 32 + hl];
        float2 a2 = h2[(size_t)i2 * 32 + hl];
        float2 a3 = h2[(size_t)i3 * 32 + hl];
        float r0 = rn[i0], r1 = rn[i1], r2 = rn[i2], r3 = rn[i3];
        float d0 = a0.x * hd.x + a0.y * hd.y;
        float d1 = a1.x * hd.x + a1.y * hd.y;
        float d2 = a2.x * hd.x + a2.y * hd.y;
        float d3 = a3.x * hd.x + a3.y * hd.y;
        #pragma unroll
        for (int off = 16; off >= 1; off >>= 1) {
            d0 += __shfl_xor(d0, off, 64);
            d1 += __shfl_xor(d1, off, 64);
            d2 += __shfl_xor(d2, off, 64);
            d3 += __shfl_xor(d3, off, 64);
        }
        float e0 = __expf(brnd * r0 * d0);
        float e1 = __expf(brnd * r1 * d1);
        float e2 = __expf(brnd * r2 * d2);
        float e3 = __expf(brnd * r3 * d3);
        den0 += e0; acc0.x += e0 * a0.x; acc0.y += e0 * a0.y;
        den1 += e1; acc1.x += e1 * a1.x; acc1.y += e1 * a1.y;
        den2 += e2; acc2.x += e2 * a2.x; acc2.y += e2 * a2.y;
        den3 += e3; acc3.x += e3 * a3.x; acc3.y += e3 * a3.y;
    }
    for (; j < s1; j += 2) {
        int idx = j + half;
        bool act = idx < s1;
        int is = act ? csr_src[idx] : csr_src[s0];
        float2 a = h2[(size_t)is * 32 + hl];
        float rs = rn[is];
        float d = a.x * hd.x + a.y * hd.y;
        #pragma unroll
        for (int off = 16; off >= 1; off >>= 1) d += __shfl_xor(d, off, 64);
        float e = act ? __expf(brnd * rs * d) : 0.0f;
        den0 += e; acc0.x += e * a.x; acc0.y += e * a.y;
    }
    float ax = (acc0.x + acc1.x) + (acc2.x + acc3.x);
    float ay = (acc0.y + acc1.y) + (acc2.y + acc3.y);
    float dn = (den0 + den1) + (den2 + den3);
    ax += __shfl_xor(ax, 32, 64);
    ay += __shfl_xor(ay, 32, 64);
    dn += __shfl_xor(dn, 32, 64);
    float ox = ax / dn, oy = ay / dn;
    if (half == 0) ((float2*)out)[(size_t)node * 32 + hl] = make_float2(ox, oy);
    float q = ox * ox + oy * oy;
    #pragma unroll
    for (int off = 16; off >= 1; off >>= 1) q += __shfl_xor(q, off, 64);
    if (lane == 0) rn_out[node] = rsqrtf(fmaxf(q, 1e-24f));
}

// ---------------- Linear2 + log_softmax ----------------

__global__ __launch_bounds__(256) void k_out(const float* __restrict__ h,
                                             const float* __restrict__ W2,
                                             const float* __restrict__ b2,
                                             float* __restrict__ out, int n) {
    __shared__ float W2s[HID * OUTC];  // 10 KB
    __shared__ float b2s[OUTC];
    int tid = threadIdx.x;
    for (int i = tid; i < HID * OUTC; i += 256) W2s[i] = W2[i];
    if (tid < OUTC) b2s[tid] = b2[tid];
    __syncthreads();

    int node = blockIdx.x * 4 + (tid >> 6);
    if (node >= n) return;
    int lane = tid & 63;

    float logit = -INFINITY;
    if (lane < OUTC) {
        float s = b2s[lane];
        #pragma unroll
        for (int k = 0; k < HID; ++k) s += h[(size_t)node * HID + k] * W2s[k * OUTC + lane];
        logit = s;
    }
    float m = logit;
    #pragma unroll
    for (int off = 32; off >= 1; off >>= 1) m = fmaxf(m, __shfl_xor(m, off, 64));
    float z = (lane < OUTC) ? __expf(logit - m) : 0.0f;
    #pragma unroll
    for (int off = 32; off >= 1; off >>= 1) z += __shfl_xor(z, off, 64);
    if (lane < OUTC) out[(size_t)node * OUTC + lane] = logit - m - __logf(z);
}

// ---------------- launch ----------------

extern "C" void kernel_launch(void* const* d_in, const int* in_sizes, int n_in,
                              void* d_out, int out_size, void* d_ws, size_t ws_size,
                              hipStream_t stream) {
    const float* x   = (const float*)d_in[0];
    const int*   ei  = (const int*)d_in[1];
    const float* W1  = (const float*)d_in[2];
    const float* b1  = (const float*)d_in[3];
    const float* W2  = (const float*)d_in[4];
    const float* b2  = (const float*)d_in[5];
    const float* beta2 = (const float*)d_in[6];
    float* out = (float*)d_out;

    const int n = in_sizes[0] / INC;       // 100000
    const int E = in_sizes[1] / 2;         // 1600000
    const int M = E + n;
    const int nbuck = (n + (1 << SHIFT) - 1) >> SHIFT;   // 196

    // workspace layout
    char* p = (char*)d_ws;
    float* h1  = (float*)p;            p += (size_t)n * HID * 4;
    float* h2  = (float*)p;            p += (size_t)n * HID * 4;
    float* rn1 = (float*)p;            p += (size_t)n * 4;
    float* rn2 = (float*)p;            p += (size_t)n * 4;
    int* bucket_cnt  = (int*)p;        p += MAXB * 4;
    int* pair_base   = (int*)p;        p += MAXB * 4;
    int* pair_fill   = (int*)p;        p += MAXB * 4;
    int* bucket_base = (int*)p;        p += MAXB * 4;
    int* row_ptr = (int*)p;            p += (size_t)(n + 1) * 4;
    int* csr_src = (int*)p;            p += (size_t)M * 4;
    int2* pairs = (int2*)h2;           // alias: dead before prop1 writes h2
    float* h3 = h1;                    // reuse

    // CSR build (bucketed counting sort)
    int cgrid = (E + 4095) / 4096;     // 391
    hipMemsetAsync(bucket_cnt, 0, MAXB * 4, stream);
    k_hist<<<cgrid, 256, 0, stream>>>(ei, E, bucket_cnt, nbuck);
    k_bscan<<<1, 256, 0, stream>>>(bucket_cnt, pair_base, pair_fill, bucket_base,
                                   row_ptr, n, E, nbuck);
    k_bin<<<cgrid, 256, 0, stream>>>(ei, E, pair_fill, pairs, nbuck);
    k_build<<<nbuck, 256, 0, stream>>>(pairs, pair_base, bucket_cnt, bucket_base,
                                       row_ptr, csr_src, n);

    // MLP front + props + head
    k_linear1<<<(n + NPB - 1) / NPB, 256, 0, stream>>>(x, W1, b1, h1, rn1, n);
    int pgrid = (n + 3) / 4;
    k_prop<<<pgrid, 256, 0, stream>>>(h1, rn1, row_ptr, csr_src, nullptr, h2, rn2, n);
    k_prop<<<pgrid, 256, 0, stream>>>(h2, rn2, row_ptr, csr_src, beta2, h3, rn1, n);
    k_out<<<pgrid, 256, 0, stream>>>(h3, W2, b2, out, n);
}

// Round 7
// 301.616 us; speedup vs baseline: 2.5408x; 1.1749x over previous
//
#include <hip/hip_runtime.h>
#include <math.h>

#define INC 128
#define HID 64
#define OUTC 40
#define SHIFT 9
#define MAXB 256
#define NPB 64
#define ONB 96
#define LSW 41

// ---------------- CSR build: bucketed counting sort (no self loops) ----------------

__global__ __launch_bounds__(256) void k_hist(const int* __restrict__ ei, int E,
                                              int* __restrict__ bucket_cnt,
                                              int* __restrict__ blk_cnt, int nbuck) {
    __shared__ int lh[MAXB];
    int tid = threadIdx.x;
    for (int i = tid; i < nbuck; i += 256) lh[i] = 0;
    __syncthreads();
    int base = blockIdx.x * 4096;
    int end = min(base + 4096, E);
    for (int e = base + tid; e < end; e += 256)
        atomicAdd(&lh[ei[E + e] >> SHIFT], 1);
    __syncthreads();
    for (int i = tid; i < nbuck; i += 256) {
        int v = lh[i];
        blk_cnt[blockIdx.x * MAXB + i] = v;
        if (v) atomicAdd(&bucket_cnt[i], v);
    }
}

__global__ __launch_bounds__(256) void k_bscan(const int* __restrict__ bucket_cnt,
                                               int* __restrict__ pair_base,
                                               int* __restrict__ pair_fill,
                                               int* __restrict__ row_ptr,
                                               int n, int E, int nbuck) {
    __shared__ int tmp[MAXB];
    int tid = threadIdx.x;
    int cnt = (tid < nbuck) ? bucket_cnt[tid] : 0;
    tmp[tid] = cnt;
    __syncthreads();
    for (int off = 1; off < 256; off <<= 1) {
        int t = (tid >= off) ? tmp[tid - off] : 0;
        __syncthreads();
        tmp[tid] += t;
        __syncthreads();
    }
    if (tid < nbuck) { int pb = tmp[tid] - cnt; pair_base[tid] = pb; pair_fill[tid] = pb; }
    if (tid == 0) row_ptr[n] = E;
}

__global__ __launch_bounds__(256) void k_bin(const int* __restrict__ ei, int E,
                                             const int* __restrict__ blk_cnt,
                                             int* __restrict__ pair_fill,
                                             int2* __restrict__ pairs, int nbuck) {
    __shared__ int lbase[MAXB];
    int tid = threadIdx.x;
    for (int i = tid; i < nbuck; i += 256) {
        int v = blk_cnt[blockIdx.x * MAXB + i];
        lbase[i] = v ? atomicAdd(&pair_fill[i], v) : 0;
    }
    __syncthreads();
    int base = blockIdx.x * 4096;
    int end = min(base + 4096, E);
    for (int e = base + tid; e < end; e += 256) {
        int s = ei[e], d = ei[E + e];
        int pos = atomicAdd(&lbase[d >> SHIFT], 1);
        pairs[pos] = make_int2(s, d);
    }
}

__global__ __launch_bounds__(256) void k_build(const int2* __restrict__ pairs,
                                               const int* __restrict__ pair_base,
                                               const int* __restrict__ bucket_cnt,
                                               int* __restrict__ row_ptr,
                                               int* __restrict__ csr_src, int n) {
    __shared__ int cnt[1 << SHIFT];
    __shared__ int offs[1 << SHIFT];
    __shared__ int stmp[256];
    int b = blockIdx.x;
    int tid = threadIdx.x;
    int nb0 = b << SHIFT;
    int W = min(n - nb0, 1 << SHIFT);
    int p0 = pair_base[b], pc = bucket_cnt[b];

    cnt[tid] = 0; cnt[tid + 256] = 0;
    __syncthreads();
    for (int i = tid; i < pc; i += 256)
        atomicAdd(&cnt[pairs[p0 + i].y - nb0], 1);
    __syncthreads();

    int i0 = 2 * tid, i1 = 2 * tid + 1;
    int s0 = (i0 < W) ? cnt[i0] : 0;
    int s1 = (i1 < W) ? cnt[i1] : 0;
    int ps = s0 + s1;
    stmp[tid] = ps;
    __syncthreads();
    for (int off = 1; off < 256; off <<= 1) {
        int t = (tid >= off) ? stmp[tid - off] : 0;
        __syncthreads();
        stmp[tid] += t;
        __syncthreads();
    }
    int excl = stmp[tid] - ps;
    if (i0 < W) { row_ptr[nb0 + i0] = p0 + excl;      offs[i0] = excl; }
    if (i1 < W) { row_ptr[nb0 + i1] = p0 + excl + s0; offs[i1] = excl + s0; }
    __syncthreads();
    for (int i = tid; i < pc; i += 256) {
        int2 pr = pairs[p0 + i];
        int pos = atomicAdd(&offs[pr.y - nb0], 1);
        csr_src[p0 + pos] = pr.x;
    }
}

// ---------------- Linear1: register-tiled 64x64 GEMM + ReLU + row-norm ----------------

__device__ inline void fma4(float4& a, float s, const float4& w) {
    a.x += s * w.x; a.y += s * w.y; a.z += s * w.z; a.w += s * w.w;
}

__global__ __launch_bounds__(256) void k_linear1(const float* __restrict__ x,
                                                 const float* __restrict__ W1,
                                                 const float* __restrict__ b1,
                                                 float* __restrict__ h1,
                                                 float* __restrict__ rn1, int n) {
    __shared__ float W1s[INC * HID];   // 32 KB  [k][c]
    __shared__ float xs[NPB * INC];    // 32 KB  [node][k] XOR-swizzled
    int tid = threadIdx.x;
    int base = blockIdx.x * NPB;

    for (int i = tid; i < INC * HID / 4; i += 256)
        ((float4*)W1s)[i] = ((const float4*)W1)[i];
    for (int i = tid; i < NPB * INC / 4; i += 256) {
        int nl = i >> 5;                 // 32 float4 per node
        int k4 = i & 31;
        int gn = base + nl;
        float4 v = (gn < n) ? ((const float4*)x)[(size_t)gn * 32 + k4]
                            : make_float4(0.f, 0.f, 0.f, 0.f);
        int swk = (k4 * 4) ^ (((nl >> 2) & 7) << 2);
        *(float4*)&xs[nl * INC + swk] = v;
    }
    __syncthreads();

    int cg = tid & 15;                   // cols cg*4..+3
    int ng = tid >> 4;                   // nodes ng*4..+3
    int n0 = ng * 4;
    const int sw = ((ng & 7) << 2);      // same key for all 4 rows of this thread
    float4 acc0 = {0,0,0,0}, acc1 = {0,0,0,0}, acc2 = {0,0,0,0}, acc3 = {0,0,0,0};

    #pragma unroll 8
    for (int k = 0; k < INC; k += 4) {
        float4 w0 = *(float4*)&W1s[(k + 0) * HID + cg * 4];
        float4 w1 = *(float4*)&W1s[(k + 1) * HID + cg * 4];
        float4 w2 = *(float4*)&W1s[(k + 2) * HID + cg * 4];
        float4 w3 = *(float4*)&W1s[(k + 3) * HID + cg * 4];
        float4 x0 = *(float4*)&xs[(n0 + 0) * INC + (k ^ sw)];
        float4 x1 = *(float4*)&xs[(n0 + 1) * INC + (k ^ sw)];
        float4 x2 = *(float4*)&xs[(n0 + 2) * INC + (k ^ sw)];
        float4 x3 = *(float4*)&xs[(n0 + 3) * INC + (k ^ sw)];
        fma4(acc0, x0.x, w0); fma4(acc0, x0.y, w1); fma4(acc0, x0.z, w2); fma4(acc0, x0.w, w3);
        fma4(acc1, x1.x, w0); fma4(acc1, x1.y, w1); fma4(acc1, x1.z, w2); fma4(acc1, x1.w, w3);
        fma4(acc2, x2.x, w0); fma4(acc2, x2.y, w1); fma4(acc2, x2.z, w2); fma4(acc2, x2.w, w3);
        fma4(acc3, x3.x, w0); fma4(acc3, x3.y, w1); fma4(acc3, x3.z, w2); fma4(acc3, x3.w, w3);
    }

    float4 bb = ((const float4*)b1)[cg];
    float4 r[4] = {acc0, acc1, acc2, acc3};
    #pragma unroll
    for (int nl = 0; nl < 4; ++nl) {
        int node = base + n0 + nl;
        float4 v = r[nl];
        v.x = fmaxf(v.x + bb.x, 0.f); v.y = fmaxf(v.y + bb.y, 0.f);
        v.z = fmaxf(v.z + bb.z, 0.f); v.w = fmaxf(v.w + bb.w, 0.f);
        float q = v.x * v.x + v.y * v.y + v.z * v.z + v.w * v.w;
        #pragma unroll
        for (int off = 8; off >= 1; off >>= 1) q += __shfl_xor(q, off, 64);
        if (node < n) {
            ((float4*)h1)[(size_t)node * 16 + cg] = v;
            if (cg == 0) rn1[node] = rsqrtf(fmaxf(q, 1e-24f));
        }
    }
}

// ---------------- AGNN propagation ----------------
// one wave per dst node; quarter-wave (16 lanes x float4) per edge; 4 chains => 16 edges in flight
// self-loop handled analytically: cos(h,h)=1 => e_self = exp(beta) (1 for zero rows)

__global__ __launch_bounds__(256) void k_prop(const float* __restrict__ h,
                                              const float* __restrict__ rn,
                                              const int* __restrict__ row_ptr,
                                              const int* __restrict__ csr_src,
                                              const float* __restrict__ beta_ptr,
                                              float* __restrict__ out,
                                              float* __restrict__ rn_out, int n) {
    int node = blockIdx.x * 4 + (threadIdx.x >> 6);
    if (node >= n) return;
    int lane = threadIdx.x & 63;
    int q  = lane >> 4;        // quarter 0..3
    int ql = lane & 15;        // lane in quarter: col chunk ql*4..+3
    float beta = beta_ptr ? beta_ptr[0] : 1.0f;

    const float4* h4 = (const float4*)h;
    float4 hd = h4[(size_t)node * 16 + ql];
    float rnd = rn[node];
    float brnd = beta * rnd;
    int s0 = row_ptr[node], s1 = row_ptr[node + 1];

    // self contribution, once (quarter 0 only)
    float eself = (q == 0) ? ((rnd < 1e11f) ? __expf(beta) : 1.0f) : 0.0f;
    float4 acc0 = {eself * hd.x, eself * hd.y, eself * hd.z, eself * hd.w};
    float4 acc1 = {0,0,0,0}, acc2 = {0,0,0,0}, acc3 = {0,0,0,0};
    float den0 = eself, den1 = 0.f, den2 = 0.f, den3 = 0.f;

    for (int j = s0; j < s1; j += 16) {
        int p0 = j + q, p1 = j + 4 + q, p2 = j + 8 + q, p3 = j + 12 + q;
        bool a0v = p0 < s1, a1v = p1 < s1, a2v = p2 < s1, a3v = p3 < s1;
        int i0 = a0v ? csr_src[p0] : 0;
        int i1 = a1v ? csr_src[p1] : 0;
        int i2 = a2v ? csr_src[p2] : 0;
        int i3 = a3v ? csr_src[p3] : 0;
        float4 a0 = h4[(size_t)i0 * 16 + ql];
        float4 a1 = h4[(size_t)i1 * 16 + ql];
        float4 a2 = h4[(size_t)i2 * 16 + ql];
        float4 a3 = h4[(size_t)i3 * 16 + ql];
        float r0 = rn[i0], r1 = rn[i1], r2 = rn[i2], r3 = rn[i3];
        float d0 = a0.x * hd.x + a0.y * hd.y + a0.z * hd.z + a0.w * hd.w;
        float d1 = a1.x * hd.x + a1.y * hd.y + a1.z * hd.z + a1.w * hd.w;
        float d2 = a2.x * hd.x + a2.y * hd.y + a2.z * hd.z + a2.w * hd.w;
        float d3 = a3.x * hd.x + a3.y * hd.y + a3.z * hd.z + a3.w * hd.w;
        #pragma unroll
        for (int off = 8; off >= 1; off >>= 1) {
            d0 += __shfl_xor(d0, off, 64);
            d1 += __shfl_xor(d1, off, 64);
            d2 += __shfl_xor(d2, off, 64);
            d3 += __shfl_xor(d3, off, 64);
        }
        float e0 = a0v ? __expf(brnd * r0 * d0) : 0.f;
        float e1 = a1v ? __expf(brnd * r1 * d1) : 0.f;
        float e2 = a2v ? __expf(brnd * r2 * d2) : 0.f;
        float e3 = a3v ? __expf(brnd * r3 * d3) : 0.f;
        den0 += e0; fma4(acc0, e0, a0);
        den1 += e1; fma4(acc1, e1, a1);
        den2 += e2; fma4(acc2, e2, a2);
        den3 += e3; fma4(acc3, e3, a3);
    }

    float4 acc = {(acc0.x + acc1.x) + (acc2.x + acc3.x),
                  (acc0.y + acc1.y) + (acc2.y + acc3.y),
                  (acc0.z + acc1.z) + (acc2.z + acc3.z),
                  (acc0.w + acc1.w) + (acc2.w + acc3.w)};
    float den = (den0 + den1) + (den2 + den3);
    #pragma unroll
    for (int off = 16; off <= 32; off <<= 1) {
        acc.x += __shfl_xor(acc.x, off, 64);
        acc.y += __shfl_xor(acc.y, off, 64);
        acc.z += __shfl_xor(acc.z, off, 64);
        acc.w += __shfl_xor(acc.w, off, 64);
        den   += __shfl_xor(den, off, 64);
    }
    float inv = 1.0f / den;
    float4 o = {acc.x * inv, acc.y * inv, acc.z * inv, acc.w * inv};
    if (q == 0) ((float4*)out)[(size_t)node * 16 + ql] = o;
    float qq = o.x * o.x + o.y * o.y + o.z * o.z + o.w * o.w;
    #pragma unroll
    for (int off = 8; off >= 1; off >>= 1) qq += __shfl_xor(qq, off, 64);
    if (lane == 0) rn_out[node] = rsqrtf(fmaxf(qq, 1e-24f));
}

// ---------------- Linear2 + log_softmax: register-tiled ----------------

__global__ __launch_bounds__(256) void k_out(const float* __restrict__ h,
                                             const float* __restrict__ W2,
                                             const float* __restrict__ b2,
                                             float* __restrict__ out, int n) {
    __shared__ float hs[ONB * HID];     // 24 KB swizzled
    __shared__ float W2s[HID * OUTC];   // 10 KB [k][c]
    __shared__ float ls[ONB * LSW];     // logits, padded stride
    int tid = threadIdx.x;
    int base = blockIdx.x * ONB;

    for (int i = tid; i < HID * OUTC / 4; i += 256)
        ((float4*)W2s)[i] = ((const float4*)W2)[i];
    for (int i = tid; i < ONB * 16; i += 256) {
        int nl = i >> 4, k4 = i & 15;
        int gn = base + nl;
        float4 v = (gn < n) ? ((const float4*)h)[(size_t)gn * 16 + k4]
                            : make_float4(0.f, 0.f, 0.f, 0.f);
        int swk = (k4 * 4) ^ (((nl >> 2) & 7) << 2);
        *(float4*)&hs[nl * HID + swk] = v;
    }
    __syncthreads();

    if (tid < 240) {
        int ng = tid / 10, cg = tid % 10;   // 24 node groups x 10 col groups
        int n0 = ng * 4;
        const int sw = ((ng & 7) << 2);
        float4 acc0 = {0,0,0,0}, acc1 = {0,0,0,0}, acc2 = {0,0,0,0}, acc3 = {0,0,0,0};
        #pragma unroll 4
        for (int k = 0; k < HID; k += 4) {
            float4 w0 = *(float4*)&W2s[(k + 0) * OUTC + cg * 4];
            float4 w1 = *(float4*)&W2s[(k + 1) * OUTC + cg * 4];
            float4 w2 = *(float4*)&W2s[(k + 2) * OUTC + cg * 4];
            float4 w3 = *(float4*)&W2s[(k + 3) * OUTC + cg * 4];
            float4 x0 = *(float4*)&hs[(n0 + 0) * HID + (k ^ sw)];
            float4 x1 = *(float4*)&hs[(n0 + 1) * HID + (k ^ sw)];
            float4 x2 = *(float4*)&hs[(n0 + 2) * HID + (k ^ sw)];
            float4 x3 = *(float4*)&hs[(n0 + 3) * HID + (k ^ sw)];
            fma4(acc0, x0.x, w0); fma4(acc0, x0.y, w1); fma4(acc0, x0.z, w2); fma4(acc0, x0.w, w3);
            fma4(acc1, x1.x, w0); fma4(acc1, x1.y, w1); fma4(acc1, x1.z, w2); fma4(acc1, x1.w, w3);
            fma4(acc2, x2.x, w0); fma4(acc2, x2.y, w1); fma4(acc2, x2.z, w2); fma4(acc2, x2.w, w3);
            fma4(acc3, x3.x, w0); fma4(acc3, x3.y, w1); fma4(acc3, x3.z, w2); fma4(acc3, x3.w, w3);
        }
        float4 bb = ((const float4*)b2)[cg];
        float4 rr[4] = {acc0, acc1, acc2, acc3};
        #pragma unroll
        for (int i = 0; i < 4; ++i) {
            int lb = (n0 + i) * LSW + cg * 4;
            ls[lb + 0] = rr[i].x + bb.x;
            ls[lb + 1] = rr[i].y + bb.y;
            ls[lb + 2] = rr[i].z + bb.z;
            ls[lb + 3] = rr[i].w + bb.w;
        }
    }
    __syncthreads();

    if (tid < ONB) {
        int node = base + tid;
        if (node < n) {
            float m = -INFINITY;
            #pragma unroll
            for (int c = 0; c < OUTC; ++c) m = fmaxf(m, ls[tid * LSW + c]);
            float z = 0.f;
            #pragma unroll
            for (int c = 0; c < OUTC; ++c) z += __expf(ls[tid * LSW + c] - m);
            float lz = m + __logf(z);
            #pragma unroll
            for (int c = 0; c < OUTC; ++c)
                out[(size_t)node * OUTC + c] = ls[tid * LSW + c] - lz;
        }
    }
}

// ---------------- launch ----------------

extern "C" void kernel_launch(void* const* d_in, const int* in_sizes, int n_in,
                              void* d_out, int out_size, void* d_ws, size_t ws_size,
                              hipStream_t stream) {
    const float* x   = (const float*)d_in[0];
    const int*   ei  = (const int*)d_in[1];
    const float* W1  = (const float*)d_in[2];
    const float* b1  = (const float*)d_in[3];
    const float* W2  = (const float*)d_in[4];
    const float* b2  = (const float*)d_in[5];
    const float* beta2 = (const float*)d_in[6];
    float* out = (float*)d_out;

    const int n = in_sizes[0] / INC;       // 100000
    const int E = in_sizes[1] / 2;         // 1600000
    const int nbuck = (n + (1 << SHIFT) - 1) >> SHIFT;   // 196
    const int cgrid = (E + 4095) / 4096;   // 391

    // workspace layout
    char* p = (char*)d_ws;
    float* h1  = (float*)p;            p += (size_t)n * HID * 4;
    float* h2  = (float*)p;            p += (size_t)n * HID * 4;
    float* rn1 = (float*)p;            p += (size_t)n * 4;
    float* rn2 = (float*)p;            p += (size_t)n * 4;
    int* bucket_cnt  = (int*)p;        p += MAXB * 4;
    int* pair_base   = (int*)p;        p += MAXB * 4;
    int* pair_fill   = (int*)p;        p += MAXB * 4;
    int* row_ptr = (int*)p;            p += (size_t)(n + 1) * 4;
    int* csr_src = (int*)p;            p += (size_t)E * 4;
    int* blk_cnt = (int*)p;            p += (size_t)cgrid * MAXB * 4;
    int2* pairs = (int2*)h2;           // alias: dead before prop1 writes h2
    float* h3 = h1;                    // reuse

    // CSR build (bucketed counting sort, edges only)
    hipMemsetAsync(bucket_cnt, 0, MAXB * 4, stream);
    k_hist<<<cgrid, 256, 0, stream>>>(ei, E, bucket_cnt, blk_cnt, nbuck);
    k_bscan<<<1, 256, 0, stream>>>(bucket_cnt, pair_base, pair_fill, row_ptr, n, E, nbuck);
    k_bin<<<cgrid, 256, 0, stream>>>(ei, E, blk_cnt, pair_fill, pairs, nbuck);
    k_build<<<nbuck, 256, 0, stream>>>(pairs, pair_base, bucket_cnt, row_ptr, csr_src, n);

    // MLP front + props + head
    k_linear1<<<(n + NPB - 1) / NPB, 256, 0, stream>>>(x, W1, b1, h1, rn1, n);
    int pgrid = (n + 3) / 4;
    k_prop<<<pgrid, 256, 0, stream>>>(h1, rn1, row_ptr, csr_src, nullptr, h2, rn2, n);
    k_prop<<<pgrid, 256, 0, stream>>>(h2, rn2, row_ptr, csr_src, beta2, h3, rn1, n);
    k_out<<<(n + ONB - 1) / ONB, 256, 0, stream>>>(h3, W2, b2, out, n);
}

// Round 8
// 277.699 us; speedup vs baseline: 2.7597x; 1.0861x over previous
//
#include <hip/hip_runtime.h>
#include <math.h>

#define INC 128
#define HID 64
#define OUTC 40
#define SHIFT 9
#define MAXB 256
#define NPB 64
#define ONB 96
#define LSW 41

// ---------------- bf16 helpers (storage-only precision) ----------------

__device__ inline unsigned short f2bf(float f) {
    unsigned u = __builtin_bit_cast(unsigned, f);
    u += 0x7fffu + ((u >> 16) & 1u);           // RNE
    return (unsigned short)(u >> 16);
}
__device__ inline float bfround(float f) {
    unsigned u = (unsigned)f2bf(f) << 16;
    return __builtin_bit_cast(float, u);
}
__device__ inline unsigned pk2(float a, float b) {
    return (unsigned)f2bf(a) | ((unsigned)f2bf(b) << 16);
}
__device__ inline float2 unpk(unsigned u) {
    return make_float2(__builtin_bit_cast(float, u << 16),
                       __builtin_bit_cast(float, u & 0xffff0000u));
}
__device__ inline void fma4(float4& a, float s, const float4& w) {
    a.x += s * w.x; a.y += s * w.y; a.z += s * w.z; a.w += s * w.w;
}

// ---------------- CSR build: bucketed counting sort (no self loops) ----------------

__global__ __launch_bounds__(256) void k_hist(const int* __restrict__ ei, int E,
                                              int* __restrict__ bucket_cnt,
                                              int* __restrict__ blk_cnt, int nbuck) {
    __shared__ int lh[MAXB];
    int tid = threadIdx.x;
    for (int i = tid; i < nbuck; i += 256) lh[i] = 0;
    __syncthreads();
    int base = blockIdx.x * 4096;
    int end = min(base + 4096, E);
    for (int e = base + tid; e < end; e += 256)
        atomicAdd(&lh[ei[E + e] >> SHIFT], 1);
    __syncthreads();
    for (int i = tid; i < nbuck; i += 256) {
        int v = lh[i];
        blk_cnt[blockIdx.x * MAXB + i] = v;
        if (v) atomicAdd(&bucket_cnt[i], v);
    }
}

__global__ __launch_bounds__(256) void k_bscan(const int* __restrict__ bucket_cnt,
                                               int* __restrict__ pair_base,
                                               int* __restrict__ pair_fill,
                                               int* __restrict__ row_ptr,
                                               int n, int E, int nbuck) {
    __shared__ int tmp[MAXB];
    int tid = threadIdx.x;
    int cnt = (tid < nbuck) ? bucket_cnt[tid] : 0;
    tmp[tid] = cnt;
    __syncthreads();
    for (int off = 1; off < 256; off <<= 1) {
        int t = (tid >= off) ? tmp[tid - off] : 0;
        __syncthreads();
        tmp[tid] += t;
        __syncthreads();
    }
    if (tid < nbuck) { int pb = tmp[tid] - cnt; pair_base[tid] = pb; pair_fill[tid] = pb; }
    if (tid == 0) row_ptr[n] = E;
}

__global__ __launch_bounds__(256) void k_bin(const int* __restrict__ ei, int E,
                                             const int* __restrict__ blk_cnt,
                                             int* __restrict__ pair_fill,
                                             int2* __restrict__ pairs, int nbuck) {
    __shared__ int lbase[MAXB];
    int tid = threadIdx.x;
    for (int i = tid; i < nbuck; i += 256) {
        int v = blk_cnt[blockIdx.x * MAXB + i];
        lbase[i] = v ? atomicAdd(&pair_fill[i], v) : 0;
    }
    __syncthreads();
    int base = blockIdx.x * 4096;
    int end = min(base + 4096, E);
    for (int e = base + tid; e < end; e += 256) {
        int s = ei[e], d = ei[E + e];
        int pos = atomicAdd(&lbase[d >> SHIFT], 1);
        pairs[pos] = make_int2(s, d);
    }
}

__global__ __launch_bounds__(256) void k_build(const int2* __restrict__ pairs,
                                               const int* __restrict__ pair_base,
                                               const int* __restrict__ bucket_cnt,
                                               int* __restrict__ row_ptr,
                                               int* __restrict__ csr_src, int n) {
    __shared__ int cnt[1 << SHIFT];
    __shared__ int offs[1 << SHIFT];
    __shared__ int stmp[256];
    int b = blockIdx.x;
    int tid = threadIdx.x;
    int nb0 = b << SHIFT;
    int W = min(n - nb0, 1 << SHIFT);
    int p0 = pair_base[b], pc = bucket_cnt[b];

    cnt[tid] = 0; cnt[tid + 256] = 0;
    __syncthreads();
    for (int i = tid; i < pc; i += 256)
        atomicAdd(&cnt[pairs[p0 + i].y - nb0], 1);
    __syncthreads();

    int i0 = 2 * tid, i1 = 2 * tid + 1;
    int s0 = (i0 < W) ? cnt[i0] : 0;
    int s1 = (i1 < W) ? cnt[i1] : 0;
    int ps = s0 + s1;
    stmp[tid] = ps;
    __syncthreads();
    for (int off = 1; off < 256; off <<= 1) {
        int t = (tid >= off) ? stmp[tid - off] : 0;
        __syncthreads();
        stmp[tid] += t;
        __syncthreads();
    }
    int excl = stmp[tid] - ps;
    if (i0 < W) { row_ptr[nb0 + i0] = p0 + excl;      offs[i0] = excl; }
    if (i1 < W) { row_ptr[nb0 + i1] = p0 + excl + s0; offs[i1] = excl + s0; }
    __syncthreads();
    for (int i = tid; i < pc; i += 256) {
        int2 pr = pairs[p0 + i];
        int pos = atomicAdd(&offs[pr.y - nb0], 1);
        csr_src[p0 + pos] = pr.x;
    }
}

// ---------------- Linear1: register-tiled 64x64 GEMM + ReLU + row-norm, bf16 out ----------------

__global__ __launch_bounds__(256) void k_linear1(const float* __restrict__ x,
                                                 const float* __restrict__ W1,
                                                 const float* __restrict__ b1,
                                                 uint2* __restrict__ hb1,
                                                 float* __restrict__ rn1, int n) {
    __shared__ float W1s[INC * HID];   // 32 KB  [k][c]
    __shared__ float xs[NPB * INC];    // 32 KB  [node][k] XOR-swizzled
    int tid = threadIdx.x;
    int base = blockIdx.x * NPB;

    for (int i = tid; i < INC * HID / 4; i += 256)
        ((float4*)W1s)[i] = ((const float4*)W1)[i];
    for (int i = tid; i < NPB * INC / 4; i += 256) {
        int nl = i >> 5;
        int k4 = i & 31;
        int gn = base + nl;
        float4 v = (gn < n) ? ((const float4*)x)[(size_t)gn * 32 + k4]
                            : make_float4(0.f, 0.f, 0.f, 0.f);
        int swk = (k4 * 4) ^ (((nl >> 2) & 7) << 2);
        *(float4*)&xs[nl * INC + swk] = v;
    }
    __syncthreads();

    int cg = tid & 15;
    int ng = tid >> 4;
    int n0 = ng * 4;
    const int sw = ((ng & 7) << 2);
    float4 acc0 = {0,0,0,0}, acc1 = {0,0,0,0}, acc2 = {0,0,0,0}, acc3 = {0,0,0,0};

    #pragma unroll 8
    for (int k = 0; k < INC; k += 4) {
        float4 w0 = *(float4*)&W1s[(k + 0) * HID + cg * 4];
        float4 w1 = *(float4*)&W1s[(k + 1) * HID + cg * 4];
        float4 w2 = *(float4*)&W1s[(k + 2) * HID + cg * 4];
        float4 w3 = *(float4*)&W1s[(k + 3) * HID + cg * 4];
        float4 x0 = *(float4*)&xs[(n0 + 0) * INC + (k ^ sw)];
        float4 x1 = *(float4*)&xs[(n0 + 1) * INC + (k ^ sw)];
        float4 x2 = *(float4*)&xs[(n0 + 2) * INC + (k ^ sw)];
        float4 x3 = *(float4*)&xs[(n0 + 3) * INC + (k ^ sw)];
        fma4(acc0, x0.x, w0); fma4(acc0, x0.y, w1); fma4(acc0, x0.z, w2); fma4(acc0, x0.w, w3);
        fma4(acc1, x1.x, w0); fma4(acc1, x1.y, w1); fma4(acc1, x1.z, w2); fma4(acc1, x1.w, w3);
        fma4(acc2, x2.x, w0); fma4(acc2, x2.y, w1); fma4(acc2, x2.z, w2); fma4(acc2, x2.w, w3);
        fma4(acc3, x3.x, w0); fma4(acc3, x3.y, w1); fma4(acc3, x3.z, w2); fma4(acc3, x3.w, w3);
    }

    float4 bb = ((const float4*)b1)[cg];
    float4 r[4] = {acc0, acc1, acc2, acc3};
    #pragma unroll
    for (int nl = 0; nl < 4; ++nl) {
        int node = base + n0 + nl;
        float4 v = r[nl];
        v.x = bfround(fmaxf(v.x + bb.x, 0.f));
        v.y = bfround(fmaxf(v.y + bb.y, 0.f));
        v.z = bfround(fmaxf(v.z + bb.z, 0.f));
        v.w = bfround(fmaxf(v.w + bb.w, 0.f));
        float q = v.x * v.x + v.y * v.y + v.z * v.z + v.w * v.w;
        #pragma unroll
        for (int off = 8; off >= 1; off >>= 1) q += __shfl_xor(q, off, 64);
        if (node < n) {
            hb1[(size_t)node * 16 + cg] = make_uint2(pk2(v.x, v.y), pk2(v.z, v.w));
            if (cg == 0) rn1[node] = rsqrtf(fmaxf(q, 1e-24f));
        }
    }
}

// ---------------- AGNN propagation (bf16 features) ----------------
// one wave per dst node; quarter-wave (16 lanes x 4ch bf16) per edge; 4 chains => 16 edges in flight
// self-loop analytic: cos(h,h)=1 => e_self = exp(beta)

template<bool BFOUT>
__global__ __launch_bounds__(256) void k_prop(const uint2* __restrict__ hb,
                                              const float* __restrict__ rn,
                                              const int* __restrict__ row_ptr,
                                              const int* __restrict__ csr_src,
                                              const float* __restrict__ beta_ptr,
                                              uint2* __restrict__ outb,
                                              float4* __restrict__ outf,
                                              float* __restrict__ rn_out, int n) {
    int node = blockIdx.x * 4 + (threadIdx.x >> 6);
    if (node >= n) return;
    int lane = threadIdx.x & 63;
    int q  = lane >> 4;
    int ql = lane & 15;
    float beta = beta_ptr ? beta_ptr[0] : 1.0f;

    unsigned nbase = ((unsigned)node << 4) + ql;
    uint2 hp = hb[nbase];
    float2 h01 = unpk(hp.x), h23 = unpk(hp.y);
    float4 hd = {h01.x, h01.y, h23.x, h23.y};
    float rnd = rn[node];
    float brnd = beta * rnd;
    int s0 = row_ptr[node], s1 = row_ptr[node + 1];

    float eself = (q == 0) ? ((rnd < 1e11f) ? __expf(beta) : 1.0f) : 0.0f;
    float4 acc0 = {eself * hd.x, eself * hd.y, eself * hd.z, eself * hd.w};
    float4 acc1 = {0,0,0,0}, acc2 = {0,0,0,0}, acc3 = {0,0,0,0};
    float den0 = eself, den1 = 0.f, den2 = 0.f, den3 = 0.f;

    for (int j = s0; j < s1; j += 16) {
        int p0 = j + q, p1 = j + 4 + q, p2 = j + 8 + q, p3 = j + 12 + q;
        bool v0 = p0 < s1, v1 = p1 < s1, v2 = p2 < s1, v3 = p3 < s1;
        int i0 = v0 ? csr_src[p0] : 0;
        int i1 = v1 ? csr_src[p1] : 0;
        int i2 = v2 ? csr_src[p2] : 0;
        int i3 = v3 ? csr_src[p3] : 0;
        uint2 b0 = hb[((unsigned)i0 << 4) + ql];
        uint2 b1 = hb[((unsigned)i1 << 4) + ql];
        uint2 b2 = hb[((unsigned)i2 << 4) + ql];
        uint2 b3 = hb[((unsigned)i3 << 4) + ql];
        float r0 = rn[i0], r1 = rn[i1], r2 = rn[i2], r3 = rn[i3];
        float2 a0l = unpk(b0.x), a0h = unpk(b0.y);
        float2 a1l = unpk(b1.x), a1h = unpk(b1.y);
        float2 a2l = unpk(b2.x), a2h = unpk(b2.y);
        float2 a3l = unpk(b3.x), a3h = unpk(b3.y);
        float4 a0 = {a0l.x, a0l.y, a0h.x, a0h.y};
        float4 a1 = {a1l.x, a1l.y, a1h.x, a1h.y};
        float4 a2 = {a2l.x, a2l.y, a2h.x, a2h.y};
        float4 a3 = {a3l.x, a3l.y, a3h.x, a3h.y};
        float d0 = a0.x * hd.x + a0.y * hd.y + a0.z * hd.z + a0.w * hd.w;
        float d1 = a1.x * hd.x + a1.y * hd.y + a1.z * hd.z + a1.w * hd.w;
        float d2 = a2.x * hd.x + a2.y * hd.y + a2.z * hd.z + a2.w * hd.w;
        float d3 = a3.x * hd.x + a3.y * hd.y + a3.z * hd.z + a3.w * hd.w;
        #pragma unroll
        for (int off = 8; off >= 1; off >>= 1) {
            d0 += __shfl_xor(d0, off, 64);
            d1 += __shfl_xor(d1, off, 64);
            d2 += __shfl_xor(d2, off, 64);
            d3 += __shfl_xor(d3, off, 64);
        }
        float e0 = v0 ? __expf(brnd * r0 * d0) : 0.f;
        float e1 = v1 ? __expf(brnd * r1 * d1) : 0.f;
        float e2 = v2 ? __expf(brnd * r2 * d2) : 0.f;
        float e3 = v3 ? __expf(brnd * r3 * d3) : 0.f;
        den0 += e0; fma4(acc0, e0, a0);
        den1 += e1; fma4(acc1, e1, a1);
        den2 += e2; fma4(acc2, e2, a2);
        den3 += e3; fma4(acc3, e3, a3);
    }

    float4 acc = {(acc0.x + acc1.x) + (acc2.x + acc3.x),
                  (acc0.y + acc1.y) + (acc2.y + acc3.y),
                  (acc0.z + acc1.z) + (acc2.z + acc3.z),
                  (acc0.w + acc1.w) + (acc2.w + acc3.w)};
    float den = (den0 + den1) + (den2 + den3);
    #pragma unroll
    for (int off = 16; off <= 32; off <<= 1) {
        acc.x += __shfl_xor(acc.x, off, 64);
        acc.y += __shfl_xor(acc.y, off, 64);
        acc.z += __shfl_xor(acc.z, off, 64);
        acc.w += __shfl_xor(acc.w, off, 64);
        den   += __shfl_xor(den, off, 64);
    }
    float inv = 1.0f / den;
    float4 o = {acc.x * inv, acc.y * inv, acc.z * inv, acc.w * inv};

    if (BFOUT) {
        // round, store bf16, and compute rn from ROUNDED values for self-consistency
        float4 orr = {bfround(o.x), bfround(o.y), bfround(o.z), bfround(o.w)};
        if (q == 0) outb[nbase] = make_uint2(pk2(o.x, o.y), pk2(o.z, o.w));
        float qq = orr.x * orr.x + orr.y * orr.y + orr.z * orr.z + orr.w * orr.w;
        #pragma unroll
        for (int off = 8; off >= 1; off >>= 1) qq += __shfl_xor(qq, off, 64);
        if (lane == 0) rn_out[node] = rsqrtf(fmaxf(qq, 1e-24f));
    } else {
        if (q == 0) outf[(size_t)node * 16 + ql] = o;
    }
}

// ---------------- Linear2 + log_softmax: register-tiled ----------------

__global__ __launch_bounds__(256) void k_out(const float* __restrict__ h,
                                             const float* __restrict__ W2,
                                             const float* __restrict__ b2,
                                             float* __restrict__ out, int n) {
    __shared__ float hs[ONB * HID];     // 24 KB swizzled
    __shared__ float W2s[HID * OUTC];   // 10 KB [k][c]
    __shared__ float ls[ONB * LSW];
    int tid = threadIdx.x;
    int base = blockIdx.x * ONB;

    for (int i = tid; i < HID * OUTC / 4; i += 256)
        ((float4*)W2s)[i] = ((const float4*)W2)[i];
    for (int i = tid; i < ONB * 16; i += 256) {
        int nl = i >> 4, k4 = i & 15;
        int gn = base + nl;
        float4 v = (gn < n) ? ((const float4*)h)[(size_t)gn * 16 + k4]
                            : make_float4(0.f, 0.f, 0.f, 0.f);
        int swk = (k4 * 4) ^ (((nl >> 2) & 7) << 2);
        *(float4*)&hs[nl * HID + swk] = v;
    }
    __syncthreads();

    if (tid < 240) {
        int ng = tid / 10, cg = tid % 10;
        int n0 = ng * 4;
        const int sw = ((ng & 7) << 2);
        float4 acc0 = {0,0,0,0}, acc1 = {0,0,0,0}, acc2 = {0,0,0,0}, acc3 = {0,0,0,0};
        #pragma unroll 4
        for (int k = 0; k < HID; k += 4) {
            float4 w0 = *(float4*)&W2s[(k + 0) * OUTC + cg * 4];
            float4 w1 = *(float4*)&W2s[(k + 1) * OUTC + cg * 4];
            float4 w2 = *(float4*)&W2s[(k + 2) * OUTC + cg * 4];
            float4 w3 = *(float4*)&W2s[(k + 3) * OUTC + cg * 4];
            float4 x0 = *(float4*)&hs[(n0 + 0) * HID + (k ^ sw)];
            float4 x1 = *(float4*)&hs[(n0 + 1) * HID + (k ^ sw)];
            float4 x2 = *(float4*)&hs[(n0 + 2) * HID + (k ^ sw)];
            float4 x3 = *(float4*)&hs[(n0 + 3) * HID + (k ^ sw)];
            fma4(acc0, x0.x, w0); fma4(acc0, x0.y, w1); fma4(acc0, x0.z, w2); fma4(acc0, x0.w, w3);
            fma4(acc1, x1.x, w0); fma4(acc1, x1.y, w1); fma4(acc1, x1.z, w2); fma4(acc1, x1.w, w3);
            fma4(acc2, x2.x, w0); fma4(acc2, x2.y, w1); fma4(acc2, x2.z, w2); fma4(acc2, x2.w, w3);
            fma4(acc3, x3.x, w0); fma4(acc3, x3.y, w1); fma4(acc3, x3.z, w2); fma4(acc3, x3.w, w3);
        }
        float4 bb = ((const float4*)b2)[cg];
        float4 rr[4] = {acc0, acc1, acc2, acc3};
        #pragma unroll
        for (int i = 0; i < 4; ++i) {
            int lb = (n0 + i) * LSW + cg * 4;
            ls[lb + 0] = rr[i].x + bb.x;
            ls[lb + 1] = rr[i].y + bb.y;
            ls[lb + 2] = rr[i].z + bb.z;
            ls[lb + 3] = rr[i].w + bb.w;
        }
    }
    __syncthreads();

    if (tid < ONB) {
        int node = base + tid;
        if (node < n) {
            float m = -INFINITY;
            #pragma unroll
            for (int c = 0; c < OUTC; ++c) m = fmaxf(m, ls[tid * LSW + c]);
            float z = 0.f;
            #pragma unroll
            for (int c = 0; c < OUTC; ++c) z += __expf(ls[tid * LSW + c] - m);
            float lz = m + __logf(z);
            #pragma unroll
            for (int c = 0; c < OUTC; ++c)
                out[(size_t)node * OUTC + c] = ls[tid * LSW + c] - lz;
        }
    }
}

// ---------------- launch ----------------

extern "C" void kernel_launch(void* const* d_in, const int* in_sizes, int n_in,
                              void* d_out, int out_size, void* d_ws, size_t ws_size,
                              hipStream_t stream) {
    const float* x   = (const float*)d_in[0];
    const int*   ei  = (const int*)d_in[1];
    const float* W1  = (const float*)d_in[2];
    const float* b1  = (const float*)d_in[3];
    const float* W2  = (const float*)d_in[4];
    const float* b2  = (const float*)d_in[5];
    const float* beta2 = (const float*)d_in[6];
    float* out = (float*)d_out;

    const int n = in_sizes[0] / INC;       // 100000
    const int E = in_sizes[1] / 2;         // 1600000
    const int nbuck = (n + (1 << SHIFT) - 1) >> SHIFT;   // 196
    const int cgrid = (E + 4095) / 4096;   // 391

    // workspace layout
    char* p = (char*)d_ws;
    uint2* hb1 = (uint2*)p;            p += (size_t)n * 16 * 8;   // 12.8 MB bf16
    uint2* hb2 = (uint2*)p;            p += (size_t)n * 16 * 8;   // 12.8 MB bf16
    float* h3  = (float*)p;            p += (size_t)n * HID * 4;  // 25.6 MB fp32
    float* rn1 = (float*)p;            p += (size_t)n * 4;
    float* rn2 = (float*)p;            p += (size_t)n * 4;
    int* bucket_cnt  = (int*)p;        p += MAXB * 4;
    int* pair_base   = (int*)p;        p += MAXB * 4;
    int* pair_fill   = (int*)p;        p += MAXB * 4;
    int* row_ptr = (int*)p;            p += (size_t)(n + 1) * 4;
    int* csr_src = (int*)p;            p += (size_t)E * 4;
    int* blk_cnt = (int*)p;            p += (size_t)cgrid * MAXB * 4;
    int2* pairs = (int2*)h3;           // alias: pairs dead before prop2 writes h3

    // CSR build (bucketed counting sort, edges only)
    hipMemsetAsync(bucket_cnt, 0, MAXB * 4, stream);
    k_hist<<<cgrid, 256, 0, stream>>>(ei, E, bucket_cnt, blk_cnt, nbuck);
    k_bscan<<<1, 256, 0, stream>>>(bucket_cnt, pair_base, pair_fill, row_ptr, n, E, nbuck);
    k_bin<<<cgrid, 256, 0, stream>>>(ei, E, blk_cnt, pair_fill, pairs, nbuck);
    k_build<<<nbuck, 256, 0, stream>>>(pairs, pair_base, bucket_cnt, row_ptr, csr_src, n);

    // MLP front + props + head
    k_linear1<<<(n + NPB - 1) / NPB, 256, 0, stream>>>(x, W1, b1, hb1, rn1, n);
    int pgrid = (n + 3) / 4;
    k_prop<true><<<pgrid, 256, 0, stream>>>(hb1, rn1, row_ptr, csr_src, nullptr,
                                            hb2, nullptr, rn2, n);
    k_prop<false><<<pgrid, 256, 0, stream>>>(hb2, rn2, row_ptr, csr_src, beta2,
                                             nullptr, (float4*)h3, nullptr, n);
    k_out<<<(n + ONB - 1) / ONB, 256, 0, stream>>>(h3, W2, b2, out, n);
}

// Round 9
// 251.779 us; speedup vs baseline: 3.0438x; 1.1029x over previous
//
#include <hip/hip_runtime.h>
#include <math.h>

#define INC 128
#define HID 64
#define OUTC 40
#define SHIFT 9
#define MAXB 256
#define NPB 64
#define ONB 96
#define LSW 41

typedef _Float16 half2_t __attribute__((ext_vector_type(2)));

__device__ inline void fma4(float4& a, float s, const float4& w) {
    a.x += s * w.x; a.y += s * w.y; a.z += s * w.z; a.w += s * w.w;
}
__device__ inline unsigned pkh(float a, float b) {
    unsigned short ua = __builtin_bit_cast(unsigned short, (_Float16)a);
    unsigned short ub = __builtin_bit_cast(unsigned short, (_Float16)b);
    return (unsigned)ua | ((unsigned)ub << 16);
}
__device__ inline float dot4(const uint4& a, const uint4& b) {
#if __has_builtin(__builtin_amdgcn_fdot2)
    float d = __builtin_amdgcn_fdot2(__builtin_bit_cast(half2_t, a.x),
                                     __builtin_bit_cast(half2_t, b.x), 0.f, false);
    d = __builtin_amdgcn_fdot2(__builtin_bit_cast(half2_t, a.y),
                               __builtin_bit_cast(half2_t, b.y), d, false);
    d = __builtin_amdgcn_fdot2(__builtin_bit_cast(half2_t, a.z),
                               __builtin_bit_cast(half2_t, b.z), d, false);
    d = __builtin_amdgcn_fdot2(__builtin_bit_cast(half2_t, a.w),
                               __builtin_bit_cast(half2_t, b.w), d, false);
    return d;
#else
    float d = 0.f;
    const unsigned* pa = &a.x; const unsigned* pb = &b.x;
    #pragma unroll
    for (int i = 0; i < 4; ++i) {
        half2_t ha = __builtin_bit_cast(half2_t, pa[i]);
        half2_t hb = __builtin_bit_cast(half2_t, pb[i]);
        d = fmaf((float)ha[0], (float)hb[0], d);
        d = fmaf((float)ha[1], (float)hb[1], d);
    }
    return d;
#endif
}
__device__ inline void accum8(float* acc, float s, const uint4& a) {
    half2_t p;
    p = __builtin_bit_cast(half2_t, a.x); acc[0] += s * (float)p[0]; acc[1] += s * (float)p[1];
    p = __builtin_bit_cast(half2_t, a.y); acc[2] += s * (float)p[0]; acc[3] += s * (float)p[1];
    p = __builtin_bit_cast(half2_t, a.z); acc[4] += s * (float)p[0]; acc[5] += s * (float)p[1];
    p = __builtin_bit_cast(half2_t, a.w); acc[6] += s * (float)p[0]; acc[7] += s * (float)p[1];
}
__device__ inline void unpack8(float* f, const uint4& a) {
    half2_t p;
    p = __builtin_bit_cast(half2_t, a.x); f[0] = (float)p[0]; f[1] = (float)p[1];
    p = __builtin_bit_cast(half2_t, a.y); f[2] = (float)p[0]; f[3] = (float)p[1];
    p = __builtin_bit_cast(half2_t, a.z); f[4] = (float)p[0]; f[5] = (float)p[1];
    p = __builtin_bit_cast(half2_t, a.w); f[6] = (float)p[0]; f[7] = (float)p[1];
}
#define EXP2(x) __builtin_amdgcn_exp2f(x)

// ---------------- CSR build: bucketed counting sort (no self loops) ----------------

__global__ __launch_bounds__(256) void k_hist(const int* __restrict__ ei, int E,
                                              int* __restrict__ bucket_cnt,
                                              int* __restrict__ blk_cnt, int nbuck) {
    __shared__ int lh[MAXB];
    int tid = threadIdx.x;
    for (int i = tid; i < nbuck; i += 256) lh[i] = 0;
    __syncthreads();
    int base = blockIdx.x * 4096;
    int end = min(base + 4096, E);
    for (int e = base + tid; e < end; e += 256)
        atomicAdd(&lh[ei[E + e] >> SHIFT], 1);
    __syncthreads();
    for (int i = tid; i < nbuck; i += 256) {
        int v = lh[i];
        blk_cnt[blockIdx.x * MAXB + i] = v;
        if (v) atomicAdd(&bucket_cnt[i], v);
    }
}

__global__ __launch_bounds__(256) void k_bscan(const int* __restrict__ bucket_cnt,
                                               int* __restrict__ pair_base,
                                               int* __restrict__ pair_fill,
                                               int* __restrict__ row_ptr,
                                               int n, int E, int nbuck) {
    __shared__ int tmp[MAXB];
    int tid = threadIdx.x;
    int cnt = (tid < nbuck) ? bucket_cnt[tid] : 0;
    tmp[tid] = cnt;
    __syncthreads();
    for (int off = 1; off < 256; off <<= 1) {
        int t = (tid >= off) ? tmp[tid - off] : 0;
        __syncthreads();
        tmp[tid] += t;
        __syncthreads();
    }
    if (tid < nbuck) { int pb = tmp[tid] - cnt; pair_base[tid] = pb; pair_fill[tid] = pb; }
    if (tid == 0) row_ptr[n] = E;
}

__global__ __launch_bounds__(256) void k_bin(const int* __restrict__ ei, int E,
                                             const int* __restrict__ blk_cnt,
                                             int* __restrict__ pair_fill,
                                             int2* __restrict__ pairs, int nbuck) {
    __shared__ int lbase[MAXB];
    int tid = threadIdx.x;
    for (int i = tid; i < nbuck; i += 256) {
        int v = blk_cnt[blockIdx.x * MAXB + i];
        lbase[i] = v ? atomicAdd(&pair_fill[i], v) : 0;
    }
    __syncthreads();
    int base = blockIdx.x * 4096;
    int end = min(base + 4096, E);
    for (int e = base + tid; e < end; e += 256) {
        int s = ei[e], d = ei[E + e];
        int pos = atomicAdd(&lbase[d >> SHIFT], 1);
        pairs[pos] = make_int2(s, d);
    }
}

__global__ __launch_bounds__(256) void k_build(const int2* __restrict__ pairs,
                                               const int* __restrict__ pair_base,
                                               const int* __restrict__ bucket_cnt,
                                               int* __restrict__ row_ptr,
                                               int* __restrict__ csr_src, int n) {
    __shared__ int cnt[1 << SHIFT];
    __shared__ int offs[1 << SHIFT];
    __shared__ int stmp[256];
    int b = blockIdx.x;
    int tid = threadIdx.x;
    int nb0 = b << SHIFT;
    int W = min(n - nb0, 1 << SHIFT);
    int p0 = pair_base[b], pc = bucket_cnt[b];

    cnt[tid] = 0; cnt[tid + 256] = 0;
    __syncthreads();
    for (int i = tid; i < pc; i += 256)
        atomicAdd(&cnt[pairs[p0 + i].y - nb0], 1);
    __syncthreads();

    int i0 = 2 * tid, i1 = 2 * tid + 1;
    int s0 = (i0 < W) ? cnt[i0] : 0;
    int s1 = (i1 < W) ? cnt[i1] : 0;
    int ps = s0 + s1;
    stmp[tid] = ps;
    __syncthreads();
    for (int off = 1; off < 256; off <<= 1) {
        int t = (tid >= off) ? stmp[tid - off] : 0;
        __syncthreads();
        stmp[tid] += t;
        __syncthreads();
    }
    int excl = stmp[tid] - ps;
    if (i0 < W) { row_ptr[nb0 + i0] = p0 + excl;      offs[i0] = excl; }
    if (i1 < W) { row_ptr[nb0 + i1] = p0 + excl + s0; offs[i1] = excl + s0; }
    __syncthreads();
    for (int i = tid; i < pc; i += 256) {
        int2 pr = pairs[p0 + i];
        int pos = atomicAdd(&offs[pr.y - nb0], 1);
        csr_src[p0 + pos] = pr.x;
    }
}

// ---------------- Linear1: register-tiled GEMM + ReLU + normalize, fp16 out ----------------

__global__ __launch_bounds__(256) void k_linear1(const float* __restrict__ x,
                                                 const float* __restrict__ W1,
                                                 const float* __restrict__ b1,
                                                 uint2* __restrict__ X1,
                                                 float* __restrict__ nrm1, int n) {
    __shared__ float W1s[INC * HID];   // 32 KB  [k][c]
    __shared__ float xs[NPB * INC];    // 32 KB  [node][k] XOR-swizzled
    int tid = threadIdx.x;
    int base = blockIdx.x * NPB;

    for (int i = tid; i < INC * HID / 4; i += 256)
        ((float4*)W1s)[i] = ((const float4*)W1)[i];
    for (int i = tid; i < NPB * INC / 4; i += 256) {
        int nl = i >> 5;
        int k4 = i & 31;
        int gn = base + nl;
        float4 v = (gn < n) ? ((const float4*)x)[(size_t)gn * 32 + k4]
                            : make_float4(0.f, 0.f, 0.f, 0.f);
        int swk = (k4 * 4) ^ (((nl >> 2) & 7) << 2);
        *(float4*)&xs[nl * INC + swk] = v;
    }
    __syncthreads();

    int cg = tid & 15;
    int ng = tid >> 4;
    int n0 = ng * 4;
    const int sw = ((ng & 7) << 2);
    float4 acc0 = {0,0,0,0}, acc1 = {0,0,0,0}, acc2 = {0,0,0,0}, acc3 = {0,0,0,0};

    #pragma unroll 8
    for (int k = 0; k < INC; k += 4) {
        float4 w0 = *(float4*)&W1s[(k + 0) * HID + cg * 4];
        float4 w1 = *(float4*)&W1s[(k + 1) * HID + cg * 4];
        float4 w2 = *(float4*)&W1s[(k + 2) * HID + cg * 4];
        float4 w3 = *(float4*)&W1s[(k + 3) * HID + cg * 4];
        float4 x0 = *(float4*)&xs[(n0 + 0) * INC + (k ^ sw)];
        float4 x1 = *(float4*)&xs[(n0 + 1) * INC + (k ^ sw)];
        float4 x2 = *(float4*)&xs[(n0 + 2) * INC + (k ^ sw)];
        float4 x3 = *(float4*)&xs[(n0 + 3) * INC + (k ^ sw)];
        fma4(acc0, x0.x, w0); fma4(acc0, x0.y, w1); fma4(acc0, x0.z, w2); fma4(acc0, x0.w, w3);
        fma4(acc1, x1.x, w0); fma4(acc1, x1.y, w1); fma4(acc1, x1.z, w2); fma4(acc1, x1.w, w3);
        fma4(acc2, x2.x, w0); fma4(acc2, x2.y, w1); fma4(acc2, x2.z, w2); fma4(acc2, x2.w, w3);
        fma4(acc3, x3.x, w0); fma4(acc3, x3.y, w1); fma4(acc3, x3.z, w2); fma4(acc3, x3.w, w3);
    }

    float4 bb = ((const float4*)b1)[cg];
    float4 r[4] = {acc0, acc1, acc2, acc3};
    #pragma unroll
    for (int nl = 0; nl < 4; ++nl) {
        int node = base + n0 + nl;
        float4 v = r[nl];
        v.x = fmaxf(v.x + bb.x, 0.f); v.y = fmaxf(v.y + bb.y, 0.f);
        v.z = fmaxf(v.z + bb.z, 0.f); v.w = fmaxf(v.w + bb.w, 0.f);
        float q = v.x * v.x + v.y * v.y + v.z * v.z + v.w * v.w;
        #pragma unroll
        for (int off = 8; off >= 1; off >>= 1) q += __shfl_xor(q, off, 64);
        float rq = rsqrtf(fmaxf(q, 1e-24f));
        if (node < n) {
            X1[(size_t)node * 16 + cg] = make_uint2(pkh(v.x * rq, v.y * rq),
                                                    pkh(v.z * rq, v.w * rq));
            if (cg == 0) nrm1[node] = sqrtf(fmaxf(q, 1e-24f));
        }
    }
}

// ---------------- AGNN propagation (fp16 normalized features + fp32 magnitude) ----------------
// one wave per dst node; 8 lanes x 8ch per edge; 2 chains => 16 edges/iter

template<bool HFOUT>
__global__ __launch_bounds__(256) void k_prop(const uint4* __restrict__ X,
                                              const float* __restrict__ nrm,
                                              const int* __restrict__ row_ptr,
                                              const int* __restrict__ csr_src,
                                              const float* __restrict__ beta_ptr,
                                              uint4* __restrict__ Xout,
                                              float* __restrict__ nrm_out,
                                              float4* __restrict__ outf, int n) {
    int node = blockIdx.x * 4 + (threadIdx.x >> 6);
    if (node >= n) return;
    int lane = threadIdx.x & 63;
    int g = lane >> 3, gl = lane & 7;
    float beta = beta_ptr ? beta_ptr[0] : 1.0f;
    float b2 = beta * 1.4426950408889634f;   // fold log2(e): exp(x) = exp2(b2/beta*x)

    uint4 hdp = X[(size_t)node * 8 + gl];
    float hdf[8]; unpack8(hdf, hdp);
    int s0 = row_ptr[node], s1 = row_ptr[node + 1];

    // self edge via identical arithmetic (dot of stored row with itself)
    float ds = dot4(hdp, hdp);
    ds += __shfl_xor(ds, 1, 64); ds += __shfl_xor(ds, 2, 64); ds += __shfl_xor(ds, 4, 64);
    float eself = EXP2(b2 * ds);
    float nd = nrm[node];
    float den0 = (g == 0) ? eself : 0.f;
    float es = (g == 0) ? eself * nd : 0.f;
    float acc[8];
    #pragma unroll
    for (int c = 0; c < 8; ++c) acc[c] = es * hdf[c];
    float den1 = 0.f;

    for (int j = s0; j < s1; j += 16) {
        int p0 = j + g, p1 = j + 8 + g;
        bool v0 = p0 < s1, v1 = p1 < s1;
        int i0 = v0 ? csr_src[p0] : 0;
        int i1 = v1 ? csr_src[p1] : 0;
        uint4 a0 = X[(size_t)i0 * 8 + gl];
        uint4 a1 = X[(size_t)i1 * 8 + gl];
        float n0 = nrm[i0], n1 = nrm[i1];
        float d0 = dot4(a0, hdp);
        float d1 = dot4(a1, hdp);
        d0 += __shfl_xor(d0, 1, 64); d1 += __shfl_xor(d1, 1, 64);
        d0 += __shfl_xor(d0, 2, 64); d1 += __shfl_xor(d1, 2, 64);
        d0 += __shfl_xor(d0, 4, 64); d1 += __shfl_xor(d1, 4, 64);
        float e0 = v0 ? EXP2(b2 * d0) : 0.f;
        float e1 = v1 ? EXP2(b2 * d1) : 0.f;
        den0 += e0; den1 += e1;
        float sc0 = e0 * n0, sc1 = e1 * n1;
        accum8(acc, sc0, a0);
        accum8(acc, sc1, a1);
    }

    float den = den0 + den1;
    #pragma unroll
    for (int c = 0; c < 8; ++c) {
        acc[c] += __shfl_xor(acc[c], 8, 64);
        acc[c] += __shfl_xor(acc[c], 16, 64);
        acc[c] += __shfl_xor(acc[c], 32, 64);
    }
    den += __shfl_xor(den, 8, 64);
    den += __shfl_xor(den, 16, 64);
    den += __shfl_xor(den, 32, 64);
    float inv = 1.0f / den;
    float o[8];
    #pragma unroll
    for (int c = 0; c < 8; ++c) o[c] = acc[c] * inv;

    if (HFOUT) {
        float q = 0.f;
        #pragma unroll
        for (int c = 0; c < 8; ++c) q += o[c] * o[c];
        q += __shfl_xor(q, 1, 64); q += __shfl_xor(q, 2, 64); q += __shfl_xor(q, 4, 64);
        float rq = rsqrtf(fmaxf(q, 1e-24f));
        if (g == 0) {
            uint4 w;
            w.x = pkh(o[0] * rq, o[1] * rq);
            w.y = pkh(o[2] * rq, o[3] * rq);
            w.z = pkh(o[4] * rq, o[5] * rq);
            w.w = pkh(o[6] * rq, o[7] * rq);
            Xout[(size_t)node * 8 + gl] = w;
            if (gl == 0) nrm_out[node] = sqrtf(fmaxf(q, 1e-24f));
        }
    } else {
        if (g == 0) {
            outf[(size_t)node * 16 + gl * 2]     = make_float4(o[0], o[1], o[2], o[3]);
            outf[(size_t)node * 16 + gl * 2 + 1] = make_float4(o[4], o[5], o[6], o[7]);
        }
    }
}

// ---------------- Linear2 + log_softmax: register-tiled ----------------

__global__ __launch_bounds__(256) void k_out(const float* __restrict__ h,
                                             const float* __restrict__ W2,
                                             const float* __restrict__ b2,
                                             float* __restrict__ out, int n) {
    __shared__ float hs[ONB * HID];     // 24 KB swizzled
    __shared__ float W2s[HID * OUTC];   // 10 KB [k][c]
    __shared__ float ls[ONB * LSW];
    int tid = threadIdx.x;
    int base = blockIdx.x * ONB;

    for (int i = tid; i < HID * OUTC / 4; i += 256)
        ((float4*)W2s)[i] = ((const float4*)W2)[i];
    for (int i = tid; i < ONB * 16; i += 256) {
        int nl = i >> 4, k4 = i & 15;
        int gn = base + nl;
        float4 v = (gn < n) ? ((const float4*)h)[(size_t)gn * 16 + k4]
                            : make_float4(0.f, 0.f, 0.f, 0.f);
        int swk = (k4 * 4) ^ (((nl >> 2) & 7) << 2);
        *(float4*)&hs[nl * HID + swk] = v;
    }
    __syncthreads();

    if (tid < 240) {
        int ng = tid / 10, cg = tid % 10;
        int n0 = ng * 4;
        const int sw = ((ng & 7) << 2);
        float4 acc0 = {0,0,0,0}, acc1 = {0,0,0,0}, acc2 = {0,0,0,0}, acc3 = {0,0,0,0};
        #pragma unroll 4
        for (int k = 0; k < HID; k += 4) {
            float4 w0 = *(float4*)&W2s[(k + 0) * OUTC + cg * 4];
            float4 w1 = *(float4*)&W2s[(k + 1) * OUTC + cg * 4];
            float4 w2 = *(float4*)&W2s[(k + 2) * OUTC + cg * 4];
            float4 w3 = *(float4*)&W2s[(k + 3) * OUTC + cg * 4];
            float4 x0 = *(float4*)&hs[(n0 + 0) * HID + (k ^ sw)];
            float4 x1 = *(float4*)&hs[(n0 + 1) * HID + (k ^ sw)];
            float4 x2 = *(float4*)&hs[(n0 + 2) * HID + (k ^ sw)];
            float4 x3 = *(float4*)&hs[(n0 + 3) * HID + (k ^ sw)];
            fma4(acc0, x0.x, w0); fma4(acc0, x0.y, w1); fma4(acc0, x0.z, w2); fma4(acc0, x0.w, w3);
            fma4(acc1, x1.x, w0); fma4(acc1, x1.y, w1); fma4(acc1, x1.z, w2); fma4(acc1, x1.w, w3);
            fma4(acc2, x2.x, w0); fma4(acc2, x2.y, w1); fma4(acc2, x2.z, w2); fma4(acc2, x2.w, w3);
            fma4(acc3, x3.x, w0); fma4(acc3, x3.y, w1); fma4(acc3, x3.z, w2); fma4(acc3, x3.w, w3);
        }
        float4 bb = ((const float4*)b2)[cg];
        float4 rr[4] = {acc0, acc1, acc2, acc3};
        #pragma unroll
        for (int i = 0; i < 4; ++i) {
            int lb = (n0 + i) * LSW + cg * 4;
            ls[lb + 0] = rr[i].x + bb.x;
            ls[lb + 1] = rr[i].y + bb.y;
            ls[lb + 2] = rr[i].z + bb.z;
            ls[lb + 3] = rr[i].w + bb.w;
        }
    }
    __syncthreads();

    if (tid < ONB) {
        int node = base + tid;
        if (node < n) {
            float m = -INFINITY;
            #pragma unroll
            for (int c = 0; c < OUTC; ++c) m = fmaxf(m, ls[tid * LSW + c]);
            float z = 0.f;
            #pragma unroll
            for (int c = 0; c < OUTC; ++c) z += __expf(ls[tid * LSW + c] - m);
            float lz = m + __logf(z);
            #pragma unroll
            for (int c = 0; c < OUTC; ++c)
                out[(size_t)node * OUTC + c] = ls[tid * LSW + c] - lz;
        }
    }
}

// ---------------- launch ----------------

extern "C" void kernel_launch(void* const* d_in, const int* in_sizes, int n_in,
                              void* d_out, int out_size, void* d_ws, size_t ws_size,
                              hipStream_t stream) {
    const float* x   = (const float*)d_in[0];
    const int*   ei  = (const int*)d_in[1];
    const float* W1  = (const float*)d_in[2];
    const float* b1  = (const float*)d_in[3];
    const float* W2  = (const float*)d_in[4];
    const float* b2  = (const float*)d_in[5];
    const float* beta2 = (const float*)d_in[6];
    float* out = (float*)d_out;

    const int n = in_sizes[0] / INC;       // 100000
    const int E = in_sizes[1] / 2;         // 1600000
    const int nbuck = (n + (1 << SHIFT) - 1) >> SHIFT;   // 196
    const int cgrid = (E + 4095) / 4096;   // 391

    // workspace layout
    char* p = (char*)d_ws;
    uint4* X1 = (uint4*)p;             p += (size_t)n * 8 * 16;   // 12.8 MB fp16 normalized
    uint4* X2 = (uint4*)p;             p += (size_t)n * 8 * 16;   // 12.8 MB
    float* h3 = (float*)p;             p += (size_t)n * HID * 4;  // 25.6 MB fp32
    float* nrm1 = (float*)p;           p += (size_t)n * 4;
    float* nrm2 = (float*)p;           p += (size_t)n * 4;
    int* bucket_cnt  = (int*)p;        p += MAXB * 4;
    int* pair_base   = (int*)p;        p += MAXB * 4;
    int* pair_fill   = (int*)p;        p += MAXB * 4;
    int* row_ptr = (int*)p;            p += (size_t)(n + 1) * 4;
    int* csr_src = (int*)p;            p += (size_t)E * 4;
    int* blk_cnt = (int*)p;            p += (size_t)cgrid * MAXB * 4;
    int2* pairs = (int2*)h3;           // alias: pairs dead before prop2 writes h3

    // CSR build (bucketed counting sort, edges only)
    hipMemsetAsync(bucket_cnt, 0, MAXB * 4, stream);
    k_hist<<<cgrid, 256, 0, stream>>>(ei, E, bucket_cnt, blk_cnt, nbuck);
    k_bscan<<<1, 256, 0, stream>>>(bucket_cnt, pair_base, pair_fill, row_ptr, n, E, nbuck);
    k_bin<<<cgrid, 256, 0, stream>>>(ei, E, blk_cnt, pair_fill, pairs, nbuck);
    k_build<<<nbuck, 256, 0, stream>>>(pairs, pair_base, bucket_cnt, row_ptr, csr_src, n);

    // MLP front + props + head
    k_linear1<<<(n + NPB - 1) / NPB, 256, 0, stream>>>(x, W1, b1, (uint2*)X1, nrm1, n);
    int pgrid = (n + 3) / 4;
    k_prop<true><<<pgrid, 256, 0, stream>>>(X1, nrm1, row_ptr, csr_src, nullptr,
                                            X2, nrm2, nullptr, n);
    k_prop<false><<<pgrid, 256, 0, stream>>>(X2, nrm2, row_ptr, csr_src, beta2,
                                             nullptr, nullptr, (float4*)h3, n);
    k_out<<<(n + ONB - 1) / ONB, 256, 0, stream>>>(h3, W2, b2, out, n);
}

// Round 10
// 220.079 us; speedup vs baseline: 3.4822x; 1.1440x over previous
//
#include <hip/hip_runtime.h>
#include <math.h>

#define INC 128
#define HID 64
#define OUTC 40
#define SHIFT 9
#define MAXB 256
#define NPB 64
#define ONB 96
#define LSW 41

typedef _Float16 half2_t __attribute__((ext_vector_type(2)));

__device__ inline void fma4(float4& a, float s, const float4& w) {
    a.x += s * w.x; a.y += s * w.y; a.z += s * w.z; a.w += s * w.w;
}
__device__ inline unsigned pkh(float a, float b) {
    unsigned short ua = __builtin_bit_cast(unsigned short, (_Float16)a);
    unsigned short ub = __builtin_bit_cast(unsigned short, (_Float16)b);
    return (unsigned)ua | ((unsigned)ub << 16);
}
__device__ inline float fdot2_(unsigned a, unsigned b, float c) {
#if __has_builtin(__builtin_amdgcn_fdot2)
    return __builtin_amdgcn_fdot2(__builtin_bit_cast(half2_t, a),
                                  __builtin_bit_cast(half2_t, b), c, false);
#else
    half2_t ha = __builtin_bit_cast(half2_t, a);
    half2_t hb = __builtin_bit_cast(half2_t, b);
    return fmaf((float)ha[0], (float)hb[0], fmaf((float)ha[1], (float)hb[1], c));
#endif
}
__device__ inline float dot4(const uint4& a, const uint4& b) {
    float d = fdot2_(a.x, b.x, 0.f);
    d = fdot2_(a.y, b.y, d);
    d = fdot2_(a.z, b.z, d);
    d = fdot2_(a.w, b.w, d);
    return d;
}
__device__ inline void accum8(float* acc, float s, const uint4& a) {
    half2_t p;
    p = __builtin_bit_cast(half2_t, a.x); acc[0] += s * (float)p[0]; acc[1] += s * (float)p[1];
    p = __builtin_bit_cast(half2_t, a.y); acc[2] += s * (float)p[0]; acc[3] += s * (float)p[1];
    p = __builtin_bit_cast(half2_t, a.z); acc[4] += s * (float)p[0]; acc[5] += s * (float)p[1];
    p = __builtin_bit_cast(half2_t, a.w); acc[6] += s * (float)p[0]; acc[7] += s * (float)p[1];
}
__device__ inline void unpack8(float* f, const uint4& a) {
    half2_t p;
    p = __builtin_bit_cast(half2_t, a.x); f[0] = (float)p[0]; f[1] = (float)p[1];
    p = __builtin_bit_cast(half2_t, a.y); f[2] = (float)p[0]; f[3] = (float)p[1];
    p = __builtin_bit_cast(half2_t, a.z); f[4] = (float)p[0]; f[5] = (float)p[1];
    p = __builtin_bit_cast(half2_t, a.w); f[6] = (float)p[0]; f[7] = (float)p[1];
}
__device__ inline void dacc4(float4& a, unsigned xp_, const uint4& w) {
    a.x = fdot2_(xp_, w.x, a.x);
    a.y = fdot2_(xp_, w.y, a.y);
    a.z = fdot2_(xp_, w.z, a.z);
    a.w = fdot2_(xp_, w.w, a.w);
}
#define EXP2(x) __builtin_amdgcn_exp2f(x)

// ---------------- CSR build: bucketed counting sort (no self loops) ----------------

__global__ __launch_bounds__(256) void k_hist(const int* __restrict__ ei, int E,
                                              int* __restrict__ bucket_cnt,
                                              int* __restrict__ blk_cnt, int nbuck) {
    __shared__ int lh[MAXB];
    int tid = threadIdx.x;
    for (int i = tid; i < nbuck; i += 256) lh[i] = 0;
    __syncthreads();
    int base = blockIdx.x * 4096;
    int end = min(base + 4096, E);
    for (int e = base + tid; e < end; e += 256)
        atomicAdd(&lh[ei[E + e] >> SHIFT], 1);
    __syncthreads();
    for (int i = tid; i < nbuck; i += 256) {
        int v = lh[i];
        blk_cnt[blockIdx.x * MAXB + i] = v;
        if (v) atomicAdd(&bucket_cnt[i], v);
    }
}

__global__ __launch_bounds__(256) void k_bscan(const int* __restrict__ bucket_cnt,
                                               int* __restrict__ pair_base,
                                               int* __restrict__ pair_fill,
                                               int* __restrict__ row_ptr,
                                               int n, int E, int nbuck) {
    __shared__ int tmp[MAXB];
    int tid = threadIdx.x;
    int cnt = (tid < nbuck) ? bucket_cnt[tid] : 0;
    tmp[tid] = cnt;
    __syncthreads();
    for (int off = 1; off < 256; off <<= 1) {
        int t = (tid >= off) ? tmp[tid - off] : 0;
        __syncthreads();
        tmp[tid] += t;
        __syncthreads();
    }
    if (tid < nbuck) { int pb = tmp[tid] - cnt; pair_base[tid] = pb; pair_fill[tid] = pb; }
    if (tid == 0) row_ptr[n] = E;
}

__global__ __launch_bounds__(256) void k_bin(const int* __restrict__ ei, int E,
                                             const int* __restrict__ blk_cnt,
                                             int* __restrict__ pair_fill,
                                             int2* __restrict__ pairs, int nbuck) {
    __shared__ int lbase[MAXB];
    int tid = threadIdx.x;
    for (int i = tid; i < nbuck; i += 256) {
        int v = blk_cnt[blockIdx.x * MAXB + i];
        lbase[i] = v ? atomicAdd(&pair_fill[i], v) : 0;
    }
    __syncthreads();
    int base = blockIdx.x * 4096;
    int end = min(base + 4096, E);
    for (int e = base + tid; e < end; e += 256) {
        int s = ei[e], d = ei[E + e];
        int pos = atomicAdd(&lbase[d >> SHIFT], 1);
        pairs[pos] = make_int2(s, d);
    }
}

__global__ __launch_bounds__(256) void k_build(const int2* __restrict__ pairs,
                                               const int* __restrict__ pair_base,
                                               const int* __restrict__ bucket_cnt,
                                               int* __restrict__ row_ptr,
                                               int* __restrict__ csr_src, int n) {
    __shared__ int cnt[1 << SHIFT];
    __shared__ int offs[1 << SHIFT];
    __shared__ int stmp[256];
    int b = blockIdx.x;
    int tid = threadIdx.x;
    int nb0 = b << SHIFT;
    int W = min(n - nb0, 1 << SHIFT);
    int p0 = pair_base[b], pc = bucket_cnt[b];

    cnt[tid] = 0; cnt[tid + 256] = 0;
    __syncthreads();
    for (int i = tid; i < pc; i += 256)
        atomicAdd(&cnt[pairs[p0 + i].y - nb0], 1);
    __syncthreads();

    int i0 = 2 * tid, i1 = 2 * tid + 1;
    int s0 = (i0 < W) ? cnt[i0] : 0;
    int s1 = (i1 < W) ? cnt[i1] : 0;
    int ps = s0 + s1;
    stmp[tid] = ps;
    __syncthreads();
    for (int off = 1; off < 256; off <<= 1) {
        int t = (tid >= off) ? stmp[tid - off] : 0;
        __syncthreads();
        stmp[tid] += t;
        __syncthreads();
    }
    int excl = stmp[tid] - ps;
    if (i0 < W) { row_ptr[nb0 + i0] = p0 + excl;      offs[i0] = excl; }
    if (i1 < W) { row_ptr[nb0 + i1] = p0 + excl + s0; offs[i1] = excl + s0; }
    __syncthreads();
    for (int i = tid; i < pc; i += 256) {
        int2 pr = pairs[p0 + i];
        int pos = atomicAdd(&offs[pr.y - nb0], 1);
        csr_src[p0 + pos] = pr.x;
    }
}

// ---------------- Linear1: fp16-pair dot2 GEMM + ReLU + normalize, fp16 out ----------------
// LDS 32 KB (Wp 16 + xp 16) -> 4+ blocks/CU; 1024 dot2/thread

__global__ __launch_bounds__(256, 4) void k_linear1(const float* __restrict__ x,
                                                    const float* __restrict__ W1,
                                                    const float* __restrict__ b1,
                                                    uint2* __restrict__ X1,
                                                    float* __restrict__ nrm1, int n) {
    __shared__ unsigned Wp[64 * 64];   // [kp][c] fp16 pairs (k,k+1), 16 KB
    __shared__ unsigned xp[64 * 64];   // [node][kp] fp16 pairs, swizzled, 16 KB
    int tid = threadIdx.x;
    int base = blockIdx.x * NPB;

    // stage W1 -> packed pairs [kp][c]
    for (int t = tid; t < 1024; t += 256) {
        int kp = t >> 4;            // 0..63
        int c4 = t & 15;            // 0..15
        float4 a = ((const float4*)W1)[(2 * kp) * 16 + c4];
        float4 b = ((const float4*)W1)[(2 * kp + 1) * 16 + c4];
        uint4 w;
        w.x = pkh(a.x, b.x); w.y = pkh(a.y, b.y);
        w.z = pkh(a.z, b.z); w.w = pkh(a.w, b.w);
        *(uint4*)&Wp[kp * 64 + c4 * 4] = w;
    }
    // stage x -> packed pairs [node][kp ^ key]
    for (int t = tid; t < 1024; t += 256) {
        int nl = t >> 4;            // 0..63
        int k8 = t & 15;            // 8 k's per task
        int gn = base + nl;
        float4 a, b;
        if (gn < n) {
            a = ((const float4*)x)[(size_t)gn * 32 + k8 * 2];
            b = ((const float4*)x)[(size_t)gn * 32 + k8 * 2 + 1];
        } else { a = make_float4(0,0,0,0); b = a; }
        uint4 v;
        v.x = pkh(a.x, a.y); v.y = pkh(a.z, a.w);
        v.z = pkh(b.x, b.y); v.w = pkh(b.z, b.w);
        int key = ((nl >> 2) & 3) << 2;
        *(uint4*)&xp[nl * 64 + ((k8 * 4) ^ key)] = v;
    }
    __syncthreads();

    int cg = tid & 15;                 // cols cg*4..+3
    int ng = tid >> 4;                 // nodes ng*4..+3
    int n0 = ng * 4;
    const int key = (ng & 3) << 2;
    float4 acc0 = {0,0,0,0}, acc1 = {0,0,0,0}, acc2 = {0,0,0,0}, acc3 = {0,0,0,0};

    #pragma unroll 4
    for (int k4 = 0; k4 < 64; k4 += 4) {
        uint4 xq0 = *(uint4*)&xp[(n0 + 0) * 64 + (k4 ^ key)];
        uint4 xq1 = *(uint4*)&xp[(n0 + 1) * 64 + (k4 ^ key)];
        uint4 xq2 = *(uint4*)&xp[(n0 + 2) * 64 + (k4 ^ key)];
        uint4 xq3 = *(uint4*)&xp[(n0 + 3) * 64 + (k4 ^ key)];
        uint4 wq0 = *(uint4*)&Wp[(k4 + 0) * 64 + cg * 4];
        uint4 wq1 = *(uint4*)&Wp[(k4 + 1) * 64 + cg * 4];
        uint4 wq2 = *(uint4*)&Wp[(k4 + 2) * 64 + cg * 4];
        uint4 wq3 = *(uint4*)&Wp[(k4 + 3) * 64 + cg * 4];
        dacc4(acc0, xq0.x, wq0); dacc4(acc0, xq0.y, wq1); dacc4(acc0, xq0.z, wq2); dacc4(acc0, xq0.w, wq3);
        dacc4(acc1, xq1.x, wq0); dacc4(acc1, xq1.y, wq1); dacc4(acc1, xq1.z, wq2); dacc4(acc1, xq1.w, wq3);
        dacc4(acc2, xq2.x, wq0); dacc4(acc2, xq2.y, wq1); dacc4(acc2, xq2.z, wq2); dacc4(acc2, xq2.w, wq3);
        dacc4(acc3, xq3.x, wq0); dacc4(acc3, xq3.y, wq1); dacc4(acc3, xq3.z, wq2); dacc4(acc3, xq3.w, wq3);
    }

    float4 bb = ((const float4*)b1)[cg];
    float4 r[4] = {acc0, acc1, acc2, acc3};
    #pragma unroll
    for (int nl = 0; nl < 4; ++nl) {
        int node = base + n0 + nl;
        float4 v = r[nl];
        v.x = fmaxf(v.x + bb.x, 0.f); v.y = fmaxf(v.y + bb.y, 0.f);
        v.z = fmaxf(v.z + bb.z, 0.f); v.w = fmaxf(v.w + bb.w, 0.f);
        float q = v.x * v.x + v.y * v.y + v.z * v.z + v.w * v.w;
        #pragma unroll
        for (int off = 8; off >= 1; off >>= 1) q += __shfl_xor(q, off, 64);
        float rq = rsqrtf(fmaxf(q, 1e-24f));
        if (node < n) {
            X1[(size_t)node * 16 + cg] = make_uint2(pkh(v.x * rq, v.y * rq),
                                                    pkh(v.z * rq, v.w * rq));
            if (cg == 0) nrm1[node] = sqrtf(fmaxf(q, 1e-24f));
        }
    }
}

// ---------------- AGNN propagation (fp16 normalized features + fp32 magnitude) ----------------
// one wave per dst node; 8 lanes x 8ch per edge; 2 chains => 16 edges/iter

template<bool HFOUT>
__global__ __launch_bounds__(256) void k_prop(const uint4* __restrict__ X,
                                              const float* __restrict__ nrm,
                                              const int* __restrict__ row_ptr,
                                              const int* __restrict__ csr_src,
                                              const float* __restrict__ beta_ptr,
                                              uint4* __restrict__ Xout,
                                              float* __restrict__ nrm_out,
                                              float4* __restrict__ outf, int n) {
    int node = blockIdx.x * 4 + (threadIdx.x >> 6);
    if (node >= n) return;
    int lane = threadIdx.x & 63;
    int g = lane >> 3, gl = lane & 7;
    float beta = beta_ptr ? beta_ptr[0] : 1.0f;
    float b2 = beta * 1.4426950408889634f;

    uint4 hdp = X[(size_t)node * 8 + gl];
    float hdf[8]; unpack8(hdf, hdp);
    int s0 = row_ptr[node], s1 = row_ptr[node + 1];

    float ds = dot4(hdp, hdp);
    ds += __shfl_xor(ds, 1, 64); ds += __shfl_xor(ds, 2, 64); ds += __shfl_xor(ds, 4, 64);
    float eself = EXP2(b2 * ds);
    float nd = nrm[node];
    float den0 = (g == 0) ? eself : 0.f;
    float es = (g == 0) ? eself * nd : 0.f;
    float acc[8];
    #pragma unroll
    for (int c = 0; c < 8; ++c) acc[c] = es * hdf[c];
    float den1 = 0.f;

    for (int j = s0; j < s1; j += 16) {
        int p0 = j + g, p1 = j + 8 + g;
        bool v0 = p0 < s1, v1 = p1 < s1;
        int i0 = v0 ? csr_src[p0] : 0;
        int i1 = v1 ? csr_src[p1] : 0;
        uint4 a0 = X[(size_t)i0 * 8 + gl];
        uint4 a1 = X[(size_t)i1 * 8 + gl];
        float n0 = nrm[i0], n1 = nrm[i1];
        float d0 = dot4(a0, hdp);
        float d1 = dot4(a1, hdp);
        d0 += __shfl_xor(d0, 1, 64); d1 += __shfl_xor(d1, 1, 64);
        d0 += __shfl_xor(d0, 2, 64); d1 += __shfl_xor(d1, 2, 64);
        d0 += __shfl_xor(d0, 4, 64); d1 += __shfl_xor(d1, 4, 64);
        float e0 = v0 ? EXP2(b2 * d0) : 0.f;
        float e1 = v1 ? EXP2(b2 * d1) : 0.f;
        den0 += e0; den1 += e1;
        float sc0 = e0 * n0, sc1 = e1 * n1;
        accum8(acc, sc0, a0);
        accum8(acc, sc1, a1);
    }

    float den = den0 + den1;
    #pragma unroll
    for (int c = 0; c < 8; ++c) {
        acc[c] += __shfl_xor(acc[c], 8, 64);
        acc[c] += __shfl_xor(acc[c], 16, 64);
        acc[c] += __shfl_xor(acc[c], 32, 64);
    }
    den += __shfl_xor(den, 8, 64);
    den += __shfl_xor(den, 16, 64);
    den += __shfl_xor(den, 32, 64);
    float inv = 1.0f / den;
    float o[8];
    #pragma unroll
    for (int c = 0; c < 8; ++c) o[c] = acc[c] * inv;

    if (HFOUT) {
        float q = 0.f;
        #pragma unroll
        for (int c = 0; c < 8; ++c) q += o[c] * o[c];
        q += __shfl_xor(q, 1, 64); q += __shfl_xor(q, 2, 64); q += __shfl_xor(q, 4, 64);
        float rq = rsqrtf(fmaxf(q, 1e-24f));
        if (g == 0) {
            uint4 w;
            w.x = pkh(o[0] * rq, o[1] * rq);
            w.y = pkh(o[2] * rq, o[3] * rq);
            w.z = pkh(o[4] * rq, o[5] * rq);
            w.w = pkh(o[6] * rq, o[7] * rq);
            Xout[(size_t)node * 8 + gl] = w;
            if (gl == 0) nrm_out[node] = sqrtf(fmaxf(q, 1e-24f));
        }
    } else {
        if (g == 0) {
            outf[(size_t)node * 16 + gl * 2]     = make_float4(o[0], o[1], o[2], o[3]);
            outf[(size_t)node * 16 + gl * 2 + 1] = make_float4(o[4], o[5], o[6], o[7]);
        }
    }
}

// ---------------- Linear2 + log_softmax: register-tiled ----------------

__global__ __launch_bounds__(256) void k_out(const float* __restrict__ h,
                                             const float* __restrict__ W2,
                                             const float* __restrict__ b2,
                                             float* __restrict__ out, int n) {
    __shared__ float hs[ONB * HID];     // 24 KB swizzled
    __shared__ float W2s[HID * OUTC];   // 10 KB [k][c]
    __shared__ float ls[ONB * LSW];
    int tid = threadIdx.x;
    int base = blockIdx.x * ONB;

    for (int i = tid; i < HID * OUTC / 4; i += 256)
        ((float4*)W2s)[i] = ((const float4*)W2)[i];
    for (int i = tid; i < ONB * 16; i += 256) {
        int nl = i >> 4, k4 = i & 15;
        int gn = base + nl;
        float4 v = (gn < n) ? ((const float4*)h)[(size_t)gn * 16 + k4]
                            : make_float4(0.f, 0.f, 0.f, 0.f);
        int swk = (k4 * 4) ^ (((nl >> 2) & 7) << 2);
        *(float4*)&hs[nl * HID + swk] = v;
    }
    __syncthreads();

    if (tid < 240) {
        int ng = tid / 10, cg = tid % 10;
        int n0 = ng * 4;
        const int sw = ((ng & 7) << 2);
        float4 acc0 = {0,0,0,0}, acc1 = {0,0,0,0}, acc2 = {0,0,0,0}, acc3 = {0,0,0,0};
        #pragma unroll 4
        for (int k = 0; k < HID; k += 4) {
            float4 w0 = *(float4*)&W2s[(k + 0) * OUTC + cg * 4];
            float4 w1 = *(float4*)&W2s[(k + 1) * OUTC + cg * 4];
            float4 w2 = *(float4*)&W2s[(k + 2) * OUTC + cg * 4];
            float4 w3 = *(float4*)&W2s[(k + 3) * OUTC + cg * 4];
            float4 x0 = *(float4*)&hs[(n0 + 0) * HID + (k ^ sw)];
            float4 x1 = *(float4*)&hs[(n0 + 1) * HID + (k ^ sw)];
            float4 x2 = *(float4*)&hs[(n0 + 2) * HID + (k ^ sw)];
            float4 x3 = *(float4*)&hs[(n0 + 3) * HID + (k ^ sw)];
            fma4(acc0, x0.x, w0); fma4(acc0, x0.y, w1); fma4(acc0, x0.z, w2); fma4(acc0, x0.w, w3);
            fma4(acc1, x1.x, w0); fma4(acc1, x1.y, w1); fma4(acc1, x1.z, w2); fma4(acc1, x1.w, w3);
            fma4(acc2, x2.x, w0); fma4(acc2, x2.y, w1); fma4(acc2, x2.z, w2); fma4(acc2, x2.w, w3);
            fma4(acc3, x3.x, w0); fma4(acc3, x3.y, w1); fma4(acc3, x3.z, w2); fma4(acc3, x3.w, w3);
        }
        float4 bb = ((const float4*)b2)[cg];
        float4 rr[4] = {acc0, acc1, acc2, acc3};
        #pragma unroll
        for (int i = 0; i < 4; ++i) {
            int lb = (n0 + i) * LSW + cg * 4;
            ls[lb + 0] = rr[i].x + bb.x;
            ls[lb + 1] = rr[i].y + bb.y;
            ls[lb + 2] = rr[i].z + bb.z;
            ls[lb + 3] = rr[i].w + bb.w;
        }
    }
    __syncthreads();

    if (tid < ONB) {
        int node = base + tid;
        if (node < n) {
            float m = -INFINITY;
            #pragma unroll
            for (int c = 0; c < OUTC; ++c) m = fmaxf(m, ls[tid * LSW + c]);
            float z = 0.f;
            #pragma unroll
            for (int c = 0; c < OUTC; ++c) z += __expf(ls[tid * LSW + c] - m);
            float lz = m + __logf(z);
            #pragma unroll
            for (int c = 0; c < OUTC; ++c)
                out[(size_t)node * OUTC + c] = ls[tid * LSW + c] - lz;
        }
    }
}

// ---------------- launch ----------------

extern "C" void kernel_launch(void* const* d_in, const int* in_sizes, int n_in,
                              void* d_out, int out_size, void* d_ws, size_t ws_size,
                              hipStream_t stream) {
    const float* x   = (const float*)d_in[0];
    const int*   ei  = (const int*)d_in[1];
    const float* W1  = (const float*)d_in[2];
    const float* b1  = (const float*)d_in[3];
    const float* W2  = (const float*)d_in[4];
    const float* b2  = (const float*)d_in[5];
    const float* beta2 = (const float*)d_in[6];
    float* out = (float*)d_out;

    const int n = in_sizes[0] / INC;       // 100000
    const int E = in_sizes[1] / 2;         // 1600000
    const int nbuck = (n + (1 << SHIFT) - 1) >> SHIFT;   // 196
    const int cgrid = (E + 4095) / 4096;   // 391

    // workspace layout
    char* p = (char*)d_ws;
    uint4* X1 = (uint4*)p;             p += (size_t)n * 8 * 16;   // 12.8 MB fp16 normalized
    uint4* X2 = (uint4*)p;             p += (size_t)n * 8 * 16;   // 12.8 MB
    float* h3 = (float*)p;             p += (size_t)n * HID * 4;  // 25.6 MB fp32
    float* nrm1 = (float*)p;           p += (size_t)n * 4;
    float* nrm2 = (float*)p;           p += (size_t)n * 4;
    int* bucket_cnt  = (int*)p;        p += MAXB * 4;
    int* pair_base   = (int*)p;        p += MAXB * 4;
    int* pair_fill   = (int*)p;        p += MAXB * 4;
    int* row_ptr = (int*)p;            p += (size_t)(n + 1) * 4;
    int* csr_src = (int*)p;            p += (size_t)E * 4;
    int* blk_cnt = (int*)p;            p += (size_t)cgrid * MAXB * 4;
    int2* pairs = (int2*)h3;           // alias: pairs dead before prop2 writes h3

    // CSR build (bucketed counting sort, edges only)
    hipMemsetAsync(bucket_cnt, 0, MAXB * 4, stream);
    k_hist<<<cgrid, 256, 0, stream>>>(ei, E, bucket_cnt, blk_cnt, nbuck);
    k_bscan<<<1, 256, 0, stream>>>(bucket_cnt, pair_base, pair_fill, row_ptr, n, E, nbuck);
    k_bin<<<cgrid, 256, 0, stream>>>(ei, E, blk_cnt, pair_fill, pairs, nbuck);
    k_build<<<nbuck, 256, 0, stream>>>(pairs, pair_base, bucket_cnt, row_ptr, csr_src, n);

    // MLP front + props + head
    k_linear1<<<(n + NPB - 1) / NPB, 256, 0, stream>>>(x, W1, b1, (uint2*)X1, nrm1, n);
    int pgrid = (n + 3) / 4;
    k_prop<true><<<pgrid, 256, 0, stream>>>(X1, nrm1, row_ptr, csr_src, nullptr,
                                            X2, nrm2, nullptr, n);
    k_prop<false><<<pgrid, 256, 0, stream>>>(X2, nrm2, row_ptr, csr_src, beta2,
                                             nullptr, nullptr, (float4*)h3, n);
    k_out<<<(n + ONB - 1) / ONB, 256, 0, stream>>>(h3, W2, b2, out, n);
}

// Round 12
// 206.574 us; speedup vs baseline: 3.7098x; 1.0654x over previous
//
#include <hip/hip_runtime.h>
#include <math.h>

#define INC 128
#define HID 64
#define OUTC 40
#define SHIFT 9
#define MAXB 256
#define NPB 64
#define ONB 96
#define LSW 41
#define SRCM 0x1FFFF

typedef _Float16 half2_t __attribute__((ext_vector_type(2)));

__device__ inline void fma4(float4& a, float s, const float4& w) {
    a.x += s * w.x; a.y += s * w.y; a.z += s * w.z; a.w += s * w.w;
}
__device__ inline unsigned pkh(float a, float b) {
    unsigned short ua = __builtin_bit_cast(unsigned short, (_Float16)a);
    unsigned short ub = __builtin_bit_cast(unsigned short, (_Float16)b);
    return (unsigned)ua | ((unsigned)ub << 16);
}
__device__ inline float fdot2_(unsigned a, unsigned b, float c) {
#if __has_builtin(__builtin_amdgcn_fdot2)
    return __builtin_amdgcn_fdot2(__builtin_bit_cast(half2_t, a),
                                  __builtin_bit_cast(half2_t, b), c, false);
#else
    half2_t ha = __builtin_bit_cast(half2_t, a);
    half2_t hb = __builtin_bit_cast(half2_t, b);
    return fmaf((float)ha[0], (float)hb[0], fmaf((float)ha[1], (float)hb[1], c));
#endif
}
__device__ inline float dot4(const uint4& a, const uint4& b) {
    float d = fdot2_(a.x, b.x, 0.f);
    d = fdot2_(a.y, b.y, d);
    d = fdot2_(a.z, b.z, d);
    d = fdot2_(a.w, b.w, d);
    return d;
}
__device__ inline void accum8(float* acc, float s, const uint4& a) {
    half2_t p;
    p = __builtin_bit_cast(half2_t, a.x); acc[0] += s * (float)p[0]; acc[1] += s * (float)p[1];
    p = __builtin_bit_cast(half2_t, a.y); acc[2] += s * (float)p[0]; acc[3] += s * (float)p[1];
    p = __builtin_bit_cast(half2_t, a.z); acc[4] += s * (float)p[0]; acc[5] += s * (float)p[1];
    p = __builtin_bit_cast(half2_t, a.w); acc[6] += s * (float)p[0]; acc[7] += s * (float)p[1];
}
__device__ inline void unpack8(float* f, const uint4& a) {
    half2_t p;
    p = __builtin_bit_cast(half2_t, a.x); f[0] = (float)p[0]; f[1] = (float)p[1];
    p = __builtin_bit_cast(half2_t, a.y); f[2] = (float)p[0]; f[3] = (float)p[1];
    p = __builtin_bit_cast(half2_t, a.z); f[4] = (float)p[0]; f[5] = (float)p[1];
    p = __builtin_bit_cast(half2_t, a.w); f[6] = (float)p[0]; f[7] = (float)p[1];
}
__device__ inline void dacc4(float4& a, unsigned xp_, const uint4& w) {
    a.x = fdot2_(xp_, w.x, a.x);
    a.y = fdot2_(xp_, w.y, a.y);
    a.z = fdot2_(xp_, w.z, a.z);
    a.w = fdot2_(xp_, w.w, a.w);
}
// DPP-modified add: d += lane-permuted(d). Single VALU op, no LDS pipe.
// ctrl must be an immediate -> template parameter.
template<int CTRL>
__device__ inline float dppadd(float d) {
    int x = __builtin_amdgcn_update_dpp(0, __builtin_bit_cast(int, d),
                                        CTRL, 0xf, 0xf, true);
    return d + __builtin_bit_cast(float, x);
}
// sum over aligned 8-lane group (any pairing perm works for sums)
__device__ inline float red8(float d) {
    d = dppadd<0xB1>(d);    // quad_perm [1,0,3,2]  : xor1
    d = dppadd<0x4E>(d);    // quad_perm [2,3,0,1]  : xor2
    d = dppadd<0x141>(d);   // row_half_mirror      : cross-quad within 8
    return d;
}
// sum over aligned 16-lane group
__device__ inline float red16(float d) {
    d = dppadd<0xB1>(d);
    d = dppadd<0x4E>(d);
    d = dppadd<0x141>(d);
    d = dppadd<0x140>(d);   // row_mirror: cross-8 within 16
    return d;
}
#define EXP2(x) __builtin_amdgcn_exp2f(x)

// ---------------- CSR build: bucketed counting sort (no self loops) ----------------

__global__ __launch_bounds__(256) void k_hist(const int* __restrict__ ei, int E,
                                              int* __restrict__ bucket_cnt,
                                              int* __restrict__ blk_cnt, int nbuck) {
    __shared__ int lh[MAXB];
    int tid = threadIdx.x;
    for (int i = tid; i < nbuck; i += 256) lh[i] = 0;
    __syncthreads();
    int base = blockIdx.x * 4096;
    int end = min(base + 4096, E);
    for (int e = base + tid; e < end; e += 256)
        atomicAdd(&lh[ei[E + e] >> SHIFT], 1);
    __syncthreads();
    for (int i = tid; i < nbuck; i += 256) {
        int v = lh[i];
        blk_cnt[blockIdx.x * MAXB + i] = v;
        if (v) atomicAdd(&bucket_cnt[i], v);
    }
}

__global__ __launch_bounds__(256) void k_bscan(const int* __restrict__ bucket_cnt,
                                               int* __restrict__ pair_base,
                                               int* __restrict__ pair_fill,
                                               int* __restrict__ row_ptr,
                                               int n, int E, int nbuck) {
    __shared__ int tmp[MAXB];
    int tid = threadIdx.x;
    int cnt = (tid < nbuck) ? bucket_cnt[tid] : 0;
    tmp[tid] = cnt;
    __syncthreads();
    for (int off = 1; off < 256; off <<= 1) {
        int t = (tid >= off) ? tmp[tid - off] : 0;
        __syncthreads();
        tmp[tid] += t;
        __syncthreads();
    }
    if (tid < nbuck) { int pb = tmp[tid] - cnt; pair_base[tid] = pb; pair_fill[tid] = pb; }
    if (tid == 0) row_ptr[n] = E;
}

__global__ __launch_bounds__(256) void k_bin(const int* __restrict__ ei, int E,
                                             const int* __restrict__ blk_cnt,
                                             int* __restrict__ pair_fill,
                                             unsigned* __restrict__ pairs, int nbuck) {
    __shared__ int lbase[MAXB];
    int tid = threadIdx.x;
    for (int i = tid; i < nbuck; i += 256) {
        int v = blk_cnt[blockIdx.x * MAXB + i];
        lbase[i] = v ? atomicAdd(&pair_fill[i], v) : 0;
    }
    __syncthreads();
    int base = blockIdx.x * 4096;
    int end = min(base + 4096, E);
    for (int e = base + tid; e < end; e += 256) {
        int s = ei[e], d = ei[E + e];
        int pos = atomicAdd(&lbase[d >> SHIFT], 1);
        pairs[pos] = (unsigned)s | ((unsigned)(d & ((1 << SHIFT) - 1)) << 17);
    }
}

__global__ __launch_bounds__(256) void k_build(const unsigned* __restrict__ pairs,
                                               const int* __restrict__ pair_base,
                                               const int* __restrict__ bucket_cnt,
                                               int* __restrict__ row_ptr,
                                               int* __restrict__ csr_src, int n) {
    __shared__ int cnt[1 << SHIFT];
    __shared__ int offs[1 << SHIFT];
    __shared__ int stmp[256];
    int b = blockIdx.x;
    int tid = threadIdx.x;
    int nb0 = b << SHIFT;
    int W = min(n - nb0, 1 << SHIFT);
    int p0 = pair_base[b], pc = bucket_cnt[b];

    cnt[tid] = 0; cnt[tid + 256] = 0;
    __syncthreads();
    for (int i = tid; i < pc; i += 256)
        atomicAdd(&cnt[pairs[p0 + i] >> 17], 1);
    __syncthreads();

    int i0 = 2 * tid, i1 = 2 * tid + 1;
    int s0 = (i0 < W) ? cnt[i0] : 0;
    int s1 = (i1 < W) ? cnt[i1] : 0;
    int ps = s0 + s1;
    stmp[tid] = ps;
    __syncthreads();
    for (int off = 1; off < 256; off <<= 1) {
        int t = (tid >= off) ? stmp[tid - off] : 0;
        __syncthreads();
        stmp[tid] += t;
        __syncthreads();
    }
    int excl = stmp[tid] - ps;
    if (i0 < W) { row_ptr[nb0 + i0] = p0 + excl;      offs[i0] = excl; }
    if (i1 < W) { row_ptr[nb0 + i1] = p0 + excl + s0; offs[i1] = excl + s0; }
    __syncthreads();
    for (int i = tid; i < pc; i += 256) {
        unsigned pr = pairs[p0 + i];
        int pos = atomicAdd(&offs[pr >> 17], 1);
        csr_src[p0 + pos] = (int)(pr & SRCM);
    }
}

// ---------------- Linear1: fp16-pair dot2 GEMM + ReLU + normalize, fp16 out ----------------

__global__ __launch_bounds__(256, 4) void k_linear1(const float* __restrict__ x,
                                                    const float* __restrict__ W1,
                                                    const float* __restrict__ b1,
                                                    uint2* __restrict__ X1,
                                                    float* __restrict__ nrm1, int n) {
    __shared__ unsigned Wp[64 * 64];   // [kp][c] fp16 pairs, 16 KB
    __shared__ unsigned xp[64 * 64];   // [node][kp] fp16 pairs, swizzled, 16 KB
    int tid = threadIdx.x;
    int base = blockIdx.x * NPB;

    for (int t = tid; t < 1024; t += 256) {
        int kp = t >> 4;
        int c4 = t & 15;
        float4 a = ((const float4*)W1)[(2 * kp) * 16 + c4];
        float4 b = ((const float4*)W1)[(2 * kp + 1) * 16 + c4];
        uint4 w;
        w.x = pkh(a.x, b.x); w.y = pkh(a.y, b.y);
        w.z = pkh(a.z, b.z); w.w = pkh(a.w, b.w);
        *(uint4*)&Wp[kp * 64 + c4 * 4] = w;
    }
    for (int t = tid; t < 1024; t += 256) {
        int nl = t >> 4;
        int k8 = t & 15;
        int gn = base + nl;
        float4 a, b;
        if (gn < n) {
            a = ((const float4*)x)[(size_t)gn * 32 + k8 * 2];
            b = ((const float4*)x)[(size_t)gn * 32 + k8 * 2 + 1];
        } else { a = make_float4(0,0,0,0); b = a; }
        uint4 v;
        v.x = pkh(a.x, a.y); v.y = pkh(a.z, a.w);
        v.z = pkh(b.x, b.y); v.w = pkh(b.z, b.w);
        int key = ((nl >> 2) & 3) << 2;
        *(uint4*)&xp[nl * 64 + ((k8 * 4) ^ key)] = v;
    }
    __syncthreads();

    int cg = tid & 15;
    int ng = tid >> 4;
    int n0 = ng * 4;
    const int key = (ng & 3) << 2;
    float4 acc0 = {0,0,0,0}, acc1 = {0,0,0,0}, acc2 = {0,0,0,0}, acc3 = {0,0,0,0};

    #pragma unroll 4
    for (int k4 = 0; k4 < 64; k4 += 4) {
        uint4 xq0 = *(uint4*)&xp[(n0 + 0) * 64 + (k4 ^ key)];
        uint4 xq1 = *(uint4*)&xp[(n0 + 1) * 64 + (k4 ^ key)];
        uint4 xq2 = *(uint4*)&xp[(n0 + 2) * 64 + (k4 ^ key)];
        uint4 xq3 = *(uint4*)&xp[(n0 + 3) * 64 + (k4 ^ key)];
        uint4 wq0 = *(uint4*)&Wp[(k4 + 0) * 64 + cg * 4];
        uint4 wq1 = *(uint4*)&Wp[(k4 + 1) * 64 + cg * 4];
        uint4 wq2 = *(uint4*)&Wp[(k4 + 2) * 64 + cg * 4];
        uint4 wq3 = *(uint4*)&Wp[(k4 + 3) * 64 + cg * 4];
        dacc4(acc0, xq0.x, wq0); dacc4(acc0, xq0.y, wq1); dacc4(acc0, xq0.z, wq2); dacc4(acc0, xq0.w, wq3);
        dacc4(acc1, xq1.x, wq0); dacc4(acc1, xq1.y, wq1); dacc4(acc1, xq1.z, wq2); dacc4(acc1, xq1.w, wq3);
        dacc4(acc2, xq2.x, wq0); dacc4(acc2, xq2.y, wq1); dacc4(acc2, xq2.z, wq2); dacc4(acc2, xq2.w, wq3);
        dacc4(acc3, xq3.x, wq0); dacc4(acc3, xq3.y, wq1); dacc4(acc3, xq3.z, wq2); dacc4(acc3, xq3.w, wq3);
    }

    float4 bb = ((const float4*)b1)[cg];
    float4 r[4] = {acc0, acc1, acc2, acc3};
    #pragma unroll
    for (int nl = 0; nl < 4; ++nl) {
        int node = base + n0 + nl;
        float4 v = r[nl];
        v.x = fmaxf(v.x + bb.x, 0.f); v.y = fmaxf(v.y + bb.y, 0.f);
        v.z = fmaxf(v.z + bb.z, 0.f); v.w = fmaxf(v.w + bb.w, 0.f);
        float q = v.x * v.x + v.y * v.y + v.z * v.z + v.w * v.w;
        q = red16(q);
        float rq = rsqrtf(fmaxf(q, 1e-24f));
        if (node < n) {
            X1[(size_t)node * 16 + cg] = make_uint2(pkh(v.x * rq, v.y * rq),
                                                    pkh(v.z * rq, v.w * rq));
            if (cg == 0) nrm1[node] = sqrtf(fmaxf(q, 1e-24f));
        }
    }
}

// ---------------- AGNN propagation (fp16 normalized + fp32 magnitude, DPP butterfly) ----------------

template<bool HFOUT>
__global__ __launch_bounds__(256) void k_prop(const uint4* __restrict__ X,
                                              const float* __restrict__ nrm,
                                              const int* __restrict__ row_ptr,
                                              const int* __restrict__ csr_src,
                                              const float* __restrict__ beta_ptr,
                                              uint4* __restrict__ Xout,
                                              float* __restrict__ nrm_out,
                                              float4* __restrict__ outf, int n) {
    int node = blockIdx.x * 4 + (threadIdx.x >> 6);
    if (node >= n) return;
    int lane = threadIdx.x & 63;
    int g = lane >> 3, gl = lane & 7;
    float beta = beta_ptr ? beta_ptr[0] : 1.0f;
    float b2 = beta * 1.4426950408889634f;

    uint4 hdp = X[(size_t)node * 8 + gl];
    float hdf[8]; unpack8(hdf, hdp);
    int s0 = row_ptr[node], s1 = row_ptr[node + 1];

    float ds = red8(dot4(hdp, hdp));
    float eself = EXP2(b2 * ds);
    float nd = nrm[node];
    float den0 = (g == 0) ? eself : 0.f;
    float es = (g == 0) ? eself * nd : 0.f;
    float acc[8];
    #pragma unroll
    for (int c = 0; c < 8; ++c) acc[c] = es * hdf[c];
    float den1 = 0.f;

    for (int j = s0; j < s1; j += 16) {
        int p0 = j + g, p1 = j + 8 + g;
        bool v0 = p0 < s1, v1 = p1 < s1;
        int i0 = v0 ? csr_src[p0] : 0;
        int i1 = v1 ? csr_src[p1] : 0;
        uint4 a0 = X[(size_t)i0 * 8 + gl];
        uint4 a1 = X[(size_t)i1 * 8 + gl];
        float n0 = nrm[i0], n1 = nrm[i1];
        float d0 = red8(dot4(a0, hdp));
        float d1 = red8(dot4(a1, hdp));
        float e0 = v0 ? EXP2(b2 * d0) : 0.f;
        float e1 = v1 ? EXP2(b2 * d1) : 0.f;
        den0 += e0; den1 += e1;
        float sc0 = e0 * n0, sc1 = e1 * n1;
        accum8(acc, sc0, a0);
        accum8(acc, sc1, a1);
    }

    float den = den0 + den1;
    #pragma unroll
    for (int c = 0; c < 8; ++c) {
        acc[c] += __shfl_xor(acc[c], 8, 64);
        acc[c] += __shfl_xor(acc[c], 16, 64);
        acc[c] += __shfl_xor(acc[c], 32, 64);
    }
    den += __shfl_xor(den, 8, 64);
    den += __shfl_xor(den, 16, 64);
    den += __shfl_xor(den, 32, 64);
    float inv = 1.0f / den;
    float o[8];
    #pragma unroll
    for (int c = 0; c < 8; ++c) o[c] = acc[c] * inv;

    if (HFOUT) {
        float q = 0.f;
        #pragma unroll
        for (int c = 0; c < 8; ++c) q += o[c] * o[c];
        q = red8(q);
        float rq = rsqrtf(fmaxf(q, 1e-24f));
        if (g == 0) {
            uint4 w;
            w.x = pkh(o[0] * rq, o[1] * rq);
            w.y = pkh(o[2] * rq, o[3] * rq);
            w.z = pkh(o[4] * rq, o[5] * rq);
            w.w = pkh(o[6] * rq, o[7] * rq);
            Xout[(size_t)node * 8 + gl] = w;
            if (gl == 0) nrm_out[node] = sqrtf(fmaxf(q, 1e-24f));
        }
    } else {
        if (g == 0) {
            outf[(size_t)node * 16 + gl * 2]     = make_float4(o[0], o[1], o[2], o[3]);
            outf[(size_t)node * 16 + gl * 2 + 1] = make_float4(o[4], o[5], o[6], o[7]);
        }
    }
}

// ---------------- Linear2 + log_softmax: register-tiled ----------------

__global__ __launch_bounds__(256) void k_out(const float* __restrict__ h,
                                             const float* __restrict__ W2,
                                             const float* __restrict__ b2,
                                             float* __restrict__ out, int n) {
    __shared__ float hs[ONB * HID];
    __shared__ float W2s[HID * OUTC];
    __shared__ float ls[ONB * LSW];
    int tid = threadIdx.x;
    int base = blockIdx.x * ONB;

    for (int i = tid; i < HID * OUTC / 4; i += 256)
        ((float4*)W2s)[i] = ((const float4*)W2)[i];
    for (int i = tid; i < ONB * 16; i += 256) {
        int nl = i >> 4, k4 = i & 15;
        int gn = base + nl;
        float4 v = (gn < n) ? ((const float4*)h)[(size_t)gn * 16 + k4]
                            : make_float4(0.f, 0.f, 0.f, 0.f);
        int swk = (k4 * 4) ^ (((nl >> 2) & 7) << 2);
        *(float4*)&hs[nl * HID + swk] = v;
    }
    __syncthreads();

    if (tid < 240) {
        int ng = tid / 10, cg = tid % 10;
        int n0 = ng * 4;
        const int sw = ((ng & 7) << 2);
        float4 acc0 = {0,0,0,0}, acc1 = {0,0,0,0}, acc2 = {0,0,0,0}, acc3 = {0,0,0,0};
        #pragma unroll 4
        for (int k = 0; k < HID; k += 4) {
            float4 w0 = *(float4*)&W2s[(k + 0) * OUTC + cg * 4];
            float4 w1 = *(float4*)&W2s[(k + 1) * OUTC + cg * 4];
            float4 w2 = *(float4*)&W2s[(k + 2) * OUTC + cg * 4];
            float4 w3 = *(float4*)&W2s[(k + 3) * OUTC + cg * 4];
            float4 x0 = *(float4*)&hs[(n0 + 0) * HID + (k ^ sw)];
            float4 x1 = *(float4*)&hs[(n0 + 1) * HID + (k ^ sw)];
            float4 x2 = *(float4*)&hs[(n0 + 2) * HID + (k ^ sw)];
            float4 x3 = *(float4*)&hs[(n0 + 3) * HID + (k ^ sw)];
            fma4(acc0, x0.x, w0); fma4(acc0, x0.y, w1); fma4(acc0, x0.z, w2); fma4(acc0, x0.w, w3);
            fma4(acc1, x1.x, w0); fma4(acc1, x1.y, w1); fma4(acc1, x1.z, w2); fma4(acc1, x1.w, w3);
            fma4(acc2, x2.x, w0); fma4(acc2, x2.y, w1); fma4(acc2, x2.z, w2); fma4(acc2, x2.w, w3);
            fma4(acc3, x3.x, w0); fma4(acc3, x3.y, w1); fma4(acc3, x3.z, w2); fma4(acc3, x3.w, w3);
        }
        float4 bb = ((const float4*)b2)[cg];
        float4 rr[4] = {acc0, acc1, acc2, acc3};
        #pragma unroll
        for (int i = 0; i < 4; ++i) {
            int lb = (n0 + i) * LSW + cg * 4;
            ls[lb + 0] = rr[i].x + bb.x;
            ls[lb + 1] = rr[i].y + bb.y;
            ls[lb + 2] = rr[i].z + bb.z;
            ls[lb + 3] = rr[i].w + bb.w;
        }
    }
    __syncthreads();

    if (tid < ONB) {
        int node = base + tid;
        if (node < n) {
            float m = -INFINITY;
            #pragma unroll
            for (int c = 0; c < OUTC; ++c) m = fmaxf(m, ls[tid * LSW + c]);
            float z = 0.f;
            #pragma unroll
            for (int c = 0; c < OUTC; ++c) z += __expf(ls[tid * LSW + c] - m);
            float lz = m + __logf(z);
            #pragma unroll
            for (int c = 0; c < OUTC; ++c)
                out[(size_t)node * OUTC + c] = ls[tid * LSW + c] - lz;
        }
    }
}

// ---------------- launch ----------------

extern "C" void kernel_launch(void* const* d_in, const int* in_sizes, int n_in,
                              void* d_out, int out_size, void* d_ws, size_t ws_size,
                              hipStream_t stream) {
    const float* x   = (const float*)d_in[0];
    const int*   ei  = (const int*)d_in[1];
    const float* W1  = (const float*)d_in[2];
    const float* b1  = (const float*)d_in[3];
    const float* W2  = (const float*)d_in[4];
    const float* b2  = (const float*)d_in[5];
    const float* beta2 = (const float*)d_in[6];
    float* out = (float*)d_out;

    const int n = in_sizes[0] / INC;       // 100000
    const int E = in_sizes[1] / 2;         // 1600000
    const int nbuck = (n + (1 << SHIFT) - 1) >> SHIFT;   // 196
    const int cgrid = (E + 4095) / 4096;   // 391

    // workspace layout
    char* p = (char*)d_ws;
    uint4* X1 = (uint4*)p;             p += (size_t)n * 8 * 16;
    uint4* X2 = (uint4*)p;             p += (size_t)n * 8 * 16;
    float* h3 = (float*)p;             p += (size_t)n * HID * 4;
    float* nrm1 = (float*)p;           p += (size_t)n * 4;
    float* nrm2 = (float*)p;           p += (size_t)n * 4;
    int* bucket_cnt  = (int*)p;        p += MAXB * 4;
    int* pair_base   = (int*)p;        p += MAXB * 4;
    int* pair_fill   = (int*)p;        p += MAXB * 4;
    int* row_ptr = (int*)p;            p += (size_t)(n + 1) * 4;
    int* csr_src = (int*)p;            p += (size_t)E * 4;
    int* blk_cnt = (int*)p;            p += (size_t)cgrid * MAXB * 4;
    unsigned* pairs = (unsigned*)h3;   // alias: pairs dead before prop2 writes h3

    // CSR build
    hipMemsetAsync(bucket_cnt, 0, MAXB * 4, stream);
    k_hist<<<cgrid, 256, 0, stream>>>(ei, E, bucket_cnt, blk_cnt, nbuck);
    k_bscan<<<1, 256, 0, stream>>>(bucket_cnt, pair_base, pair_fill, row_ptr, n, E, nbuck);
    k_bin<<<cgrid, 256, 0, stream>>>(ei, E, blk_cnt, pair_fill, pairs, nbuck);
    k_build<<<nbuck, 256, 0, stream>>>(pairs, pair_base, bucket_cnt, row_ptr, csr_src, n);

    // MLP front + props + head
    k_linear1<<<(n + NPB - 1) / NPB, 256, 0, stream>>>(x, W1, b1, (uint2*)X1, nrm1, n);
    int pgrid = (n + 3) / 4;
    k_prop<true><<<pgrid, 256, 0, stream>>>(X1, nrm1, row_ptr, csr_src, nullptr,
                                            X2, nrm2, nullptr, n);
    k_prop<false><<<pgrid, 256, 0, stream>>>(X2, nrm2, row_ptr, csr_src, beta2,
                                             nullptr, nullptr, (float4*)h3, n);
    k_out<<<(n + ONB - 1) / ONB, 256, 0, stream>>>(h3, W2, b2, out, n);
}

// Round 13
// 195.176 us; speedup vs baseline: 3.9265x; 1.0584x over previous
//
#include <hip/hip_runtime.h>
#include <math.h>

#define INC 128
#define HID 64
#define OUTC 40
#define SHIFT 9
#define MAXB 256
#define NPB 64
#define ONB 96
#define LSW 41
#define SRCM 0x1FFFF
#define PLDS 12288

typedef _Float16 half2_t __attribute__((ext_vector_type(2)));

__device__ inline void fma4(float4& a, float s, const float4& w) {
    a.x += s * w.x; a.y += s * w.y; a.z += s * w.z; a.w += s * w.w;
}
__device__ inline unsigned pkh(float a, float b) {
    unsigned short ua = __builtin_bit_cast(unsigned short, (_Float16)a);
    unsigned short ub = __builtin_bit_cast(unsigned short, (_Float16)b);
    return (unsigned)ua | ((unsigned)ub << 16);
}
__device__ inline float fdot2_(unsigned a, unsigned b, float c) {
#if __has_builtin(__builtin_amdgcn_fdot2)
    return __builtin_amdgcn_fdot2(__builtin_bit_cast(half2_t, a),
                                  __builtin_bit_cast(half2_t, b), c, false);
#else
    half2_t ha = __builtin_bit_cast(half2_t, a);
    half2_t hb = __builtin_bit_cast(half2_t, b);
    return fmaf((float)ha[0], (float)hb[0], fmaf((float)ha[1], (float)hb[1], c));
#endif
}
__device__ inline float dot4(const uint4& a, const uint4& b) {
    float d = fdot2_(a.x, b.x, 0.f);
    d = fdot2_(a.y, b.y, d);
    d = fdot2_(a.z, b.z, d);
    d = fdot2_(a.w, b.w, d);
    return d;
}
__device__ inline void accum8(float* acc, float s, const uint4& a) {
    half2_t p;
    p = __builtin_bit_cast(half2_t, a.x); acc[0] += s * (float)p[0]; acc[1] += s * (float)p[1];
    p = __builtin_bit_cast(half2_t, a.y); acc[2] += s * (float)p[0]; acc[3] += s * (float)p[1];
    p = __builtin_bit_cast(half2_t, a.z); acc[4] += s * (float)p[0]; acc[5] += s * (float)p[1];
    p = __builtin_bit_cast(half2_t, a.w); acc[6] += s * (float)p[0]; acc[7] += s * (float)p[1];
}
__device__ inline void unpack8(float* f, const uint4& a) {
    half2_t p;
    p = __builtin_bit_cast(half2_t, a.x); f[0] = (float)p[0]; f[1] = (float)p[1];
    p = __builtin_bit_cast(half2_t, a.y); f[2] = (float)p[0]; f[3] = (float)p[1];
    p = __builtin_bit_cast(half2_t, a.z); f[4] = (float)p[0]; f[5] = (float)p[1];
    p = __builtin_bit_cast(half2_t, a.w); f[6] = (float)p[0]; f[7] = (float)p[1];
}
__device__ inline void dacc4(float4& a, unsigned xp_, const uint4& w) {
    a.x = fdot2_(xp_, w.x, a.x);
    a.y = fdot2_(xp_, w.y, a.y);
    a.z = fdot2_(xp_, w.z, a.z);
    a.w = fdot2_(xp_, w.w, a.w);
}
template<int CTRL>
__device__ inline float dppadd(float d) {
    int x = __builtin_amdgcn_update_dpp(0, __builtin_bit_cast(int, d),
                                        CTRL, 0xf, 0xf, true);
    return d + __builtin_bit_cast(float, x);
}
__device__ inline float red8(float d) {
    d = dppadd<0xB1>(d);    // quad_perm xor1
    d = dppadd<0x4E>(d);    // quad_perm xor2
    d = dppadd<0x141>(d);   // row_half_mirror
    return d;
}
__device__ inline float red16(float d) {
    d = dppadd<0xB1>(d);
    d = dppadd<0x4E>(d);
    d = dppadd<0x141>(d);
    d = dppadd<0x140>(d);
    return d;
}
#define EXP2(x) __builtin_amdgcn_exp2f(x)

// ---------------- CSR build: bucketed counting sort (no self loops) ----------------

__global__ __launch_bounds__(256) void k_hist(const int* __restrict__ ei, int E,
                                              int* __restrict__ bucket_cnt,
                                              int* __restrict__ blk_cnt, int nbuck) {
    __shared__ int lh[MAXB];
    int tid = threadIdx.x;
    for (int i = tid; i < nbuck; i += 256) lh[i] = 0;
    __syncthreads();
    int base = blockIdx.x * 4096;
    int end = min(base + 4096, E);
    for (int e = base + tid; e < end; e += 256)
        atomicAdd(&lh[ei[E + e] >> SHIFT], 1);
    __syncthreads();
    for (int i = tid; i < nbuck; i += 256) {
        int v = lh[i];
        blk_cnt[blockIdx.x * MAXB + i] = v;
        if (v) atomicAdd(&bucket_cnt[i], v);
    }
}

__global__ __launch_bounds__(256) void k_bscan(const int* __restrict__ bucket_cnt,
                                               int* __restrict__ pair_base,
                                               int* __restrict__ pair_fill,
                                               int* __restrict__ row_ptr,
                                               int n, int E, int nbuck) {
    __shared__ int tmp[MAXB];
    int tid = threadIdx.x;
    int cnt = (tid < nbuck) ? bucket_cnt[tid] : 0;
    tmp[tid] = cnt;
    __syncthreads();
    for (int off = 1; off < 256; off <<= 1) {
        int t = (tid >= off) ? tmp[tid - off] : 0;
        __syncthreads();
        tmp[tid] += t;
        __syncthreads();
    }
    if (tid < nbuck) { int pb = tmp[tid] - cnt; pair_base[tid] = pb; pair_fill[tid] = pb; }
    if (tid == 0) row_ptr[n] = E;
}

__global__ __launch_bounds__(256) void k_bin(const int* __restrict__ ei, int E,
                                             const int* __restrict__ blk_cnt,
                                             int* __restrict__ pair_fill,
                                             unsigned* __restrict__ pairs, int nbuck) {
    __shared__ int lbase[MAXB];
    int tid = threadIdx.x;
    for (int i = tid; i < nbuck; i += 256) {
        int v = blk_cnt[blockIdx.x * MAXB + i];
        lbase[i] = v ? atomicAdd(&pair_fill[i], v) : 0;
    }
    __syncthreads();
    int base = blockIdx.x * 4096;
    int end = min(base + 4096, E);
    for (int e = base + tid; e < end; e += 256) {
        int s = ei[e], d = ei[E + e];
        int pos = atomicAdd(&lbase[d >> SHIFT], 1);
        pairs[pos] = (unsigned)s | ((unsigned)(d & ((1 << SHIFT) - 1)) << 17);
    }
}

__global__ __launch_bounds__(256) void k_build(const unsigned* __restrict__ pairs,
                                               const int* __restrict__ pair_base,
                                               const int* __restrict__ bucket_cnt,
                                               int* __restrict__ row_ptr,
                                               int* __restrict__ csr_src, int n) {
    __shared__ int cnt[1 << SHIFT];
    __shared__ int offs[1 << SHIFT];
    __shared__ int stmp[256];
    __shared__ unsigned plds[PLDS];     // 48 KB staging: single global read
    int b = blockIdx.x;
    int tid = threadIdx.x;
    int nb0 = b << SHIFT;
    int W = min(n - nb0, 1 << SHIFT);
    int p0 = pair_base[b], pc = bucket_cnt[b];
    bool inl = (pc <= PLDS);

    cnt[tid] = 0; cnt[tid + 256] = 0;
    if (inl) for (int i = tid; i < pc; i += 256) plds[i] = pairs[p0 + i];
    __syncthreads();
    if (inl) {
        for (int i = tid; i < pc; i += 256) atomicAdd(&cnt[plds[i] >> 17], 1);
    } else {
        for (int i = tid; i < pc; i += 256) atomicAdd(&cnt[pairs[p0 + i] >> 17], 1);
    }
    __syncthreads();

    int i0 = 2 * tid, i1 = 2 * tid + 1;
    int s0 = (i0 < W) ? cnt[i0] : 0;
    int s1 = (i1 < W) ? cnt[i1] : 0;
    int ps = s0 + s1;
    stmp[tid] = ps;
    __syncthreads();
    for (int off = 1; off < 256; off <<= 1) {
        int t = (tid >= off) ? stmp[tid - off] : 0;
        __syncthreads();
        stmp[tid] += t;
        __syncthreads();
    }
    int excl = stmp[tid] - ps;
    if (i0 < W) { row_ptr[nb0 + i0] = p0 + excl;      offs[i0] = excl; }
    if (i1 < W) { row_ptr[nb0 + i1] = p0 + excl + s0; offs[i1] = excl + s0; }
    __syncthreads();
    if (inl) {
        for (int i = tid; i < pc; i += 256) {
            unsigned pr = plds[i];
            int pos = atomicAdd(&offs[pr >> 17], 1);
            csr_src[p0 + pos] = (int)(pr & SRCM);
        }
    } else {
        for (int i = tid; i < pc; i += 256) {
            unsigned pr = pairs[p0 + i];
            int pos = atomicAdd(&offs[pr >> 17], 1);
            csr_src[p0 + pos] = (int)(pr & SRCM);
        }
    }
}

// ---------------- Linear1: fp16-pair dot2 GEMM + ReLU + normalize, fp16 out ----------------

__global__ __launch_bounds__(256, 4) void k_linear1(const float* __restrict__ x,
                                                    const float* __restrict__ W1,
                                                    const float* __restrict__ b1,
                                                    uint2* __restrict__ X1,
                                                    float* __restrict__ nrm1, int n) {
    __shared__ unsigned Wp[64 * 64];
    __shared__ unsigned xp[64 * 64];
    int tid = threadIdx.x;
    int base = blockIdx.x * NPB;

    for (int t = tid; t < 1024; t += 256) {
        int kp = t >> 4;
        int c4 = t & 15;
        float4 a = ((const float4*)W1)[(2 * kp) * 16 + c4];
        float4 b = ((const float4*)W1)[(2 * kp + 1) * 16 + c4];
        uint4 w;
        w.x = pkh(a.x, b.x); w.y = pkh(a.y, b.y);
        w.z = pkh(a.z, b.z); w.w = pkh(a.w, b.w);
        *(uint4*)&Wp[kp * 64 + c4 * 4] = w;
    }
    for (int t = tid; t < 1024; t += 256) {
        int nl = t >> 4;
        int k8 = t & 15;
        int gn = base + nl;
        float4 a, b;
        if (gn < n) {
            a = ((const float4*)x)[(size_t)gn * 32 + k8 * 2];
            b = ((const float4*)x)[(size_t)gn * 32 + k8 * 2 + 1];
        } else { a = make_float4(0,0,0,0); b = a; }
        uint4 v;
        v.x = pkh(a.x, a.y); v.y = pkh(a.z, a.w);
        v.z = pkh(b.x, b.y); v.w = pkh(b.z, b.w);
        int key = ((nl >> 2) & 3) << 2;
        *(uint4*)&xp[nl * 64 + ((k8 * 4) ^ key)] = v;
    }
    __syncthreads();

    int cg = tid & 15;
    int ng = tid >> 4;
    int n0 = ng * 4;
    const int key = (ng & 3) << 2;
    float4 acc0 = {0,0,0,0}, acc1 = {0,0,0,0}, acc2 = {0,0,0,0}, acc3 = {0,0,0,0};

    #pragma unroll 4
    for (int k4 = 0; k4 < 64; k4 += 4) {
        uint4 xq0 = *(uint4*)&xp[(n0 + 0) * 64 + (k4 ^ key)];
        uint4 xq1 = *(uint4*)&xp[(n0 + 1) * 64 + (k4 ^ key)];
        uint4 xq2 = *(uint4*)&xp[(n0 + 2) * 64 + (k4 ^ key)];
        uint4 xq3 = *(uint4*)&xp[(n0 + 3) * 64 + (k4 ^ key)];
        uint4 wq0 = *(uint4*)&Wp[(k4 + 0) * 64 + cg * 4];
        uint4 wq1 = *(uint4*)&Wp[(k4 + 1) * 64 + cg * 4];
        uint4 wq2 = *(uint4*)&Wp[(k4 + 2) * 64 + cg * 4];
        uint4 wq3 = *(uint4*)&Wp[(k4 + 3) * 64 + cg * 4];
        dacc4(acc0, xq0.x, wq0); dacc4(acc0, xq0.y, wq1); dacc4(acc0, xq0.z, wq2); dacc4(acc0, xq0.w, wq3);
        dacc4(acc1, xq1.x, wq0); dacc4(acc1, xq1.y, wq1); dacc4(acc1, xq1.z, wq2); dacc4(acc1, xq1.w, wq3);
        dacc4(acc2, xq2.x, wq0); dacc4(acc2, xq2.y, wq1); dacc4(acc2, xq2.z, wq2); dacc4(acc2, xq2.w, wq3);
        dacc4(acc3, xq3.x, wq0); dacc4(acc3, xq3.y, wq1); dacc4(acc3, xq3.z, wq2); dacc4(acc3, xq3.w, wq3);
    }

    float4 bb = ((const float4*)b1)[cg];
    float4 r[4] = {acc0, acc1, acc2, acc3};
    #pragma unroll
    for (int nl = 0; nl < 4; ++nl) {
        int node = base + n0 + nl;
        float4 v = r[nl];
        v.x = fmaxf(v.x + bb.x, 0.f); v.y = fmaxf(v.y + bb.y, 0.f);
        v.z = fmaxf(v.z + bb.z, 0.f); v.w = fmaxf(v.w + bb.w, 0.f);
        float q = v.x * v.x + v.y * v.y + v.z * v.z + v.w * v.w;
        q = red16(q);
        float rq = rsqrtf(fmaxf(q, 1e-24f));
        if (node < n) {
            X1[(size_t)node * 16 + cg] = make_uint2(pkh(v.x * rq, v.y * rq),
                                                    pkh(v.z * rq, v.w * rq));
            if (cg == 0) nrm1[node] = sqrtf(fmaxf(q, 1e-24f));
        }
    }
}

// ---------------- AGNN propagation ----------------
// unpredicated 16-edge main loop + 8-edge predicated tail

template<bool HFOUT>
__global__ __launch_bounds__(256) void k_prop(const uint4* __restrict__ X,
                                              const float* __restrict__ nrm,
                                              const int* __restrict__ row_ptr,
                                              const int* __restrict__ csr_src,
                                              const float* __restrict__ beta_ptr,
                                              uint4* __restrict__ Xout,
                                              float* __restrict__ nrm_out,
                                              float4* __restrict__ outf, int n) {
    int node = blockIdx.x * 4 + (threadIdx.x >> 6);
    if (node >= n) return;
    int lane = threadIdx.x & 63;
    int g = lane >> 3, gl = lane & 7;
    float beta = beta_ptr ? beta_ptr[0] : 1.0f;
    float b2 = beta * 1.4426950408889634f;

    uint4 hdp = X[(size_t)node * 8 + gl];
    float hdf[8]; unpack8(hdf, hdp);
    int s0 = row_ptr[node], s1 = row_ptr[node + 1];

    float ds = red8(dot4(hdp, hdp));
    float eself = EXP2(b2 * ds);
    float nd = nrm[node];
    float den0 = (g == 0) ? eself : 0.f;
    float es = (g == 0) ? eself * nd : 0.f;
    float acc[8];
    #pragma unroll
    for (int c = 0; c < 8; ++c) acc[c] = es * hdf[c];
    float den1 = 0.f;

    int j = s0;
    // main: 16 edges per iter, fully valid -> no predication
    for (; j + 16 <= s1; j += 16) {
        int i0 = csr_src[j + g];
        int i1 = csr_src[j + 8 + g];
        uint4 a0 = X[(size_t)i0 * 8 + gl];
        uint4 a1 = X[(size_t)i1 * 8 + gl];
        float n0 = nrm[i0], n1 = nrm[i1];
        float d0 = red8(dot4(a0, hdp));
        float d1 = red8(dot4(a1, hdp));
        float e0 = EXP2(b2 * d0);
        float e1 = EXP2(b2 * d1);
        den0 += e0; den1 += e1;
        accum8(acc, e0 * n0, a0);
        accum8(acc, e1 * n1, a1);
    }
    // tail: 8 edges per iter, predicated
    for (; j < s1; j += 8) {
        int p0 = j + g;
        bool v0 = p0 < s1;
        int i0 = v0 ? csr_src[p0] : 0;
        uint4 a0 = X[(size_t)i0 * 8 + gl];
        float n0 = nrm[i0];
        float d0 = red8(dot4(a0, hdp));
        float e0 = v0 ? EXP2(b2 * d0) : 0.f;
        den0 += e0;
        accum8(acc, e0 * n0, a0);
    }

    float den = den0 + den1;
    #pragma unroll
    for (int c = 0; c < 8; ++c) {
        acc[c] += __shfl_xor(acc[c], 8, 64);
        acc[c] += __shfl_xor(acc[c], 16, 64);
        acc[c] += __shfl_xor(acc[c], 32, 64);
    }
    den += __shfl_xor(den, 8, 64);
    den += __shfl_xor(den, 16, 64);
    den += __shfl_xor(den, 32, 64);
    float inv = 1.0f / den;
    float o[8];
    #pragma unroll
    for (int c = 0; c < 8; ++c) o[c] = acc[c] * inv;

    if (HFOUT) {
        float q = 0.f;
        #pragma unroll
        for (int c = 0; c < 8; ++c) q += o[c] * o[c];
        q = red8(q);
        float rq = rsqrtf(fmaxf(q, 1e-24f));
        if (g == 0) {
            uint4 w;
            w.x = pkh(o[0] * rq, o[1] * rq);
            w.y = pkh(o[2] * rq, o[3] * rq);
            w.z = pkh(o[4] * rq, o[5] * rq);
            w.w = pkh(o[6] * rq, o[7] * rq);
            Xout[(size_t)node * 8 + gl] = w;
            if (gl == 0) nrm_out[node] = sqrtf(fmaxf(q, 1e-24f));
        }
    } else {
        if (g == 0) {
            outf[(size_t)node * 16 + gl * 2]     = make_float4(o[0], o[1], o[2], o[3]);
            outf[(size_t)node * 16 + gl * 2 + 1] = make_float4(o[4], o[5], o[6], o[7]);
        }
    }
}

// ---------------- Linear2 + log_softmax: register-tiled ----------------

__global__ __launch_bounds__(256) void k_out(const float* __restrict__ h,
                                             const float* __restrict__ W2,
                                             const float* __restrict__ b2,
                                             float* __restrict__ out, int n) {
    __shared__ float hs[ONB * HID];
    __shared__ float W2s[HID * OUTC];
    __shared__ float ls[ONB * LSW];
    int tid = threadIdx.x;
    int base = blockIdx.x * ONB;

    for (int i = tid; i < HID * OUTC / 4; i += 256)
        ((float4*)W2s)[i] = ((const float4*)W2)[i];
    for (int i = tid; i < ONB * 16; i += 256) {
        int nl = i >> 4, k4 = i & 15;
        int gn = base + nl;
        float4 v = (gn < n) ? ((const float4*)h)[(size_t)gn * 16 + k4]
                            : make_float4(0.f, 0.f, 0.f, 0.f);
        int swk = (k4 * 4) ^ (((nl >> 2) & 7) << 2);
        *(float4*)&hs[nl * HID + swk] = v;
    }
    __syncthreads();

    if (tid < 240) {
        int ng = tid / 10, cg = tid % 10;
        int n0 = ng * 4;
        const int sw = ((ng & 7) << 2);
        float4 acc0 = {0,0,0,0}, acc1 = {0,0,0,0}, acc2 = {0,0,0,0}, acc3 = {0,0,0,0};
        #pragma unroll 4
        for (int k = 0; k < HID; k += 4) {
            float4 w0 = *(float4*)&W2s[(k + 0) * OUTC + cg * 4];
            float4 w1 = *(float4*)&W2s[(k + 1) * OUTC + cg * 4];
            float4 w2 = *(float4*)&W2s[(k + 2) * OUTC + cg * 4];
            float4 w3 = *(float4*)&W2s[(k + 3) * OUTC + cg * 4];
            float4 x0 = *(float4*)&hs[(n0 + 0) * HID + (k ^ sw)];
            float4 x1 = *(float4*)&hs[(n0 + 1) * HID + (k ^ sw)];
            float4 x2 = *(float4*)&hs[(n0 + 2) * HID + (k ^ sw)];
            float4 x3 = *(float4*)&hs[(n0 + 3) * HID + (k ^ sw)];
            fma4(acc0, x0.x, w0); fma4(acc0, x0.y, w1); fma4(acc0, x0.z, w2); fma4(acc0, x0.w, w3);
            fma4(acc1, x1.x, w0); fma4(acc1, x1.y, w1); fma4(acc1, x1.z, w2); fma4(acc1, x1.w, w3);
            fma4(acc2, x2.x, w0); fma4(acc2, x2.y, w1); fma4(acc2, x2.z, w2); fma4(acc2, x2.w, w3);
            fma4(acc3, x3.x, w0); fma4(acc3, x3.y, w1); fma4(acc3, x3.z, w2); fma4(acc3, x3.w, w3);
        }
        float4 bb = ((const float4*)b2)[cg];
        float4 rr[4] = {acc0, acc1, acc2, acc3};
        #pragma unroll
        for (int i = 0; i < 4; ++i) {
            int lb = (n0 + i) * LSW + cg * 4;
            ls[lb + 0] = rr[i].x + bb.x;
            ls[lb + 1] = rr[i].y + bb.y;
            ls[lb + 2] = rr[i].z + bb.z;
            ls[lb + 3] = rr[i].w + bb.w;
        }
    }
    __syncthreads();

    if (tid < ONB) {
        int node = base + tid;
        if (node < n) {
            float m = -INFINITY;
            #pragma unroll
            for (int c = 0; c < OUTC; ++c) m = fmaxf(m, ls[tid * LSW + c]);
            float z = 0.f;
            #pragma unroll
            for (int c = 0; c < OUTC; ++c) z += __expf(ls[tid * LSW + c] - m);
            float lz = m + __logf(z);
            #pragma unroll
            for (int c = 0; c < OUTC; ++c)
                out[(size_t)node * OUTC + c] = ls[tid * LSW + c] - lz;
        }
    }
}

// ---------------- launch ----------------

extern "C" void kernel_launch(void* const* d_in, const int* in_sizes, int n_in,
                              void* d_out, int out_size, void* d_ws, size_t ws_size,
                              hipStream_t stream) {
    const float* x   = (const float*)d_in[0];
    const int*   ei  = (const int*)d_in[1];
    const float* W1  = (const float*)d_in[2];
    const float* b1  = (const float*)d_in[3];
    const float* W2  = (const float*)d_in[4];
    const float* b2  = (const float*)d_in[5];
    const float* beta2 = (const float*)d_in[6];
    float* out = (float*)d_out;

    const int n = in_sizes[0] / INC;       // 100000
    const int E = in_sizes[1] / 2;         // 1600000
    const int nbuck = (n + (1 << SHIFT) - 1) >> SHIFT;   // 196
    const int cgrid = (E + 4095) / 4096;   // 391

    // workspace layout
    char* p = (char*)d_ws;
    uint4* X1 = (uint4*)p;             p += (size_t)n * 8 * 16;
    uint4* X2 = (uint4*)p;             p += (size_t)n * 8 * 16;
    float* h3 = (float*)p;             p += (size_t)n * HID * 4;
    float* nrm1 = (float*)p;           p += (size_t)n * 4;
    float* nrm2 = (float*)p;           p += (size_t)n * 4;
    int* bucket_cnt  = (int*)p;        p += MAXB * 4;
    int* pair_base   = (int*)p;        p += MAXB * 4;
    int* pair_fill   = (int*)p;        p += MAXB * 4;
    int* row_ptr = (int*)p;            p += (size_t)(n + 1) * 4;
    int* csr_src = (int*)p;            p += (size_t)E * 4;
    int* blk_cnt = (int*)p;            p += (size_t)cgrid * MAXB * 4;
    unsigned* pairs = (unsigned*)h3;   // alias: pairs dead before prop2 writes h3

    // CSR build
    hipMemsetAsync(bucket_cnt, 0, MAXB * 4, stream);
    k_hist<<<cgrid, 256, 0, stream>>>(ei, E, bucket_cnt, blk_cnt, nbuck);
    k_bscan<<<1, 256, 0, stream>>>(bucket_cnt, pair_base, pair_fill, row_ptr, n, E, nbuck);
    k_bin<<<cgrid, 256, 0, stream>>>(ei, E, blk_cnt, pair_fill, pairs, nbuck);
    k_build<<<nbuck, 256, 0, stream>>>(pairs, pair_base, bucket_cnt, row_ptr, csr_src, n);

    // MLP front + props + head
    k_linear1<<<(n + NPB - 1) / NPB, 256, 0, stream>>>(x, W1, b1, (uint2*)X1, nrm1, n);
    int pgrid = (n + 3) / 4;
    k_prop<true><<<pgrid, 256, 0, stream>>>(X1, nrm1, row_ptr, csr_src, nullptr,
                                            X2, nrm2, nullptr, n);
    k_prop<false><<<pgrid, 256, 0, stream>>>(X2, nrm2, row_ptr, csr_src, beta2,
                                             nullptr, nullptr, (float4*)h3, n);
    k_out<<<(n + ONB - 1) / ONB, 256, 0, stream>>>(h3, W2, b2, out, n);
}

// Round 14
// 190.487 us; speedup vs baseline: 4.0231x; 1.0246x over previous
//
#include <hip/hip_runtime.h>
#include <math.h>

#define INC 128
#define HID 64
#define OUTC 40
#define SHIFT 9
#define MAXB 256
#define NPB 64
#define ONB 96
#define LSW 41
#define SRCM 0x1FFFF
#define PLDS 12288

typedef _Float16 half2_t __attribute__((ext_vector_type(2)));

__device__ inline void fma4(float4& a, float s, const float4& w) {
    a.x += s * w.x; a.y += s * w.y; a.z += s * w.z; a.w += s * w.w;
}
__device__ inline unsigned pkh(float a, float b) {
    unsigned short ua = __builtin_bit_cast(unsigned short, (_Float16)a);
    unsigned short ub = __builtin_bit_cast(unsigned short, (_Float16)b);
    return (unsigned)ua | ((unsigned)ub << 16);
}
__device__ inline float fdot2_(unsigned a, unsigned b, float c) {
#if __has_builtin(__builtin_amdgcn_fdot2)
    return __builtin_amdgcn_fdot2(__builtin_bit_cast(half2_t, a),
                                  __builtin_bit_cast(half2_t, b), c, false);
#else
    half2_t ha = __builtin_bit_cast(half2_t, a);
    half2_t hb = __builtin_bit_cast(half2_t, b);
    return fmaf((float)ha[0], (float)hb[0], fmaf((float)ha[1], (float)hb[1], c));
#endif
}
__device__ inline float dot4(const uint4& a, const uint4& b) {
    float d = fdot2_(a.x, b.x, 0.f);
    d = fdot2_(a.y, b.y, d);
    d = fdot2_(a.z, b.z, d);
    d = fdot2_(a.w, b.w, d);
    return d;
}
__device__ inline void accum8(float* acc, float s, const uint4& a) {
    half2_t p;
    p = __builtin_bit_cast(half2_t, a.x); acc[0] += s * (float)p[0]; acc[1] += s * (float)p[1];
    p = __builtin_bit_cast(half2_t, a.y); acc[2] += s * (float)p[0]; acc[3] += s * (float)p[1];
    p = __builtin_bit_cast(half2_t, a.z); acc[4] += s * (float)p[0]; acc[5] += s * (float)p[1];
    p = __builtin_bit_cast(half2_t, a.w); acc[6] += s * (float)p[0]; acc[7] += s * (float)p[1];
}
__device__ inline void unpack8(float* f, const uint4& a) {
    half2_t p;
    p = __builtin_bit_cast(half2_t, a.x); f[0] = (float)p[0]; f[1] = (float)p[1];
    p = __builtin_bit_cast(half2_t, a.y); f[2] = (float)p[0]; f[3] = (float)p[1];
    p = __builtin_bit_cast(half2_t, a.z); f[4] = (float)p[0]; f[5] = (float)p[1];
    p = __builtin_bit_cast(half2_t, a.w); f[6] = (float)p[0]; f[7] = (float)p[1];
}
__device__ inline void dacc4(float4& a, unsigned xp_, const uint4& w) {
    a.x = fdot2_(xp_, w.x, a.x);
    a.y = fdot2_(xp_, w.y, a.y);
    a.z = fdot2_(xp_, w.z, a.z);
    a.w = fdot2_(xp_, w.w, a.w);
}
template<int CTRL>
__device__ inline float dppadd(float d) {
    int x = __builtin_amdgcn_update_dpp(0, __builtin_bit_cast(int, d),
                                        CTRL, 0xf, 0xf, true);
    return d + __builtin_bit_cast(float, x);
}
__device__ inline float red8(float d) {
    d = dppadd<0xB1>(d);    // quad_perm xor1
    d = dppadd<0x4E>(d);    // quad_perm xor2
    d = dppadd<0x141>(d);   // row_half_mirror
    return d;
}
__device__ inline float red16(float d) {
    d = dppadd<0xB1>(d);
    d = dppadd<0x4E>(d);
    d = dppadd<0x141>(d);
    d = dppadd<0x140>(d);
    return d;
}
#define EXP2(x) __builtin_amdgcn_exp2f(x)

// ---------------- CSR build: bucketed counting sort (no self loops) ----------------

__global__ __launch_bounds__(256) void k_hist(const int* __restrict__ ei, int E,
                                              int* __restrict__ bucket_cnt,
                                              int* __restrict__ blk_cnt, int nbuck) {
    __shared__ int lh[MAXB];
    int tid = threadIdx.x;
    for (int i = tid; i < nbuck; i += 256) lh[i] = 0;
    __syncthreads();
    int base = blockIdx.x * 4096;
    int end = min(base + 4096, E);
    for (int e = base + tid; e < end; e += 256)
        atomicAdd(&lh[ei[E + e] >> SHIFT], 1);
    __syncthreads();
    for (int i = tid; i < nbuck; i += 256) {
        int v = lh[i];
        blk_cnt[blockIdx.x * MAXB + i] = v;
        if (v) atomicAdd(&bucket_cnt[i], v);
    }
}

__global__ __launch_bounds__(256) void k_bscan(const int* __restrict__ bucket_cnt,
                                               int* __restrict__ pair_base,
                                               int* __restrict__ pair_fill,
                                               int* __restrict__ row_ptr,
                                               int n, int E, int nbuck) {
    __shared__ int tmp[MAXB];
    int tid = threadIdx.x;
    int cnt = (tid < nbuck) ? bucket_cnt[tid] : 0;
    tmp[tid] = cnt;
    __syncthreads();
    for (int off = 1; off < 256; off <<= 1) {
        int t = (tid >= off) ? tmp[tid - off] : 0;
        __syncthreads();
        tmp[tid] += t;
        __syncthreads();
    }
    if (tid < nbuck) { int pb = tmp[tid] - cnt; pair_base[tid] = pb; pair_fill[tid] = pb; }
    if (tid == 0) row_ptr[n] = E;
}

__global__ __launch_bounds__(256) void k_bin(const int* __restrict__ ei, int E,
                                             const int* __restrict__ blk_cnt,
                                             int* __restrict__ pair_fill,
                                             unsigned* __restrict__ pairs, int nbuck) {
    __shared__ int lbase[MAXB];
    int tid = threadIdx.x;
    for (int i = tid; i < nbuck; i += 256) {
        int v = blk_cnt[blockIdx.x * MAXB + i];
        lbase[i] = v ? atomicAdd(&pair_fill[i], v) : 0;
    }
    __syncthreads();
    int base = blockIdx.x * 4096;
    int end = min(base + 4096, E);
    for (int e = base + tid; e < end; e += 256) {
        int s = ei[e], d = ei[E + e];
        int pos = atomicAdd(&lbase[d >> SHIFT], 1);
        pairs[pos] = (unsigned)s | ((unsigned)(d & ((1 << SHIFT) - 1)) << 17);
    }
}

__global__ __launch_bounds__(256) void k_build(const unsigned* __restrict__ pairs,
                                               const int* __restrict__ pair_base,
                                               const int* __restrict__ bucket_cnt,
                                               int* __restrict__ row_ptr,
                                               int* __restrict__ csr_src, int n) {
    __shared__ int cnt[1 << SHIFT];
    __shared__ int offs[1 << SHIFT];
    __shared__ int stmp[256];
    __shared__ unsigned plds[PLDS];
    int b = blockIdx.x;
    int tid = threadIdx.x;
    int nb0 = b << SHIFT;
    int W = min(n - nb0, 1 << SHIFT);
    int p0 = pair_base[b], pc = bucket_cnt[b];
    bool inl = (pc <= PLDS);

    cnt[tid] = 0; cnt[tid + 256] = 0;
    if (inl) for (int i = tid; i < pc; i += 256) plds[i] = pairs[p0 + i];
    __syncthreads();
    if (inl) {
        for (int i = tid; i < pc; i += 256) atomicAdd(&cnt[plds[i] >> 17], 1);
    } else {
        for (int i = tid; i < pc; i += 256) atomicAdd(&cnt[pairs[p0 + i] >> 17], 1);
    }
    __syncthreads();

    int i0 = 2 * tid, i1 = 2 * tid + 1;
    int s0 = (i0 < W) ? cnt[i0] : 0;
    int s1 = (i1 < W) ? cnt[i1] : 0;
    int ps = s0 + s1;
    stmp[tid] = ps;
    __syncthreads();
    for (int off = 1; off < 256; off <<= 1) {
        int t = (tid >= off) ? stmp[tid - off] : 0;
        __syncthreads();
        stmp[tid] += t;
        __syncthreads();
    }
    int excl = stmp[tid] - ps;
    if (i0 < W) { row_ptr[nb0 + i0] = p0 + excl;      offs[i0] = excl; }
    if (i1 < W) { row_ptr[nb0 + i1] = p0 + excl + s0; offs[i1] = excl + s0; }
    __syncthreads();
    if (inl) {
        for (int i = tid; i < pc; i += 256) {
            unsigned pr = plds[i];
            int pos = atomicAdd(&offs[pr >> 17], 1);
            csr_src[p0 + pos] = (int)(pr & SRCM);
        }
    } else {
        for (int i = tid; i < pc; i += 256) {
            unsigned pr = pairs[p0 + i];
            int pos = atomicAdd(&offs[pr >> 17], 1);
            csr_src[p0 + pos] = (int)(pr & SRCM);
        }
    }
}

// ---------------- Linear1: fp16-pair dot2 GEMM + ReLU + normalize, fp16 out ----------------

__global__ __launch_bounds__(256, 4) void k_linear1(const float* __restrict__ x,
                                                    const float* __restrict__ W1,
                                                    const float* __restrict__ b1,
                                                    uint2* __restrict__ X1,
                                                    float* __restrict__ nrm1, int n) {
    __shared__ unsigned Wp[64 * 64];
    __shared__ unsigned xp[64 * 64];
    int tid = threadIdx.x;
    int base = blockIdx.x * NPB;

    for (int t = tid; t < 1024; t += 256) {
        int kp = t >> 4;
        int c4 = t & 15;
        float4 a = ((const float4*)W1)[(2 * kp) * 16 + c4];
        float4 b = ((const float4*)W1)[(2 * kp + 1) * 16 + c4];
        uint4 w;
        w.x = pkh(a.x, b.x); w.y = pkh(a.y, b.y);
        w.z = pkh(a.z, b.z); w.w = pkh(a.w, b.w);
        *(uint4*)&Wp[kp * 64 + c4 * 4] = w;
    }
    for (int t = tid; t < 1024; t += 256) {
        int nl = t >> 4;
        int k8 = t & 15;
        int gn = base + nl;
        float4 a, b;
        if (gn < n) {
            a = ((const float4*)x)[(size_t)gn * 32 + k8 * 2];
            b = ((const float4*)x)[(size_t)gn * 32 + k8 * 2 + 1];
        } else { a = make_float4(0,0,0,0); b = a; }
        uint4 v;
        v.x = pkh(a.x, a.y); v.y = pkh(a.z, a.w);
        v.z = pkh(b.x, b.y); v.w = pkh(b.z, b.w);
        int key = ((nl >> 2) & 3) << 2;
        *(uint4*)&xp[nl * 64 + ((k8 * 4) ^ key)] = v;
    }
    __syncthreads();

    int cg = tid & 15;
    int ng = tid >> 4;
    int n0 = ng * 4;
    const int key = (ng & 3) << 2;
    float4 acc0 = {0,0,0,0}, acc1 = {0,0,0,0}, acc2 = {0,0,0,0}, acc3 = {0,0,0,0};

    #pragma unroll 4
    for (int k4 = 0; k4 < 64; k4 += 4) {
        uint4 xq0 = *(uint4*)&xp[(n0 + 0) * 64 + (k4 ^ key)];
        uint4 xq1 = *(uint4*)&xp[(n0 + 1) * 64 + (k4 ^ key)];
        uint4 xq2 = *(uint4*)&xp[(n0 + 2) * 64 + (k4 ^ key)];
        uint4 xq3 = *(uint4*)&xp[(n0 + 3) * 64 + (k4 ^ key)];
        uint4 wq0 = *(uint4*)&Wp[(k4 + 0) * 64 + cg * 4];
        uint4 wq1 = *(uint4*)&Wp[(k4 + 1) * 64 + cg * 4];
        uint4 wq2 = *(uint4*)&Wp[(k4 + 2) * 64 + cg * 4];
        uint4 wq3 = *(uint4*)&Wp[(k4 + 3) * 64 + cg * 4];
        dacc4(acc0, xq0.x, wq0); dacc4(acc0, xq0.y, wq1); dacc4(acc0, xq0.z, wq2); dacc4(acc0, xq0.w, wq3);
        dacc4(acc1, xq1.x, wq0); dacc4(acc1, xq1.y, wq1); dacc4(acc1, xq1.z, wq2); dacc4(acc1, xq1.w, wq3);
        dacc4(acc2, xq2.x, wq0); dacc4(acc2, xq2.y, wq1); dacc4(acc2, xq2.z, wq2); dacc4(acc2, xq2.w, wq3);
        dacc4(acc3, xq3.x, wq0); dacc4(acc3, xq3.y, wq1); dacc4(acc3, xq3.z, wq2); dacc4(acc3, xq3.w, wq3);
    }

    float4 bb = ((const float4*)b1)[cg];
    float4 r[4] = {acc0, acc1, acc2, acc3};
    #pragma unroll
    for (int nl = 0; nl < 4; ++nl) {
        int node = base + n0 + nl;
        float4 v = r[nl];
        v.x = fmaxf(v.x + bb.x, 0.f); v.y = fmaxf(v.y + bb.y, 0.f);
        v.z = fmaxf(v.z + bb.z, 0.f); v.w = fmaxf(v.w + bb.w, 0.f);
        float q = v.x * v.x + v.y * v.y + v.z * v.z + v.w * v.w;
        q = red16(q);
        float rq = rsqrtf(fmaxf(q, 1e-24f));
        if (node < n) {
            X1[(size_t)node * 16 + cg] = make_uint2(pkh(v.x * rq, v.y * rq),
                                                    pkh(v.z * rq, v.w * rq));
            if (cg == 0) nrm1[node] = sqrtf(fmaxf(q, 1e-24f));
        }
    }
}

// ---------------- AGNN propagation ----------------
// 2-deep software-pipelined predicated 16-edge loop; analytic self-edge

template<bool HFOUT>
__global__ __launch_bounds__(256) void k_prop(const uint4* __restrict__ X,
                                              const float* __restrict__ nrm,
                                              const int* __restrict__ row_ptr,
                                              const int* __restrict__ csr_src,
                                              const float* __restrict__ beta_ptr,
                                              uint4* __restrict__ Xout,
                                              float* __restrict__ nrm_out, int n) {
    int node = blockIdx.x * 4 + (threadIdx.x >> 6);
    if (node >= n) return;
    int lane = threadIdx.x & 63;
    int g = lane >> 3, gl = lane & 7;
    float beta = beta_ptr ? beta_ptr[0] : 1.0f;
    float b2 = beta * 1.4426950408889634f;

    uint4 hdp = X[(size_t)node * 8 + gl];
    int s0 = row_ptr[node], s1 = row_ptr[node + 1];
    float nd = nrm[node];

    // self-edge: dot(xn,xn)=1 by construction (zero rows: nrm sentinel 1e-12 -> alpha 0)
    float eself = (nd > 1.5e-12f) ? EXP2(b2) : 1.0f;
    float den0 = (g == 0) ? eself : 0.f;
    float es = (g == 0) ? eself * nd : 0.f;
    float acc[8] = {0, 0, 0, 0, 0, 0, 0, 0};
    accum8(acc, es, hdp);
    float den1 = 0.f;

    if (s0 < s1) {
        int last = s1 - 1;
        int i0 = csr_src[min(s0 + g, last)];
        int i1 = csr_src[min(s0 + 8 + g, last)];
        uint4 a0 = X[(size_t)i0 * 8 + gl];
        uint4 a1 = X[(size_t)i1 * 8 + gl];
        float n0 = nrm[i0], n1 = nrm[i1];
        bool v0 = s0 + g < s1, v1 = s0 + 8 + g < s1;
        for (int j = s0 + 16; j < s1; j += 16) {
            // prefetch next block
            int i0n = csr_src[min(j + g, last)];
            int i1n = csr_src[min(j + 8 + g, last)];
            uint4 a0n = X[(size_t)i0n * 8 + gl];
            uint4 a1n = X[(size_t)i1n * 8 + gl];
            float n0n = nrm[i0n], n1n = nrm[i1n];
            // compute current block
            float d0 = red8(dot4(a0, hdp));
            float d1 = red8(dot4(a1, hdp));
            float e0 = v0 ? EXP2(b2 * d0) : 0.f;
            float e1 = v1 ? EXP2(b2 * d1) : 0.f;
            den0 += e0; den1 += e1;
            accum8(acc, e0 * n0, a0);
            accum8(acc, e1 * n1, a1);
            a0 = a0n; a1 = a1n; n0 = n0n; n1 = n1n;
            v0 = j + g < s1; v1 = j + 8 + g < s1;
        }
        // last block
        float d0 = red8(dot4(a0, hdp));
        float d1 = red8(dot4(a1, hdp));
        float e0 = v0 ? EXP2(b2 * d0) : 0.f;
        float e1 = v1 ? EXP2(b2 * d1) : 0.f;
        den0 += e0; den1 += e1;
        accum8(acc, e0 * n0, a0);
        accum8(acc, e1 * n1, a1);
    }

    float den = den0 + den1;
    #pragma unroll
    for (int c = 0; c < 8; ++c) {
        acc[c] += __shfl_xor(acc[c], 8, 64);
        acc[c] += __shfl_xor(acc[c], 16, 64);
        acc[c] += __shfl_xor(acc[c], 32, 64);
    }
    den += __shfl_xor(den, 8, 64);
    den += __shfl_xor(den, 16, 64);
    den += __shfl_xor(den, 32, 64);
    float inv = 1.0f / den;
    float o[8];
    #pragma unroll
    for (int c = 0; c < 8; ++c) o[c] = acc[c] * inv;

    if (HFOUT) {
        // normalized fp16 + magnitude (feeds prop2)
        float q = 0.f;
        #pragma unroll
        for (int c = 0; c < 8; ++c) q += o[c] * o[c];
        q = red8(q);
        float rq = rsqrtf(fmaxf(q, 1e-24f));
        if (g == 0) {
            uint4 w;
            w.x = pkh(o[0] * rq, o[1] * rq);
            w.y = pkh(o[2] * rq, o[3] * rq);
            w.z = pkh(o[4] * rq, o[5] * rq);
            w.w = pkh(o[6] * rq, o[7] * rq);
            Xout[(size_t)node * 8 + gl] = w;
            if (gl == 0) nrm_out[node] = sqrtf(fmaxf(q, 1e-24f));
        }
    } else {
        // raw fp16 features (feeds k_out)
        if (g == 0) {
            uint4 w;
            w.x = pkh(o[0], o[1]); w.y = pkh(o[2], o[3]);
            w.z = pkh(o[4], o[5]); w.w = pkh(o[6], o[7]);
            Xout[(size_t)node * 8 + gl] = w;
        }
    }
}

// ---------------- Linear2 + log_softmax: register-tiled, fp16 input ----------------

__global__ __launch_bounds__(256) void k_out(const uint4* __restrict__ Xh,
                                             const float* __restrict__ W2,
                                             const float* __restrict__ b2,
                                             float* __restrict__ out, int n) {
    __shared__ float hs[ONB * HID];
    __shared__ float W2s[HID * OUTC];
    __shared__ float ls[ONB * LSW];
    int tid = threadIdx.x;
    int base = blockIdx.x * ONB;

    for (int i = tid; i < HID * OUTC / 4; i += 256)
        ((float4*)W2s)[i] = ((const float4*)W2)[i];
    for (int i = tid; i < ONB * 8; i += 256) {
        int nl = i >> 3, k8 = i & 7;
        int gn = base + nl;
        uint4 v = (gn < n) ? Xh[(size_t)gn * 8 + k8] : make_uint4(0, 0, 0, 0);
        float f[8]; unpack8(f, v);
        int key = ((nl >> 2) & 7) << 2;
        *(float4*)&hs[nl * HID + ((k8 * 8) ^ key)]     = make_float4(f[0], f[1], f[2], f[3]);
        *(float4*)&hs[nl * HID + ((k8 * 8 + 4) ^ key)] = make_float4(f[4], f[5], f[6], f[7]);
    }
    __syncthreads();

    if (tid < 240) {
        int ng = tid / 10, cg = tid % 10;
        int n0 = ng * 4;
        const int sw = ((ng & 7) << 2);
        float4 acc0 = {0,0,0,0}, acc1 = {0,0,0,0}, acc2 = {0,0,0,0}, acc3 = {0,0,0,0};
        #pragma unroll 4
        for (int k = 0; k < HID; k += 4) {
            float4 w0 = *(float4*)&W2s[(k + 0) * OUTC + cg * 4];
            float4 w1 = *(float4*)&W2s[(k + 1) * OUTC + cg * 4];
            float4 w2 = *(float4*)&W2s[(k + 2) * OUTC + cg * 4];
            float4 w3 = *(float4*)&W2s[(k + 3) * OUTC + cg * 4];
            float4 x0 = *(float4*)&hs[(n0 + 0) * HID + (k ^ sw)];
            float4 x1 = *(float4*)&hs[(n0 + 1) * HID + (k ^ sw)];
            float4 x2 = *(float4*)&hs[(n0 + 2) * HID + (k ^ sw)];
            float4 x3 = *(float4*)&hs[(n0 + 3) * HID + (k ^ sw)];
            fma4(acc0, x0.x, w0); fma4(acc0, x0.y, w1); fma4(acc0, x0.z, w2); fma4(acc0, x0.w, w3);
            fma4(acc1, x1.x, w0); fma4(acc1, x1.y, w1); fma4(acc1, x1.z, w2); fma4(acc1, x1.w, w3);
            fma4(acc2, x2.x, w0); fma4(acc2, x2.y, w1); fma4(acc2, x2.z, w2); fma4(acc2, x2.w, w3);
            fma4(acc3, x3.x, w0); fma4(acc3, x3.y, w1); fma4(acc3, x3.z, w2); fma4(acc3, x3.w, w3);
        }
        float4 bb = ((const float4*)b2)[cg];
        float4 rr[4] = {acc0, acc1, acc2, acc3};
        #pragma unroll
        for (int i = 0; i < 4; ++i) {
            int lb = (n0 + i) * LSW + cg * 4;
            ls[lb + 0] = rr[i].x + bb.x;
            ls[lb + 1] = rr[i].y + bb.y;
            ls[lb + 2] = rr[i].z + bb.z;
            ls[lb + 3] = rr[i].w + bb.w;
        }
    }
    __syncthreads();

    if (tid < ONB) {
        int node = base + tid;
        if (node < n) {
            float m = -INFINITY;
            #pragma unroll
            for (int c = 0; c < OUTC; ++c) m = fmaxf(m, ls[tid * LSW + c]);
            float z = 0.f;
            #pragma unroll
            for (int c = 0; c < OUTC; ++c) z += __expf(ls[tid * LSW + c] - m);
            float lz = m + __logf(z);
            #pragma unroll
            for (int c = 0; c < OUTC; ++c)
                out[(size_t)node * OUTC + c] = ls[tid * LSW + c] - lz;
        }
    }
}

// ---------------- launch ----------------

extern "C" void kernel_launch(void* const* d_in, const int* in_sizes, int n_in,
                              void* d_out, int out_size, void* d_ws, size_t ws_size,
                              hipStream_t stream) {
    const float* x   = (const float*)d_in[0];
    const int*   ei  = (const int*)d_in[1];
    const float* W1  = (const float*)d_in[2];
    const float* b1  = (const float*)d_in[3];
    const float* W2  = (const float*)d_in[4];
    const float* b2  = (const float*)d_in[5];
    const float* beta2 = (const float*)d_in[6];
    float* out = (float*)d_out;

    const int n = in_sizes[0] / INC;       // 100000
    const int E = in_sizes[1] / 2;         // 1600000
    const int nbuck = (n + (1 << SHIFT) - 1) >> SHIFT;   // 196
    const int cgrid = (E + 4095) / 4096;   // 391

    // workspace layout
    char* p = (char*)d_ws;
    uint4* X1 = (uint4*)p;             p += (size_t)n * 8 * 16;   // 12.8 MB fp16 normalized
    uint4* X2 = (uint4*)p;             p += (size_t)n * 8 * 16;   // 12.8 MB
    uint4* X3 = (uint4*)p;             p += (size_t)n * 8 * 16;   // 12.8 MB fp16 raw (prop2 out)
    float* nrm1 = (float*)p;           p += (size_t)n * 4;
    float* nrm2 = (float*)p;           p += (size_t)n * 4;
    int* bucket_cnt  = (int*)p;        p += MAXB * 4;
    int* pair_base   = (int*)p;        p += MAXB * 4;
    int* pair_fill   = (int*)p;        p += MAXB * 4;
    int* row_ptr = (int*)p;            p += (size_t)(n + 1) * 4;
    int* csr_src = (int*)p;            p += (size_t)E * 4;
    int* blk_cnt = (int*)p;            p += (size_t)cgrid * MAXB * 4;
    unsigned* pairs = (unsigned*)X3;   // alias: pairs dead before prop2 writes X3

    // CSR build
    (void)hipMemsetAsync(bucket_cnt, 0, MAXB * 4, stream);
    k_hist<<<cgrid, 256, 0, stream>>>(ei, E, bucket_cnt, blk_cnt, nbuck);
    k_bscan<<<1, 256, 0, stream>>>(bucket_cnt, pair_base, pair_fill, row_ptr, n, E, nbuck);
    k_bin<<<cgrid, 256, 0, stream>>>(ei, E, blk_cnt, pair_fill, pairs, nbuck);
    k_build<<<nbuck, 256, 0, stream>>>(pairs, pair_base, bucket_cnt, row_ptr, csr_src, n);

    // MLP front + props + head
    k_linear1<<<(n + NPB - 1) / NPB, 256, 0, stream>>>(x, W1, b1, (uint2*)X1, nrm1, n);
    int pgrid = (n + 3) / 4;
    k_prop<true><<<pgrid, 256, 0, stream>>>(X1, nrm1, row_ptr, csr_src, nullptr,
                                            X2, nrm2, n);
    k_prop<false><<<pgrid, 256, 0, stream>>>(X2, nrm2, row_ptr, csr_src, beta2,
                                             X3, nullptr, n);
    k_out<<<(n + ONB - 1) / ONB, 256, 0, stream>>>(X3, W2, b2, out, n);
}

// Round 15
// 181.173 us; speedup vs baseline: 4.2300x; 1.0514x over previous
//
#include <hip/hip_runtime.h>
#include <math.h>

#define INC 128
#define HID 64
#define OUTC 40
#define SHIFT 9
#define MAXB 256
#define NPB 64
#define ONB 96
#define LSW 41
#define SRCM 0x1FFFF
#define PLDS 12288

typedef _Float16 half2_t __attribute__((ext_vector_type(2)));

__device__ inline void fma4(float4& a, float s, const float4& w) {
    a.x += s * w.x; a.y += s * w.y; a.z += s * w.z; a.w += s * w.w;
}
__device__ inline unsigned pkh(float a, float b) {
    unsigned short ua = __builtin_bit_cast(unsigned short, (_Float16)a);
    unsigned short ub = __builtin_bit_cast(unsigned short, (_Float16)b);
    return (unsigned)ua | ((unsigned)ub << 16);
}
__device__ inline float fdot2_(unsigned a, unsigned b, float c) {
#if __has_builtin(__builtin_amdgcn_fdot2)
    return __builtin_amdgcn_fdot2(__builtin_bit_cast(half2_t, a),
                                  __builtin_bit_cast(half2_t, b), c, false);
#else
    half2_t ha = __builtin_bit_cast(half2_t, a);
    half2_t hb = __builtin_bit_cast(half2_t, b);
    return fmaf((float)ha[0], (float)hb[0], fmaf((float)ha[1], (float)hb[1], c));
#endif
}
__device__ inline float dot4(const uint4& a, const uint4& b) {
    float d = fdot2_(a.x, b.x, 0.f);
    d = fdot2_(a.y, b.y, d);
    d = fdot2_(a.z, b.z, d);
    d = fdot2_(a.w, b.w, d);
    return d;
}
__device__ inline void unpack8(float* f, const uint4& a) {
    half2_t p;
    p = __builtin_bit_cast(half2_t, a.x); f[0] = (float)p[0]; f[1] = (float)p[1];
    p = __builtin_bit_cast(half2_t, a.y); f[2] = (float)p[0]; f[3] = (float)p[1];
    p = __builtin_bit_cast(half2_t, a.z); f[4] = (float)p[0]; f[5] = (float)p[1];
    p = __builtin_bit_cast(half2_t, a.w); f[6] = (float)p[0]; f[7] = (float)p[1];
}
__device__ inline void dacc4(float4& a, unsigned xp_, const uint4& w) {
    a.x = fdot2_(xp_, w.x, a.x);
    a.y = fdot2_(xp_, w.y, a.y);
    a.z = fdot2_(xp_, w.z, a.z);
    a.w = fdot2_(xp_, w.w, a.w);
}
// packed fp16 accumulate: acc[0..3] += s * a (8 channels, 4 pk_fma)
__device__ inline void pacc(half2_t* acc, float s, const uint4& a) {
    _Float16 hs = (_Float16)s;
    half2_t s2 = {hs, hs};
    acc[0] += s2 * __builtin_bit_cast(half2_t, a.x);
    acc[1] += s2 * __builtin_bit_cast(half2_t, a.y);
    acc[2] += s2 * __builtin_bit_cast(half2_t, a.z);
    acc[3] += s2 * __builtin_bit_cast(half2_t, a.w);
}
template<int CTRL>
__device__ inline float dppadd(float d) {
    int x = __builtin_amdgcn_update_dpp(0, __builtin_bit_cast(int, d),
                                        CTRL, 0xf, 0xf, true);
    return d + __builtin_bit_cast(float, x);
}
__device__ inline float red8(float d) {
    d = dppadd<0xB1>(d);    // quad_perm xor1
    d = dppadd<0x4E>(d);    // quad_perm xor2
    d = dppadd<0x141>(d);   // row_half_mirror
    return d;
}
__device__ inline float red16(float d) {
    d = dppadd<0xB1>(d);
    d = dppadd<0x4E>(d);
    d = dppadd<0x141>(d);
    d = dppadd<0x140>(d);
    return d;
}
#define EXP2(x) __builtin_amdgcn_exp2f(x)

// ---------------- CSR build: bucketed counting sort (no self loops) ----------------

__global__ __launch_bounds__(256) void k_hist(const int* __restrict__ ei, int E,
                                              int* __restrict__ bucket_cnt,
                                              int* __restrict__ blk_cnt, int nbuck) {
    __shared__ int lh[MAXB];
    int tid = threadIdx.x;
    for (int i = tid; i < nbuck; i += 256) lh[i] = 0;
    __syncthreads();
    int base = blockIdx.x * 4096;
    int end = min(base + 4096, E);
    for (int e = base + tid; e < end; e += 256)
        atomicAdd(&lh[ei[E + e] >> SHIFT], 1);
    __syncthreads();
    for (int i = tid; i < nbuck; i += 256) {
        int v = lh[i];
        blk_cnt[blockIdx.x * MAXB + i] = v;
        if (v) atomicAdd(&bucket_cnt[i], v);
    }
}

__global__ __launch_bounds__(256) void k_bscan(const int* __restrict__ bucket_cnt,
                                               int* __restrict__ pair_base,
                                               int* __restrict__ pair_fill,
                                               int* __restrict__ row_ptr,
                                               int* __restrict__ csr_src,
                                               int n, int E, int nbuck) {
    __shared__ int tmp[MAXB];
    int tid = threadIdx.x;
    int cnt = (tid < nbuck) ? bucket_cnt[tid] : 0;
    tmp[tid] = cnt;
    __syncthreads();
    for (int off = 1; off < 256; off <<= 1) {
        int t = (tid >= off) ? tmp[tid - off] : 0;
        __syncthreads();
        tmp[tid] += t;
        __syncthreads();
    }
    if (tid < nbuck) { int pb = tmp[tid] - cnt; pair_base[tid] = pb; pair_fill[tid] = pb; }
    if (tid == 0) row_ptr[n] = E;
    if (tid < 16) csr_src[E + tid] = 0;   // pad: clamp-free pipelined reads
}

__global__ __launch_bounds__(256) void k_bin(const int* __restrict__ ei, int E,
                                             const int* __restrict__ blk_cnt,
                                             int* __restrict__ pair_fill,
                                             unsigned* __restrict__ pairs, int nbuck) {
    __shared__ int lbase[MAXB];
    int tid = threadIdx.x;
    for (int i = tid; i < nbuck; i += 256) {
        int v = blk_cnt[blockIdx.x * MAXB + i];
        lbase[i] = v ? atomicAdd(&pair_fill[i], v) : 0;
    }
    __syncthreads();
    int base = blockIdx.x * 4096;
    int end = min(base + 4096, E);
    for (int e = base + tid; e < end; e += 256) {
        int s = ei[e], d = ei[E + e];
        int pos = atomicAdd(&lbase[d >> SHIFT], 1);
        pairs[pos] = (unsigned)s | ((unsigned)(d & ((1 << SHIFT) - 1)) << 17);
    }
}

__global__ __launch_bounds__(256) void k_build(const unsigned* __restrict__ pairs,
                                               const int* __restrict__ pair_base,
                                               const int* __restrict__ bucket_cnt,
                                               int* __restrict__ row_ptr,
                                               int* __restrict__ csr_src, int n) {
    __shared__ int cnt[1 << SHIFT];
    __shared__ int offs[1 << SHIFT];
    __shared__ int stmp[256];
    __shared__ unsigned plds[PLDS];
    int b = blockIdx.x;
    int tid = threadIdx.x;
    int nb0 = b << SHIFT;
    int W = min(n - nb0, 1 << SHIFT);
    int p0 = pair_base[b], pc = bucket_cnt[b];
    bool inl = (pc <= PLDS);

    cnt[tid] = 0; cnt[tid + 256] = 0;
    if (inl) for (int i = tid; i < pc; i += 256) plds[i] = pairs[p0 + i];
    __syncthreads();
    if (inl) {
        for (int i = tid; i < pc; i += 256) atomicAdd(&cnt[plds[i] >> 17], 1);
    } else {
        for (int i = tid; i < pc; i += 256) atomicAdd(&cnt[pairs[p0 + i] >> 17], 1);
    }
    __syncthreads();

    int i0 = 2 * tid, i1 = 2 * tid + 1;
    int s0 = (i0 < W) ? cnt[i0] : 0;
    int s1 = (i1 < W) ? cnt[i1] : 0;
    int ps = s0 + s1;
    stmp[tid] = ps;
    __syncthreads();
    for (int off = 1; off < 256; off <<= 1) {
        int t = (tid >= off) ? stmp[tid - off] : 0;
        __syncthreads();
        stmp[tid] += t;
        __syncthreads();
    }
    int excl = stmp[tid] - ps;
    if (i0 < W) { row_ptr[nb0 + i0] = p0 + excl;      offs[i0] = excl; }
    if (i1 < W) { row_ptr[nb0 + i1] = p0 + excl + s0; offs[i1] = excl + s0; }
    __syncthreads();
    if (inl) {
        for (int i = tid; i < pc; i += 256) {
            unsigned pr = plds[i];
            int pos = atomicAdd(&offs[pr >> 17], 1);
            csr_src[p0 + pos] = (int)(pr & SRCM);
        }
    } else {
        for (int i = tid; i < pc; i += 256) {
            unsigned pr = pairs[p0 + i];
            int pos = atomicAdd(&offs[pr >> 17], 1);
            csr_src[p0 + pos] = (int)(pr & SRCM);
        }
    }
}

// ---------------- Linear1: fp16-pair dot2 GEMM + ReLU + normalize, fp16 out ----------------

__global__ __launch_bounds__(256, 4) void k_linear1(const float* __restrict__ x,
                                                    const float* __restrict__ W1,
                                                    const float* __restrict__ b1,
                                                    uint2* __restrict__ X1,
                                                    float* __restrict__ nrm1, int n) {
    __shared__ unsigned Wp[64 * 64];
    __shared__ unsigned xp[64 * 64];
    int tid = threadIdx.x;
    int base = blockIdx.x * NPB;

    for (int t = tid; t < 1024; t += 256) {
        int kp = t >> 4;
        int c4 = t & 15;
        float4 a = ((const float4*)W1)[(2 * kp) * 16 + c4];
        float4 b = ((const float4*)W1)[(2 * kp + 1) * 16 + c4];
        uint4 w;
        w.x = pkh(a.x, b.x); w.y = pkh(a.y, b.y);
        w.z = pkh(a.z, b.z); w.w = pkh(a.w, b.w);
        *(uint4*)&Wp[kp * 64 + c4 * 4] = w;
    }
    for (int t = tid; t < 1024; t += 256) {
        int nl = t >> 4;
        int k8 = t & 15;
        int gn = base + nl;
        float4 a, b;
        if (gn < n) {
            a = ((const float4*)x)[(size_t)gn * 32 + k8 * 2];
            b = ((const float4*)x)[(size_t)gn * 32 + k8 * 2 + 1];
        } else { a = make_float4(0,0,0,0); b = a; }
        uint4 v;
        v.x = pkh(a.x, a.y); v.y = pkh(a.z, a.w);
        v.z = pkh(b.x, b.y); v.w = pkh(b.z, b.w);
        int key = ((nl >> 2) & 3) << 2;
        *(uint4*)&xp[nl * 64 + ((k8 * 4) ^ key)] = v;
    }
    __syncthreads();

    int cg = tid & 15;
    int ng = tid >> 4;
    int n0 = ng * 4;
    const int key = (ng & 3) << 2;
    float4 acc0 = {0,0,0,0}, acc1 = {0,0,0,0}, acc2 = {0,0,0,0}, acc3 = {0,0,0,0};

    #pragma unroll 4
    for (int k4 = 0; k4 < 64; k4 += 4) {
        uint4 xq0 = *(uint4*)&xp[(n0 + 0) * 64 + (k4 ^ key)];
        uint4 xq1 = *(uint4*)&xp[(n0 + 1) * 64 + (k4 ^ key)];
        uint4 xq2 = *(uint4*)&xp[(n0 + 2) * 64 + (k4 ^ key)];
        uint4 xq3 = *(uint4*)&xp[(n0 + 3) * 64 + (k4 ^ key)];
        uint4 wq0 = *(uint4*)&Wp[(k4 + 0) * 64 + cg * 4];
        uint4 wq1 = *(uint4*)&Wp[(k4 + 1) * 64 + cg * 4];
        uint4 wq2 = *(uint4*)&Wp[(k4 + 2) * 64 + cg * 4];
        uint4 wq3 = *(uint4*)&Wp[(k4 + 3) * 64 + cg * 4];
        dacc4(acc0, xq0.x, wq0); dacc4(acc0, xq0.y, wq1); dacc4(acc0, xq0.z, wq2); dacc4(acc0, xq0.w, wq3);
        dacc4(acc1, xq1.x, wq0); dacc4(acc1, xq1.y, wq1); dacc4(acc1, xq1.z, wq2); dacc4(acc1, xq1.w, wq3);
        dacc4(acc2, xq2.x, wq0); dacc4(acc2, xq2.y, wq1); dacc4(acc2, xq2.z, wq2); dacc4(acc2, xq2.w, wq3);
        dacc4(acc3, xq3.x, wq0); dacc4(acc3, xq3.y, wq1); dacc4(acc3, xq3.z, wq2); dacc4(acc3, xq3.w, wq3);
    }

    float4 bb = ((const float4*)b1)[cg];
    float4 r[4] = {acc0, acc1, acc2, acc3};
    #pragma unroll
    for (int nl = 0; nl < 4; ++nl) {
        int node = base + n0 + nl;
        float4 v = r[nl];
        v.x = fmaxf(v.x + bb.x, 0.f); v.y = fmaxf(v.y + bb.y, 0.f);
        v.z = fmaxf(v.z + bb.z, 0.f); v.w = fmaxf(v.w + bb.w, 0.f);
        float q = v.x * v.x + v.y * v.y + v.z * v.z + v.w * v.w;
        q = red16(q);
        float rq = rsqrtf(fmaxf(q, 1e-24f));
        if (node < n) {
            X1[(size_t)node * 16 + cg] = make_uint2(pkh(v.x * rq, v.y * rq),
                                                    pkh(v.z * rq, v.w * rq));
            if (cg == 0) nrm1[node] = sqrtf(fmaxf(q, 1e-24f));
        }
    }
}

// ---------------- AGNN propagation ----------------
// 2-deep pipelined 16-edge loop; packed fp16 accumulation; packed epilogue reduce

template<bool HFOUT>
__global__ __launch_bounds__(256) void k_prop(const uint4* __restrict__ X,
                                              const float* __restrict__ nrm,
                                              const int* __restrict__ row_ptr,
                                              const int* __restrict__ csr_src,
                                              const float* __restrict__ beta_ptr,
                                              uint4* __restrict__ Xout,
                                              float* __restrict__ nrm_out, int n) {
    int node = blockIdx.x * 4 + (threadIdx.x >> 6);
    if (node >= n) return;
    int lane = threadIdx.x & 63;
    int g = lane >> 3, gl = lane & 7;
    float beta = beta_ptr ? beta_ptr[0] : 1.0f;
    float b2 = beta * 1.4426950408889634f;

    uint4 hdp = X[(unsigned)node * 8u + gl];
    int s0 = row_ptr[node], s1 = row_ptr[node + 1];
    float nd = nrm[node];

    // self-edge: dot(xn,xn)=1 by construction (zero rows: nrm sentinel -> weight exp(0)=1)
    float eself = (nd > 1.5e-12f) ? EXP2(b2) : 1.0f;
    float den0 = (g == 0) ? eself : 0.f;
    float den1 = 0.f;
    half2_t acc[4] = {{0,0},{0,0},{0,0},{0,0}};
    pacc(acc, (g == 0) ? eself * nd : 0.f, hdp);

    if (s0 < s1) {
        int i0 = csr_src[s0 + g];          // csr_src padded by 16 -> no clamp
        int i1 = csr_src[s0 + 8 + g];
        uint4 a0 = X[(unsigned)i0 * 8u + gl];
        uint4 a1 = X[(unsigned)i1 * 8u + gl];
        float n0 = nrm[i0], n1 = nrm[i1];
        bool v0 = s0 + g < s1, v1 = s0 + 8 + g < s1;
        for (int j = s0 + 16; j < s1; j += 16) {
            int i0n = csr_src[j + g];
            int i1n = csr_src[j + 8 + g];
            uint4 a0n = X[(unsigned)i0n * 8u + gl];
            uint4 a1n = X[(unsigned)i1n * 8u + gl];
            float n0n = nrm[i0n], n1n = nrm[i1n];
            float d0 = red8(dot4(a0, hdp));
            float d1 = red8(dot4(a1, hdp));
            float e0 = v0 ? EXP2(b2 * d0) : 0.f;
            float e1 = v1 ? EXP2(b2 * d1) : 0.f;
            den0 += e0; den1 += e1;
            pacc(acc, e0 * n0, a0);
            pacc(acc, e1 * n1, a1);
            a0 = a0n; a1 = a1n; n0 = n0n; n1 = n1n;
            v0 = j + g < s1; v1 = j + 8 + g < s1;
        }
        float d0 = red8(dot4(a0, hdp));
        float d1 = red8(dot4(a1, hdp));
        float e0 = v0 ? EXP2(b2 * d0) : 0.f;
        float e1 = v1 ? EXP2(b2 * d1) : 0.f;
        den0 += e0; den1 += e1;
        pacc(acc, e0 * n0, a0);
        pacc(acc, e1 * n1, a1);
    }

    // cross-group reduce: 4 packed regs + den over 3 rounds
    float den = den0 + den1;
    #pragma unroll
    for (int r = 8; r <= 32; r <<= 1) {
        #pragma unroll
        for (int c = 0; c < 4; ++c) {
            unsigned u = __shfl_xor(__builtin_bit_cast(unsigned, acc[c]), r, 64);
            acc[c] += __builtin_bit_cast(half2_t, u);
        }
        den += __shfl_xor(den, r, 64);
    }
    float inv = 1.0f / den;
    float o[8];
    #pragma unroll
    for (int c = 0; c < 4; ++c) {
        o[2 * c]     = (float)acc[c][0] * inv;
        o[2 * c + 1] = (float)acc[c][1] * inv;
    }

    if (HFOUT) {
        float q = 0.f;
        #pragma unroll
        for (int c = 0; c < 8; ++c) q += o[c] * o[c];
        q = red8(q);
        float rq = rsqrtf(fmaxf(q, 1e-24f));
        if (g == 0) {
            uint4 w;
            w.x = pkh(o[0] * rq, o[1] * rq);
            w.y = pkh(o[2] * rq, o[3] * rq);
            w.z = pkh(o[4] * rq, o[5] * rq);
            w.w = pkh(o[6] * rq, o[7] * rq);
            Xout[(unsigned)node * 8u + gl] = w;
            if (gl == 0) nrm_out[node] = sqrtf(fmaxf(q, 1e-24f));
        }
    } else {
        if (g == 0) {
            uint4 w;
            w.x = pkh(o[0], o[1]); w.y = pkh(o[2], o[3]);
            w.z = pkh(o[4], o[5]); w.w = pkh(o[6], o[7]);
            Xout[(unsigned)node * 8u + gl] = w;
        }
    }
}

// ---------------- Linear2 + log_softmax: register-tiled, fp16 input ----------------

__global__ __launch_bounds__(256) void k_out(const uint4* __restrict__ Xh,
                                             const float* __restrict__ W2,
                                             const float* __restrict__ b2,
                                             float* __restrict__ out, int n) {
    __shared__ float hs[ONB * HID];
    __shared__ float W2s[HID * OUTC];
    __shared__ float ls[ONB * LSW];
    int tid = threadIdx.x;
    int base = blockIdx.x * ONB;

    for (int i = tid; i < HID * OUTC / 4; i += 256)
        ((float4*)W2s)[i] = ((const float4*)W2)[i];
    for (int i = tid; i < ONB * 8; i += 256) {
        int nl = i >> 3, k8 = i & 7;
        int gn = base + nl;
        uint4 v = (gn < n) ? Xh[(size_t)gn * 8 + k8] : make_uint4(0, 0, 0, 0);
        float f[8]; unpack8(f, v);
        int key = ((nl >> 2) & 7) << 2;
        *(float4*)&hs[nl * HID + ((k8 * 8) ^ key)]     = make_float4(f[0], f[1], f[2], f[3]);
        *(float4*)&hs[nl * HID + ((k8 * 8 + 4) ^ key)] = make_float4(f[4], f[5], f[6], f[7]);
    }
    __syncthreads();

    if (tid < 240) {
        int ng = tid / 10, cg = tid % 10;
        int n0 = ng * 4;
        const int sw = ((ng & 7) << 2);
        float4 acc0 = {0,0,0,0}, acc1 = {0,0,0,0}, acc2 = {0,0,0,0}, acc3 = {0,0,0,0};
        #pragma unroll 4
        for (int k = 0; k < HID; k += 4) {
            float4 w0 = *(float4*)&W2s[(k + 0) * OUTC + cg * 4];
            float4 w1 = *(float4*)&W2s[(k + 1) * OUTC + cg * 4];
            float4 w2 = *(float4*)&W2s[(k + 2) * OUTC + cg * 4];
            float4 w3 = *(float4*)&W2s[(k + 3) * OUTC + cg * 4];
            float4 x0 = *(float4*)&hs[(n0 + 0) * HID + (k ^ sw)];
            float4 x1 = *(float4*)&hs[(n0 + 1) * HID + (k ^ sw)];
            float4 x2 = *(float4*)&hs[(n0 + 2) * HID + (k ^ sw)];
            float4 x3 = *(float4*)&hs[(n0 + 3) * HID + (k ^ sw)];
            fma4(acc0, x0.x, w0); fma4(acc0, x0.y, w1); fma4(acc0, x0.z, w2); fma4(acc0, x0.w, w3);
            fma4(acc1, x1.x, w0); fma4(acc1, x1.y, w1); fma4(acc1, x1.z, w2); fma4(acc1, x1.w, w3);
            fma4(acc2, x2.x, w0); fma4(acc2, x2.y, w1); fma4(acc2, x2.z, w2); fma4(acc2, x2.w, w3);
            fma4(acc3, x3.x, w0); fma4(acc3, x3.y, w1); fma4(acc3, x3.z, w2); fma4(acc3, x3.w, w3);
        }
        float4 bb = ((const float4*)b2)[cg];
        float4 rr[4] = {acc0, acc1, acc2, acc3};
        #pragma unroll
        for (int i = 0; i < 4; ++i) {
            int lb = (n0 + i) * LSW + cg * 4;
            ls[lb + 0] = rr[i].x + bb.x;
            ls[lb + 1] = rr[i].y + bb.y;
            ls[lb + 2] = rr[i].z + bb.z;
            ls[lb + 3] = rr[i].w + bb.w;
        }
    }
    __syncthreads();

    if (tid < ONB) {
        int node = base + tid;
        if (node < n) {
            float m = -INFINITY;
            #pragma unroll
            for (int c = 0; c < OUTC; ++c) m = fmaxf(m, ls[tid * LSW + c]);
            float z = 0.f;
            #pragma unroll
            for (int c = 0; c < OUTC; ++c) z += __expf(ls[tid * LSW + c] - m);
            float lz = m + __logf(z);
            #pragma unroll
            for (int c = 0; c < OUTC; ++c)
                out[(size_t)node * OUTC + c] = ls[tid * LSW + c] - lz;
        }
    }
}

// ---------------- launch ----------------

extern "C" void kernel_launch(void* const* d_in, const int* in_sizes, int n_in,
                              void* d_out, int out_size, void* d_ws, size_t ws_size,
                              hipStream_t stream) {
    const float* x   = (const float*)d_in[0];
    const int*   ei  = (const int*)d_in[1];
    const float* W1  = (const float*)d_in[2];
    const float* b1  = (const float*)d_in[3];
    const float* W2  = (const float*)d_in[4];
    const float* b2  = (const float*)d_in[5];
    const float* beta2 = (const float*)d_in[6];
    float* out = (float*)d_out;

    const int n = in_sizes[0] / INC;       // 100000
    const int E = in_sizes[1] / 2;         // 1600000
    const int nbuck = (n + (1 << SHIFT) - 1) >> SHIFT;   // 196
    const int cgrid = (E + 4095) / 4096;   // 391

    // workspace layout
    char* p = (char*)d_ws;
    uint4* X1 = (uint4*)p;             p += (size_t)n * 8 * 16;
    uint4* X2 = (uint4*)p;             p += (size_t)n * 8 * 16;
    uint4* X3 = (uint4*)p;             p += (size_t)n * 8 * 16;
    float* nrm1 = (float*)p;           p += (size_t)n * 4;
    float* nrm2 = (float*)p;           p += (size_t)n * 4;
    int* bucket_cnt  = (int*)p;        p += MAXB * 4;
    int* pair_base   = (int*)p;        p += MAXB * 4;
    int* pair_fill   = (int*)p;        p += MAXB * 4;
    int* row_ptr = (int*)p;            p += (size_t)(n + 1) * 4;
    int* csr_src = (int*)p;            p += (size_t)(E + 16) * 4;
    int* blk_cnt = (int*)p;            p += (size_t)cgrid * MAXB * 4;
    unsigned* pairs = (unsigned*)X3;   // alias: pairs dead before prop2 writes X3

    // CSR build
    (void)hipMemsetAsync(bucket_cnt, 0, MAXB * 4, stream);
    k_hist<<<cgrid, 256, 0, stream>>>(ei, E, bucket_cnt, blk_cnt, nbuck);
    k_bscan<<<1, 256, 0, stream>>>(bucket_cnt, pair_base, pair_fill, row_ptr, csr_src,
                                   n, E, nbuck);
    k_bin<<<cgrid, 256, 0, stream>>>(ei, E, blk_cnt, pair_fill, pairs, nbuck);
    k_build<<<nbuck, 256, 0, stream>>>(pairs, pair_base, bucket_cnt, row_ptr, csr_src, n);

    // MLP front + props + head
    k_linear1<<<(n + NPB - 1) / NPB, 256, 0, stream>>>(x, W1, b1, (uint2*)X1, nrm1, n);
    int pgrid = (n + 3) / 4;
    k_prop<true><<<pgrid, 256, 0, stream>>>(X1, nrm1, row_ptr, csr_src, nullptr,
                                            X2, nrm2, n);
    k_prop<false><<<pgrid, 256, 0, stream>>>(X2, nrm2, row_ptr, csr_src, beta2,
                                             X3, nullptr, n);
    k_out<<<(n + ONB - 1) / ONB, 256, 0, stream>>>(X3, W2, b2, out, n);
}